// Round 1
// baseline (5995.139 us; speedup 1.0000x reference)
//
#include <hip/hip_runtime.h>

// ---------------- constants ----------------
constexpr int B = 2, S = 4096, D = 768, H = 12, DH = 64, BLK = 64, NB = 64, NKV = 8;
constexpr int F = 3072, NS = 8, M = B * S;            // M = 8192 tokens
constexpr float SCALE = 0.125f;                        // 1/sqrt(64)
constexpr long HD = (long)M * D;                       // 6291456 floats per [M,D] buffer

// ---------------- embedding + LN ----------------
__global__ __launch_bounds__(256) void embed_ln_kern(
    const int* __restrict__ ids, const int* __restrict__ tt,
    const float* __restrict__ we, const float* __restrict__ pe, const float* __restrict__ te,
    const float* __restrict__ g, const float* __restrict__ bb, float* __restrict__ h)
{
  __shared__ float sa[4], sb[4];
  const long i = blockIdx.x;            // token index 0..8191
  const int tid = threadIdx.x;
  const int s = (int)(i & (S - 1));
  const long wo = (long)ids[i] * D;
  const long to = (long)tt[i] * D;
  const long po = (long)s * D;
  float x0 = we[wo + tid]       + pe[po + tid]       + te[to + tid];
  float x1 = we[wo + tid + 256] + pe[po + tid + 256] + te[to + tid + 256];
  float x2 = we[wo + tid + 512] + pe[po + tid + 512] + te[to + tid + 512];
  float sm = x0 + x1 + x2, sq = x0*x0 + x1*x1 + x2*x2;
  #pragma unroll
  for (int o = 32; o; o >>= 1) { sm += __shfl_xor(sm, o); sq += __shfl_xor(sq, o); }
  if ((tid & 63) == 0) { sa[tid >> 6] = sm; sb[tid >> 6] = sq; }
  __syncthreads();
  sm = sa[0] + sa[1] + sa[2] + sa[3];
  sq = sb[0] + sb[1] + sb[2] + sb[3];
  const float mean = sm * (1.f / D);
  const float var  = sq * (1.f / D) - mean * mean;
  const float rs   = rsqrtf(var + 1e-12f);
  float* row = h + i * D;
  row[tid]       = (x0 - mean) * rs * g[tid]       + bb[tid];
  row[tid + 256] = (x1 - mean) * rs * g[tid + 256] + bb[tid + 256];
  row[tid + 512] = (x2 - mean) * rs * g[tid + 512] + bb[tid + 512];
}

// ---------------- in-place LayerNorm ----------------
__global__ __launch_bounds__(256) void ln_kern(
    float* __restrict__ h, const float* __restrict__ g, const float* __restrict__ bb)
{
  __shared__ float sa[4], sb[4];
  const long i = blockIdx.x;
  const int tid = threadIdx.x;
  float* row = h + i * D;
  float x0 = row[tid], x1 = row[tid + 256], x2 = row[tid + 512];
  float sm = x0 + x1 + x2, sq = x0*x0 + x1*x1 + x2*x2;
  #pragma unroll
  for (int o = 32; o; o >>= 1) { sm += __shfl_xor(sm, o); sq += __shfl_xor(sq, o); }
  if ((tid & 63) == 0) { sa[tid >> 6] = sm; sb[tid >> 6] = sq; }
  __syncthreads();
  sm = sa[0] + sa[1] + sa[2] + sa[3];
  sq = sb[0] + sb[1] + sb[2] + sb[3];
  const float mean = sm * (1.f / D);
  const float var  = sq * (1.f / D) - mean * mean;
  const float rs   = rsqrtf(var + 1e-12f);
  row[tid]       = (x0 - mean) * rs * g[tid]       + bb[tid];
  row[tid + 256] = (x1 - mean) * rs * g[tid + 256] + bb[tid + 256];
  row[tid + 512] = (x2 - mean) * rs * g[tid + 512] + bb[tid + 512];
}

// ---------------- fp32 GEMM: C[M,N] = A[M,K] @ W[K,N] + bias (+gelu) (+residual C) ----
// BM=64, BN=128, BK=16; 256 threads; 4x8 micro-tile per thread.
__global__ __launch_bounds__(256) void gemm_kern(
    const float* __restrict__ A, const float* __restrict__ W, const float* __restrict__ bias,
    float* __restrict__ C, int N, int K, long wz, long bz, long cz, int dogelu, int dores)
{
  const int z = blockIdx.z;
  W += (long)z * wz; bias += (long)z * bz; C += (long)z * cz;
  const int tid = threadIdx.x;
  const int tx = tid & 15, ty = tid >> 4;
  const long bm = (long)blockIdx.y * 64;
  const int bn = blockIdx.x * 128;
  __shared__ float As[16][68];    // k-major: As[k][m]
  __shared__ float Bs[16][132];   // Bs[k][n]
  float acc[4][8] = {};
  const int ar = tid >> 2, ak = (tid & 3) * 4;
  for (int kk = 0; kk < K; kk += 16) {
    float4 a4 = *(const float4*)(A + (bm + ar) * K + kk + ak);
    As[ak + 0][ar] = a4.x; As[ak + 1][ar] = a4.y; As[ak + 2][ar] = a4.z; As[ak + 3][ar] = a4.w;
    #pragma unroll
    for (int q2 = 0; q2 < 2; ++q2) {
      int idx = tid + q2 * 256;
      int br = idx >> 5, bc = (idx & 31) * 4;
      *(float4*)&Bs[br][bc] = *(const float4*)(W + (long)(kk + br) * N + bn + bc);
    }
    __syncthreads();
    #pragma unroll
    for (int k2 = 0; k2 < 16; ++k2) {
      float a[4], bv[8];
      *(float4*)&a[0]  = *(const float4*)&As[k2][ty * 4];
      *(float4*)&bv[0] = *(const float4*)&Bs[k2][tx * 8];
      *(float4*)&bv[4] = *(const float4*)&Bs[k2][tx * 8 + 4];
      #pragma unroll
      for (int i2 = 0; i2 < 4; ++i2)
        #pragma unroll
        for (int j2 = 0; j2 < 8; ++j2)
          acc[i2][j2] += a[i2] * bv[j2];
    }
    __syncthreads();
  }
  #pragma unroll
  for (int i2 = 0; i2 < 4; ++i2) {
    const long row = bm + ty * 4 + i2;
    #pragma unroll
    for (int j2 = 0; j2 < 8; ++j2) {
      const int col = bn + tx * 8 + j2;
      float vv = acc[i2][j2] + bias[col];
      if (dogelu) {
        float xx = vv;
        float u = 0.7978845608028654f * (xx + 0.044715f * xx * xx * xx);
        vv = 0.5f * xx * (1.f + tanhf(u));
      }
      float* p = C + row * N + col;
      if (dores) vv += *p;
      *p = vv;
    }
  }
}

// ---------------- block attention (sparse gather or dense global rows) ----------------
// grid: (NB or 2, H, B), 256 threads = 4 waves, each wave owns 16 query rows.
// lane r = lane&15 -> local row, lg = lane>>4 -> 16-col/16-dim slice.
__global__ __launch_bounds__(256) void attn_kern(
    const float* __restrict__ q, const float* __restrict__ k, const float* __restrict__ v,
    const float* __restrict__ mask, const int* __restrict__ rb,
    float* __restrict__ ctx, int dense)
{
  int qb;
  if (dense) qb = blockIdx.x ? (NB - 1) : 0;
  else {
    qb = blockIdx.x;
    if (qb == 0 || qb == NB - 1) return;   // handled by dense launch
  }
  const int hh = blockIdx.y, b = blockIdx.z;
  const int tid = threadIdx.x, wid = tid >> 6, lane = tid & 63;
  const int rl = lane & 15, lg = lane >> 4;
  const int row = wid * 16 + rl;

  __shared__ float Ks[64][68];        // K tile, then reused for V tile
  __shared__ float Ps[4][16][68];     // per-wave probability tile

  // Q row in registers (fixed for whole kernel)
  float qr[64];
  {
    const float* qp = q + ((long)b * S + qb * 64 + row) * D + hh * 64;
    #pragma unroll
    for (int d4 = 0; d4 < 16; ++d4) {
      float4 t4 = *(const float4*)(qp + d4 * 4);
      qr[4 * d4 + 0] = t4.x; qr[4 * d4 + 1] = t4.y; qr[4 * d4 + 2] = t4.z; qr[4 * d4 + 3] = t4.w;
    }
  }

  float m_run = -1e30f, l_run = 0.f;
  float acc[16];
  #pragma unroll
  for (int dd = 0; dd < 16; ++dd) acc[dd] = 0.f;

  const int nkv = dense ? NB : NKV;
  for (int j = 0; j < nkv; ++j) {
    int kb;
    if (dense) kb = j;
    else if (j < 3) { kb = qb - 1 + j; kb = kb < 0 ? 0 : (kb > NB - 1 ? NB - 1 : kb); }
    else if (j == 3) kb = 0;
    else if (j == 4) kb = NB - 1;
    else kb = rb[qb * 3 + (j - 5)];

    const long kbase = ((long)b * S + kb * 64) * D + hh * 64;
    __syncthreads();                                    // prev PV done with Ks
    for (int t = tid; t < 1024; t += 256) {
      int r = t >> 4, c4 = (t & 15) * 4;
      *(float4*)&Ks[r][c4] = *(const float4*)(k + kbase + (long)r * D + c4);
    }
    __syncthreads();

    // scores for cols c = lg*16 + cc
    float sc[16];
    #pragma unroll
    for (int cc = 0; cc < 16; ++cc) {
      const int c = lg * 16 + cc;
      float sdot = 0.f;
      #pragma unroll
      for (int d4 = 0; d4 < 16; ++d4) {
        float4 kv4 = *(const float4*)&Ks[c][d4 * 4];
        sdot += qr[4*d4+0]*kv4.x + qr[4*d4+1]*kv4.y + qr[4*d4+2]*kv4.z + qr[4*d4+3]*kv4.w;
      }
      const float mk = mask[(long)b * S + kb * 64 + c];
      sc[cc] = sdot * SCALE + (mk - 1.0f) * 1e9f;
    }
    float mloc = sc[0];
    #pragma unroll
    for (int cc = 1; cc < 16; ++cc) mloc = fmaxf(mloc, sc[cc]);
    mloc = fmaxf(mloc, __shfl_xor(mloc, 16));
    mloc = fmaxf(mloc, __shfl_xor(mloc, 32));
    const float m_new = fmaxf(m_run, mloc);
    const float alpha = __expf(m_run - m_new);
    float ps = 0.f;
    #pragma unroll
    for (int cc = 0; cc < 16; ++cc) {
      float p = __expf(sc[cc] - m_new);
      Ps[wid][rl][lg * 16 + cc] = p;
      ps += p;
    }
    ps += __shfl_xor(ps, 16);
    ps += __shfl_xor(ps, 32);
    l_run = l_run * alpha + ps;
    m_run = m_new;
    #pragma unroll
    for (int dd = 0; dd < 16; ++dd) acc[dd] *= alpha;

    __syncthreads();                                    // K reads + Ps writes done
    for (int t = tid; t < 1024; t += 256) {             // V into same buffer
      int r = t >> 4, c4 = (t & 15) * 4;
      *(float4*)&Ks[r][c4] = *(const float4*)(v + kbase + (long)r * D + c4);
    }
    __syncthreads();

    for (int c = 0; c < 64; ++c) {
      const float p = Ps[wid][rl][c];
      float4 v0 = *(const float4*)&Ks[c][lg * 16 + 0];
      float4 v1 = *(const float4*)&Ks[c][lg * 16 + 4];
      float4 v2 = *(const float4*)&Ks[c][lg * 16 + 8];
      float4 v3 = *(const float4*)&Ks[c][lg * 16 + 12];
      acc[0]  += p * v0.x; acc[1]  += p * v0.y; acc[2]  += p * v0.z; acc[3]  += p * v0.w;
      acc[4]  += p * v1.x; acc[5]  += p * v1.y; acc[6]  += p * v1.z; acc[7]  += p * v1.w;
      acc[8]  += p * v2.x; acc[9]  += p * v2.y; acc[10] += p * v2.z; acc[11] += p * v2.w;
      acc[12] += p * v3.x; acc[13] += p * v3.y; acc[14] += p * v3.z; acc[15] += p * v3.w;
    }
  }

  const float inv = 1.f / l_run;
  const long obase = ((long)b * S + qb * 64 + row) * D + hh * 64 + lg * 16;
  #pragma unroll
  for (int dd = 0; dd < 16; ++dd) ctx[obase + dd] = acc[dd] * inv;
}

// ---------------- span mean-pool + head ----------------
__global__ __launch_bounds__(256) void span_head_kern(
    const float* __restrict__ h, const int* __restrict__ spans,
    const float* __restrict__ hw, const float* __restrict__ hb, float* __restrict__ out)
{
  __shared__ float s0[4], s1[4];
  const int bn = blockIdx.x;            // b*NS+n
  const int tid = threadIdx.x;
  const int st = spans[bn * 2], en = spans[bn * 2 + 1];
  const int b = bn >> 3;                // NS = 8
  float a0 = 0.f, a1 = 0.f, a2 = 0.f;
  for (int s = st; s < en; ++s) {
    const float* row = h + ((long)b * S + s) * D;
    a0 += row[tid]; a1 += row[tid + 256]; a2 += row[tid + 512];
  }
  const float inv = 1.f / (float)(en - st);
  a0 *= inv; a1 *= inv; a2 *= inv;
  float p0 = a0 * hw[tid * 2]     + a1 * hw[(tid + 256) * 2]     + a2 * hw[(tid + 512) * 2];
  float p1 = a0 * hw[tid * 2 + 1] + a1 * hw[(tid + 256) * 2 + 1] + a2 * hw[(tid + 512) * 2 + 1];
  #pragma unroll
  for (int o = 32; o; o >>= 1) { p0 += __shfl_xor(p0, o); p1 += __shfl_xor(p1, o); }
  if ((tid & 63) == 0) { s0[tid >> 6] = p0; s1[tid >> 6] = p1; }
  __syncthreads();
  if (tid == 0) {
    out[bn * 2]     = s0[0] + s0[1] + s0[2] + s0[3] + hb[0];
    out[bn * 2 + 1] = s1[0] + s1[1] + s1[2] + s1[3] + hb[1];
  }
}

// ---------------- launcher ----------------
extern "C" void kernel_launch(void* const* d_in, const int* in_sizes, int n_in,
                              void* d_out, int out_size, void* d_ws, size_t ws_size,
                              hipStream_t stream) {
  const int*   input_ids  = (const int*)  d_in[0];
  const float* attn_mask  = (const float*)d_in[1];
  const int*   tok_type   = (const int*)  d_in[2];
  const int*   spans      = (const int*)  d_in[3];
  const int*   rand_blk   = (const int*)  d_in[4];
  const float* word_emb   = (const float*)d_in[5];
  const float* pos_emb    = (const float*)d_in[6];
  const float* type_emb   = (const float*)d_in[7];
  const float* emb_g      = (const float*)d_in[8];
  const float* emb_b      = (const float*)d_in[9];
  const float* qkv_w      = (const float*)d_in[10];
  const float* qkv_b      = (const float*)d_in[11];
  const float* aow        = (const float*)d_in[12];
  const float* aob        = (const float*)d_in[13];
  const float* ln1g       = (const float*)d_in[14];
  const float* ln1b       = (const float*)d_in[15];
  const float* ff1w       = (const float*)d_in[16];
  const float* ff1b       = (const float*)d_in[17];
  const float* ff2w       = (const float*)d_in[18];
  const float* ff2b       = (const float*)d_in[19];
  const float* ln2g       = (const float*)d_in[20];
  const float* ln2b       = (const float*)d_in[21];
  const float* headw      = (const float*)d_in[22];
  const float* headb      = (const float*)d_in[23];

  float* ws   = (float*)d_ws;
  float* h    = ws;                 // [M, D]
  float* qkv  = ws + HD;            // q,k,v each [M, D]  (3*HD)
  float* ctx  = ws + 4 * HD;        // [M, D]
  float* ffb  = qkv;                // [M, F] overlays qkv+ctx regions (4*HD) during FFN

  embed_ln_kern<<<dim3(M), dim3(256), 0, stream>>>(
      input_ids, tok_type, word_emb, pos_emb, type_emb, emb_g, emb_b, h);

  for (int l = 0; l < 2; ++l) {
    // QKV projection (z-batched over t=0..2)
    gemm_kern<<<dim3(6, 128, 3), dim3(256), 0, stream>>>(
        h, qkv_w + (long)l * 3 * D * D, qkv_b + (long)l * 3 * D, qkv,
        D, D, (long)D * D, (long)D, HD, 0, 0);
    // sparse block attention
    attn_kern<<<dim3(NB, H, B), dim3(256), 0, stream>>>(
        qkv, qkv + HD, qkv + 2 * HD, attn_mask, rand_blk, ctx, 0);
    // dense attention for global query blocks 0 and NB-1
    attn_kern<<<dim3(2, H, B), dim3(256), 0, stream>>>(
        qkv, qkv + HD, qkv + 2 * HD, attn_mask, rand_blk, ctx, 1);
    // output projection + residual
    gemm_kern<<<dim3(6, 128, 1), dim3(256), 0, stream>>>(
        ctx, aow + (long)l * D * D, aob + (long)l * D, h, D, D, 0, 0, 0, 0, 1);
    ln_kern<<<dim3(M), dim3(256), 0, stream>>>(h, ln1g + (long)l * D, ln1b + (long)l * D);
    // FFN
    gemm_kern<<<dim3(24, 128, 1), dim3(256), 0, stream>>>(
        h, ff1w + (long)l * D * F, ff1b + (long)l * F, ffb, F, D, 0, 0, 0, 1, 0);
    gemm_kern<<<dim3(6, 128, 1), dim3(256), 0, stream>>>(
        ffb, ff2w + (long)l * F * D, ff2b + (long)l * D, h, D, F, 0, 0, 0, 0, 1);
    ln_kern<<<dim3(M), dim3(256), 0, stream>>>(h, ln2g + (long)l * D, ln2b + (long)l * D);
  }

  span_head_kern<<<dim3(B * NS), dim3(256), 0, stream>>>(h, spans, headw, headb, (float*)d_out);
}

// Round 2
// 3672.166 us; speedup vs baseline: 1.6326x; 1.6326x over previous
//
#include <hip/hip_runtime.h>

// ---------------- constants ----------------
constexpr int B = 2, S = 4096, D = 768, H = 12, DH = 64, BLK = 64, NB = 64, NKV = 8;
constexpr int F = 3072, NS = 8, M = B * S;            // M = 8192 tokens
constexpr int NCH = 4;                                 // dense split-K chunks
constexpr float SCALE = 0.125f;                        // 1/sqrt(64)
constexpr long HD = (long)M * D;                       // 6291456 floats per [M,D] buffer

// ---------------- embedding + LN ----------------
__global__ __launch_bounds__(256) void embed_ln_kern(
    const int* __restrict__ ids, const int* __restrict__ tt,
    const float* __restrict__ we, const float* __restrict__ pe, const float* __restrict__ te,
    const float* __restrict__ g, const float* __restrict__ bb, float* __restrict__ h)
{
  __shared__ float sa[4], sb[4];
  const long i = blockIdx.x;            // token index 0..8191
  const int tid = threadIdx.x;
  const int s = (int)(i & (S - 1));
  const long wo = (long)ids[i] * D;
  const long to = (long)tt[i] * D;
  const long po = (long)s * D;
  float x0 = we[wo + tid]       + pe[po + tid]       + te[to + tid];
  float x1 = we[wo + tid + 256] + pe[po + tid + 256] + te[to + tid + 256];
  float x2 = we[wo + tid + 512] + pe[po + tid + 512] + te[to + tid + 512];
  float sm = x0 + x1 + x2, sq = x0*x0 + x1*x1 + x2*x2;
  #pragma unroll
  for (int o = 32; o; o >>= 1) { sm += __shfl_xor(sm, o); sq += __shfl_xor(sq, o); }
  if ((tid & 63) == 0) { sa[tid >> 6] = sm; sb[tid >> 6] = sq; }
  __syncthreads();
  sm = sa[0] + sa[1] + sa[2] + sa[3];
  sq = sb[0] + sb[1] + sb[2] + sb[3];
  const float mean = sm * (1.f / D);
  const float var  = sq * (1.f / D) - mean * mean;
  const float rs   = rsqrtf(var + 1e-12f);
  float* row = h + i * D;
  row[tid]       = (x0 - mean) * rs * g[tid]       + bb[tid];
  row[tid + 256] = (x1 - mean) * rs * g[tid + 256] + bb[tid + 256];
  row[tid + 512] = (x2 - mean) * rs * g[tid + 512] + bb[tid + 512];
}

// ---------------- in-place LayerNorm ----------------
__global__ __launch_bounds__(256) void ln_kern(
    float* __restrict__ h, const float* __restrict__ g, const float* __restrict__ bb)
{
  __shared__ float sa[4], sb[4];
  const long i = blockIdx.x;
  const int tid = threadIdx.x;
  float* row = h + i * D;
  float x0 = row[tid], x1 = row[tid + 256], x2 = row[tid + 512];
  float sm = x0 + x1 + x2, sq = x0*x0 + x1*x1 + x2*x2;
  #pragma unroll
  for (int o = 32; o; o >>= 1) { sm += __shfl_xor(sm, o); sq += __shfl_xor(sq, o); }
  if ((tid & 63) == 0) { sa[tid >> 6] = sm; sb[tid >> 6] = sq; }
  __syncthreads();
  sm = sa[0] + sa[1] + sa[2] + sa[3];
  sq = sb[0] + sb[1] + sb[2] + sb[3];
  const float mean = sm * (1.f / D);
  const float var  = sq * (1.f / D) - mean * mean;
  const float rs   = rsqrtf(var + 1e-12f);
  row[tid]       = (x0 - mean) * rs * g[tid]       + bb[tid];
  row[tid + 256] = (x1 - mean) * rs * g[tid + 256] + bb[tid + 256];
  row[tid + 512] = (x2 - mean) * rs * g[tid + 512] + bb[tid + 512];
}

// ---------------- fp32 GEMM: C[M,N] = A[M,K] @ W[K,N] + bias (+gelu) (+residual C) ----
__global__ __launch_bounds__(256) void gemm_kern(
    const float* __restrict__ A, const float* __restrict__ W, const float* __restrict__ bias,
    float* __restrict__ C, int N, int K, long wz, long bz, long cz, int dogelu, int dores)
{
  const int z = blockIdx.z;
  W += (long)z * wz; bias += (long)z * bz; C += (long)z * cz;
  const int tid = threadIdx.x;
  const int tx = tid & 15, ty = tid >> 4;
  const long bm = (long)blockIdx.y * 64;
  const int bn = blockIdx.x * 128;
  __shared__ float As[16][68];    // k-major: As[k][m]
  __shared__ float Bs[16][132];   // Bs[k][n]
  float acc[4][8] = {};
  const int ar = tid >> 2, ak = (tid & 3) * 4;
  for (int kk = 0; kk < K; kk += 16) {
    float4 a4 = *(const float4*)(A + (bm + ar) * K + kk + ak);
    As[ak + 0][ar] = a4.x; As[ak + 1][ar] = a4.y; As[ak + 2][ar] = a4.z; As[ak + 3][ar] = a4.w;
    #pragma unroll
    for (int q2 = 0; q2 < 2; ++q2) {
      int idx = tid + q2 * 256;
      int br = idx >> 5, bc = (idx & 31) * 4;
      *(float4*)&Bs[br][bc] = *(const float4*)(W + (long)(kk + br) * N + bn + bc);
    }
    __syncthreads();
    #pragma unroll
    for (int k2 = 0; k2 < 16; ++k2) {
      float a[4], bv[8];
      *(float4*)&a[0]  = *(const float4*)&As[k2][ty * 4];
      *(float4*)&bv[0] = *(const float4*)&Bs[k2][tx * 8];
      *(float4*)&bv[4] = *(const float4*)&Bs[k2][tx * 8 + 4];
      #pragma unroll
      for (int i2 = 0; i2 < 4; ++i2)
        #pragma unroll
        for (int j2 = 0; j2 < 8; ++j2)
          acc[i2][j2] += a[i2] * bv[j2];
    }
    __syncthreads();
  }
  #pragma unroll
  for (int i2 = 0; i2 < 4; ++i2) {
    const long row = bm + ty * 4 + i2;
    #pragma unroll
    for (int j2 = 0; j2 < 8; ++j2) {
      const int col = bn + tx * 8 + j2;
      float vv = acc[i2][j2] + bias[col];
      if (dogelu) {
        float xx = vv;
        float u = 0.7978845608028654f * (xx + 0.044715f * xx * xx * xx);
        vv = 0.5f * xx * (1.f + tanhf(u));
      }
      float* p = C + row * N + col;
      if (dores) vv += *p;
      *p = vv;
    }
  }
}

// ---------------- block attention v2: 64x64 GEMM-tiled flash ----------------
// 256 threads; thread (tx=tid&15, ty=tid>>4) owns rows ty*4..+3 x cols/dims tx*4..+3.
// Q^T staged once; K^T staged per tile (buffer reused for P); V natural (k-major for PV).
// dense=1: split-K partials (acc, m, l) written to `part` for the 2 global query blocks.
__global__ __launch_bounds__(256, 3) void attn2_kern(
    const float* __restrict__ q, const float* __restrict__ k, const float* __restrict__ v,
    const float* __restrict__ mask, const int* __restrict__ rb,
    float* __restrict__ ctx, float* __restrict__ part, int dense)
{
  int qb, kv0, nkv, qb2 = 0, ch = 0;
  if (dense) {
    qb2 = blockIdx.x / NCH; ch = blockIdx.x % NCH;
    qb = qb2 ? NB - 1 : 0; kv0 = ch * (NB / NCH); nkv = NB / NCH;
  } else {
    qb = blockIdx.x;
    if (qb == 0 || qb == NB - 1) return;     // handled by dense path
    kv0 = 0; nkv = NKV;
  }
  const int hh = blockIdx.y, b = blockIdx.z;
  const int tid = threadIdx.x;
  const int tx = tid & 15, ty = tid >> 4;

  __shared__ float Qt[64][68];     // Q^T  [d][r]
  __shared__ float KtPs[64][68];   // K^T  [d][c]  then  P^T [c][r]
  __shared__ float Vs[64][68];     // V    [c][d]
  __shared__ float Ms[64];

  const long qbase = ((long)b * S + qb * 64) * D + hh * 64;

  { // stage Q^T (once)
    const int r = tid >> 2, d0 = (tid & 3) * 16;
    const float* qp = q + qbase + (long)r * D + d0;
    #pragma unroll
    for (int i = 0; i < 4; ++i) {
      float4 t4 = *(const float4*)(qp + i * 4);
      Qt[d0 + i*4 + 0][r] = t4.x;
      Qt[d0 + i*4 + 1][r] = t4.y;
      Qt[d0 + i*4 + 2][r] = t4.z;
      Qt[d0 + i*4 + 3][r] = t4.w;
    }
  }

  float acc[4][4] = {};
  float m_run[4], l_run[4];
  #pragma unroll
  for (int j = 0; j < 4; ++j) { m_run[j] = -1e30f; l_run[j] = 0.f; }

  for (int jj = 0; jj < nkv; ++jj) {
    int kb;
    if (dense) kb = kv0 + jj;
    else if (jj < 3) kb = qb - 1 + jj;            // qb in 1..62 -> no clamp needed
    else if (jj == 3) kb = 0;
    else if (jj == 4) kb = NB - 1;
    else kb = rb[qb * 3 + (jj - 5)];

    const long kbase = ((long)b * S + kb * 64) * D + hh * 64;
    __syncthreads();                               // prev PV done with KtPs/Vs
    {
      const int c = tid >> 2, d0 = (tid & 3) * 16;
      const float* kp = k + kbase + (long)c * D + d0;
      const float* vp = v + kbase + (long)c * D + d0;
      #pragma unroll
      for (int i = 0; i < 4; ++i) {
        float4 t4 = *(const float4*)(kp + i * 4);
        KtPs[d0 + i*4 + 0][c] = t4.x;
        KtPs[d0 + i*4 + 1][c] = t4.y;
        KtPs[d0 + i*4 + 2][c] = t4.z;
        KtPs[d0 + i*4 + 3][c] = t4.w;
        *(float4*)&Vs[c][d0 + i*4] = *(const float4*)(vp + i * 4);
      }
      if (tid < 64) Ms[tid] = mask[(long)b * S + kb * 64 + tid];
    }
    __syncthreads();

    // ---- QK^T: sc[j][i] = Q[row ty*4+j] . K[col tx*4+i]
    float sc[4][4] = {};
    #pragma unroll 8
    for (int d = 0; d < 64; ++d) {
      float4 qv = *(const float4*)&Qt[d][ty * 4];
      float4 kv = *(const float4*)&KtPs[d][tx * 4];
      const float qa[4] = {qv.x, qv.y, qv.z, qv.w};
      const float ka[4] = {kv.x, kv.y, kv.z, kv.w};
      #pragma unroll
      for (int j = 0; j < 4; ++j)
        #pragma unroll
        for (int i = 0; i < 4; ++i)
          sc[j][i] += qa[j] * ka[i];
    }

    // ---- online softmax (row stats via 16-lane butterfly over tx)
    float mk[4];
    #pragma unroll
    for (int i = 0; i < 4; ++i) mk[i] = (Ms[tx * 4 + i] - 1.f) * 1e9f;
    #pragma unroll
    for (int j = 0; j < 4; ++j) {
      float s0 = sc[j][0] * SCALE + mk[0];
      float s1 = sc[j][1] * SCALE + mk[1];
      float s2 = sc[j][2] * SCALE + mk[2];
      float s3 = sc[j][3] * SCALE + mk[3];
      float mx = fmaxf(fmaxf(s0, s1), fmaxf(s2, s3));
      mx = fmaxf(mx, __shfl_xor(mx, 1));
      mx = fmaxf(mx, __shfl_xor(mx, 2));
      mx = fmaxf(mx, __shfl_xor(mx, 4));
      mx = fmaxf(mx, __shfl_xor(mx, 8));
      const float mn = fmaxf(m_run[j], mx);
      const float al = __expf(m_run[j] - mn);
      float p0 = __expf(s0 - mn), p1 = __expf(s1 - mn);
      float p2 = __expf(s2 - mn), p3 = __expf(s3 - mn);
      sc[j][0] = p0; sc[j][1] = p1; sc[j][2] = p2; sc[j][3] = p3;
      float sum = p0 + p1 + p2 + p3;
      sum += __shfl_xor(sum, 1);
      sum += __shfl_xor(sum, 2);
      sum += __shfl_xor(sum, 4);
      sum += __shfl_xor(sum, 8);
      l_run[j] = l_run[j] * al + sum;
      m_run[j] = mn;
      acc[j][0] *= al; acc[j][1] *= al; acc[j][2] *= al; acc[j][3] *= al;
    }

    __syncthreads();                 // all QK reads of KtPs done
    // write P^T [c][r] into KtPs
    #pragma unroll
    for (int i = 0; i < 4; ++i)
      *(float4*)&KtPs[tx * 4 + i][ty * 4] =
          make_float4(sc[0][i], sc[1][i], sc[2][i], sc[3][i]);
    __syncthreads();

    // ---- PV: acc[j][i] += sum_c P[r][c] * V[c][d]
    #pragma unroll 8
    for (int c = 0; c < 64; ++c) {
      float4 pv = *(const float4*)&KtPs[c][ty * 4];
      float4 vv = *(const float4*)&Vs[c][tx * 4];
      const float pa[4] = {pv.x, pv.y, pv.z, pv.w};
      const float va[4] = {vv.x, vv.y, vv.z, vv.w};
      #pragma unroll
      for (int j = 0; j < 4; ++j)
        #pragma unroll
        for (int i = 0; i < 4; ++i)
          acc[j][i] += pa[j] * va[i];
    }
  }

  if (!dense) {
    #pragma unroll
    for (int j = 0; j < 4; ++j) {
      const float inv = 1.f / l_run[j];
      *(float4*)(ctx + qbase + (long)(ty * 4 + j) * D + tx * 4) =
          make_float4(acc[j][0] * inv, acc[j][1] * inv, acc[j][2] * inv, acc[j][3] * inv);
    }
  } else {
    const long pb = ((((long)b * H + hh) * 2 + qb2) * NCH + ch) * (64 * 68);
    #pragma unroll
    for (int j = 0; j < 4; ++j) {
      const int r = ty * 4 + j;
      *(float4*)(part + pb + r * 68 + tx * 4) =
          make_float4(acc[j][0], acc[j][1], acc[j][2], acc[j][3]);
      if (tx == 0) { part[pb + r * 68 + 64] = m_run[j]; part[pb + r * 68 + 65] = l_run[j]; }
    }
  }
}

// ---------------- combine dense split-K partials ----------------
__global__ __launch_bounds__(256) void attn_combine_kern(
    const float* __restrict__ part, float* __restrict__ ctx)
{
  const int g = blockIdx.x;                 // (b*H+h)*2 + qb2
  const int qb2 = g & 1;
  const int hh = (g >> 1) % H;
  const int b  = g / (2 * H);
  const int r  = threadIdx.x >> 2;          // 0..63
  const int d0 = (threadIdx.x & 3) * 16;
  const long pb = (long)g * NCH * 64 * 68;
  float mg = -1e30f;
  for (int ch = 0; ch < NCH; ++ch)
    mg = fmaxf(mg, part[pb + ch * 64 * 68 + r * 68 + 64]);
  float lg = 0.f;
  float a[16] = {};
  for (int ch = 0; ch < NCH; ++ch) {
    const float* pp = part + pb + ch * 64 * 68 + r * 68;
    const float w = __expf(pp[64] - mg);
    lg += pp[65] * w;
    #pragma unroll
    for (int i = 0; i < 4; ++i) {
      float4 t4 = *(const float4*)(pp + d0 + i * 4);
      a[i*4+0] += t4.x * w; a[i*4+1] += t4.y * w; a[i*4+2] += t4.z * w; a[i*4+3] += t4.w * w;
    }
  }
  const int qb = qb2 ? NB - 1 : 0;
  const float inv = 1.f / lg;
  float* op = ctx + ((long)b * S + qb * 64 + r) * D + hh * 64 + d0;
  #pragma unroll
  for (int i = 0; i < 4; ++i)
    *(float4*)(op + i * 4) =
        make_float4(a[i*4+0]*inv, a[i*4+1]*inv, a[i*4+2]*inv, a[i*4+3]*inv);
}

// ---------------- span mean-pool + head ----------------
__global__ __launch_bounds__(256) void span_head_kern(
    const float* __restrict__ h, const int* __restrict__ spans,
    const float* __restrict__ hw, const float* __restrict__ hb, float* __restrict__ out)
{
  __shared__ float s0[4], s1[4];
  const int bn = blockIdx.x;            // b*NS+n
  const int tid = threadIdx.x;
  const int st = spans[bn * 2], en = spans[bn * 2 + 1];
  const int b = bn >> 3;                // NS = 8
  float a0 = 0.f, a1 = 0.f, a2 = 0.f;
  for (int s = st; s < en; ++s) {
    const float* row = h + ((long)b * S + s) * D;
    a0 += row[tid]; a1 += row[tid + 256]; a2 += row[tid + 512];
  }
  const float inv = 1.f / (float)(en - st);
  a0 *= inv; a1 *= inv; a2 *= inv;
  float p0 = a0 * hw[tid * 2]     + a1 * hw[(tid + 256) * 2]     + a2 * hw[(tid + 512) * 2];
  float p1 = a0 * hw[tid * 2 + 1] + a1 * hw[(tid + 256) * 2 + 1] + a2 * hw[(tid + 512) * 2 + 1];
  #pragma unroll
  for (int o = 32; o; o >>= 1) { p0 += __shfl_xor(p0, o); p1 += __shfl_xor(p1, o); }
  if ((tid & 63) == 0) { s0[tid >> 6] = p0; s1[tid >> 6] = p1; }
  __syncthreads();
  if (tid == 0) {
    out[bn * 2]     = s0[0] + s0[1] + s0[2] + s0[3] + hb[0];
    out[bn * 2 + 1] = s1[0] + s1[1] + s1[2] + s1[3] + hb[1];
  }
}

// ---------------- launcher ----------------
extern "C" void kernel_launch(void* const* d_in, const int* in_sizes, int n_in,
                              void* d_out, int out_size, void* d_ws, size_t ws_size,
                              hipStream_t stream) {
  const int*   input_ids  = (const int*)  d_in[0];
  const float* attn_mask  = (const float*)d_in[1];
  const int*   tok_type   = (const int*)  d_in[2];
  const int*   spans      = (const int*)  d_in[3];
  const int*   rand_blk   = (const int*)  d_in[4];
  const float* word_emb   = (const float*)d_in[5];
  const float* pos_emb    = (const float*)d_in[6];
  const float* type_emb   = (const float*)d_in[7];
  const float* emb_g      = (const float*)d_in[8];
  const float* emb_b      = (const float*)d_in[9];
  const float* qkv_w      = (const float*)d_in[10];
  const float* qkv_b      = (const float*)d_in[11];
  const float* aow        = (const float*)d_in[12];
  const float* aob        = (const float*)d_in[13];
  const float* ln1g       = (const float*)d_in[14];
  const float* ln1b       = (const float*)d_in[15];
  const float* ff1w       = (const float*)d_in[16];
  const float* ff1b       = (const float*)d_in[17];
  const float* ff2w       = (const float*)d_in[18];
  const float* ff2b       = (const float*)d_in[19];
  const float* ln2g       = (const float*)d_in[20];
  const float* ln2b       = (const float*)d_in[21];
  const float* headw      = (const float*)d_in[22];
  const float* headb      = (const float*)d_in[23];

  float* ws   = (float*)d_ws;
  float* h    = ws;                 // [M, D]
  float* qkv  = ws + HD;            // q,k,v each [M, D]  (3*HD)
  float* ctx  = ws + 4 * HD;        // [M, D]
  float* ffb  = qkv;                // [M, F] overlays qkv+ctx regions during FFN
  float* part = ws + 5 * HD;        // dense split-K partials: B*H*2*NCH*64*68 floats (~6.7MB)

  embed_ln_kern<<<dim3(M), dim3(256), 0, stream>>>(
      input_ids, tok_type, word_emb, pos_emb, type_emb, emb_g, emb_b, h);

  for (int l = 0; l < 2; ++l) {
    // QKV projection (z-batched over t=0..2)
    gemm_kern<<<dim3(6, 128, 3), dim3(256), 0, stream>>>(
        h, qkv_w + (long)l * 3 * D * D, qkv_b + (long)l * 3 * D, qkv,
        D, D, (long)D * D, (long)D, HD, 0, 0);
    // sparse block attention (query blocks 1..62)
    attn2_kern<<<dim3(NB, H, B), dim3(256), 0, stream>>>(
        qkv, qkv + HD, qkv + 2 * HD, attn_mask, rand_blk, ctx, part, 0);
    // dense attention for global query blocks 0 and NB-1, split-K partials
    attn2_kern<<<dim3(2 * NCH, H, B), dim3(256), 0, stream>>>(
        qkv, qkv + HD, qkv + 2 * HD, attn_mask, rand_blk, ctx, part, 1);
    attn_combine_kern<<<dim3(B * H * 2), dim3(256), 0, stream>>>(part, ctx);
    // output projection + residual
    gemm_kern<<<dim3(6, 128, 1), dim3(256), 0, stream>>>(
        ctx, aow + (long)l * D * D, aob + (long)l * D, h, D, D, 0, 0, 0, 0, 1);
    ln_kern<<<dim3(M), dim3(256), 0, stream>>>(h, ln1g + (long)l * D, ln1b + (long)l * D);
    // FFN
    gemm_kern<<<dim3(24, 128, 1), dim3(256), 0, stream>>>(
        h, ff1w + (long)l * D * F, ff1b + (long)l * F, ffb, F, D, 0, 0, 0, 1, 0);
    gemm_kern<<<dim3(6, 128, 1), dim3(256), 0, stream>>>(
        ffb, ff2w + (long)l * F * D, ff2b + (long)l * D, h, D, F, 0, 0, 0, 0, 1);
    ln_kern<<<dim3(M), dim3(256), 0, stream>>>(h, ln2g + (long)l * D, ln2b + (long)l * D);
  }

  span_head_kern<<<dim3(B * NS), dim3(256), 0, stream>>>(h, spans, headw, headb, (float*)d_out);
}

// Round 3
// 1466.137 us; speedup vs baseline: 4.0891x; 2.5047x over previous
//
#include <hip/hip_runtime.h>

// ---------------- constants ----------------
constexpr int B = 2, S = 4096, D = 768, H = 12, DH = 64, BLK = 64, NB = 64, NKV = 8;
constexpr int F = 3072, NS = 8, M = B * S;            // M = 8192 tokens
constexpr int NCH = 4;                                 // dense split-K chunks
constexpr float SCALE = 0.125f;                        // 1/sqrt(64)
constexpr long HD = (long)M * D;                       // 6291456 floats per [M,D] buffer

using u16 = unsigned short;
using u32 = unsigned int;
using bf16 = __bf16;
using bf16x8 = __attribute__((ext_vector_type(8))) bf16;
using f32x4 = __attribute__((ext_vector_type(4))) float;

// per-layer bf16 weight region (ushort counts)
constexpr long WQ = 3L * D * D;        // 1769472
constexpr long WA = (long)D * D;       // 589824
constexpr long W1 = (long)D * F;       // 2359296
constexpr long WL = WQ + WA + W1 + W1; // 7077888 per layer

__device__ __forceinline__ u16 f2bf(float x) {
  u32 u = __builtin_bit_cast(u32, x);
  u = (u + 0x7fffu + ((u >> 16) & 1u)) >> 16;
  return (u16)u;
}
__device__ __forceinline__ u32 pack2(float a, float b) {
  return (u32)f2bf(a) | ((u32)f2bf(b) << 16);
}

// ---------------- weight transpose + cast: out[n][k] = bf16(in[k][n]) ----------------
__global__ __launch_bounds__(256) void wtrans_kern(
    const float* __restrict__ in, u16* __restrict__ out, int K, int N, long inz, long outz)
{
  in += (long)blockIdx.z * inz; out += (long)blockIdx.z * outz;
  __shared__ float T[32][33];
  const int n0 = blockIdx.x * 32, k0 = blockIdx.y * 32;
  const int c = threadIdx.x & 31, r8 = threadIdx.x >> 5;
  #pragma unroll
  for (int i = 0; i < 4; ++i)
    T[r8 + i * 8][c] = in[(long)(k0 + r8 + i * 8) * N + n0 + c];
  __syncthreads();
  #pragma unroll
  for (int i = 0; i < 4; ++i)
    out[(long)(n0 + r8 + i * 8) * K + k0 + c] = f2bf(T[c][r8 + i * 8]);
}

// ---------------- embedding + LN (fp32 h + bf16 hb) ----------------
__global__ __launch_bounds__(256) void embed_ln_kern(
    const int* __restrict__ ids, const int* __restrict__ tt,
    const float* __restrict__ we, const float* __restrict__ pe, const float* __restrict__ te,
    const float* __restrict__ g, const float* __restrict__ bb,
    float* __restrict__ h, u16* __restrict__ hb)
{
  __shared__ float sa[4], sb[4];
  const long i = blockIdx.x;
  const int tid = threadIdx.x;
  const int s = (int)(i & (S - 1));
  const long wo = (long)ids[i] * D;
  const long to = (long)tt[i] * D;
  const long po = (long)s * D;
  float x0 = we[wo + tid]       + pe[po + tid]       + te[to + tid];
  float x1 = we[wo + tid + 256] + pe[po + tid + 256] + te[to + tid + 256];
  float x2 = we[wo + tid + 512] + pe[po + tid + 512] + te[to + tid + 512];
  float sm = x0 + x1 + x2, sq = x0*x0 + x1*x1 + x2*x2;
  #pragma unroll
  for (int o = 32; o; o >>= 1) { sm += __shfl_xor(sm, o); sq += __shfl_xor(sq, o); }
  if ((tid & 63) == 0) { sa[tid >> 6] = sm; sb[tid >> 6] = sq; }
  __syncthreads();
  sm = sa[0] + sa[1] + sa[2] + sa[3];
  sq = sb[0] + sb[1] + sb[2] + sb[3];
  const float mean = sm * (1.f / D);
  const float var  = sq * (1.f / D) - mean * mean;
  const float rs   = rsqrtf(var + 1e-12f);
  float* row = h + i * D;
  u16* rb = hb + i * D;
  float y0 = (x0 - mean) * rs * g[tid]       + bb[tid];
  float y1 = (x1 - mean) * rs * g[tid + 256] + bb[tid + 256];
  float y2 = (x2 - mean) * rs * g[tid + 512] + bb[tid + 512];
  row[tid] = y0; row[tid + 256] = y1; row[tid + 512] = y2;
  rb[tid] = f2bf(y0); rb[tid + 256] = f2bf(y1); rb[tid + 512] = f2bf(y2);
}

// ---------------- in-place LayerNorm (fp32 h + bf16 hb) ----------------
__global__ __launch_bounds__(256) void ln_kern(
    float* __restrict__ h, const float* __restrict__ g, const float* __restrict__ bb,
    u16* __restrict__ hb)
{
  __shared__ float sa[4], sb[4];
  const long i = blockIdx.x;
  const int tid = threadIdx.x;
  float* row = h + i * D;
  u16* rb = hb + i * D;
  float x0 = row[tid], x1 = row[tid + 256], x2 = row[tid + 512];
  float sm = x0 + x1 + x2, sq = x0*x0 + x1*x1 + x2*x2;
  #pragma unroll
  for (int o = 32; o; o >>= 1) { sm += __shfl_xor(sm, o); sq += __shfl_xor(sq, o); }
  if ((tid & 63) == 0) { sa[tid >> 6] = sm; sb[tid >> 6] = sq; }
  __syncthreads();
  sm = sa[0] + sa[1] + sa[2] + sa[3];
  sq = sb[0] + sb[1] + sb[2] + sb[3];
  const float mean = sm * (1.f / D);
  const float var  = sq * (1.f / D) - mean * mean;
  const float rs   = rsqrtf(var + 1e-12f);
  float y0 = (x0 - mean) * rs * g[tid]       + bb[tid];
  float y1 = (x1 - mean) * rs * g[tid + 256] + bb[tid + 256];
  float y2 = (x2 - mean) * rs * g[tid + 512] + bb[tid + 512];
  row[tid] = y0; row[tid + 256] = y1; row[tid + 512] = y2;
  rb[tid] = f2bf(y0); rb[tid + 256] = f2bf(y1); rb[tid + 512] = f2bf(y2);
}

// ---------------- bf16 MFMA GEMM ----------------
// C[M,N] = A[M,K]_bf16 @ Wt[N,K]_bf16^T + bias
// 128x128 block tile, BK=64, 4 waves (2x2), 4x4 16x16x32 fragments per wave.
// mode 0: fp32 store; mode 1: gelu -> bf16 store; mode 2: fp32 residual add.
__global__ __launch_bounds__(256) void mgemm_kern(
    const u16* __restrict__ A, const u16* __restrict__ Wt,
    const float* __restrict__ bias, void* __restrict__ Cv,
    int N, int K, long wz, long bz, long cz, int mode)
{
  const int z = blockIdx.z;
  Wt += (long)z * wz; bias += (long)z * bz;
  const int tid = threadIdx.x;
  const int lane = tid & 63, w = tid >> 6;
  const int wm = w >> 1, wn = w & 1;
  const long bm = (long)blockIdx.y * 128;
  const int bn = blockIdx.x * 128;
  const int ls = lane >> 4, lr = lane & 15;

  __shared__ u16 As[8][128][8];   // [kc][row][8]  16KB
  __shared__ u16 Bs[8][128][8];   // [kc][col][8]  16KB

  f32x4 acc[4][4];
  #pragma unroll
  for (int i = 0; i < 4; ++i)
    #pragma unroll
    for (int j = 0; j < 4; ++j)
      acc[i][j] = (f32x4){0.f, 0.f, 0.f, 0.f};

  for (int kk = 0; kk < K; kk += 64) {
    __syncthreads();
    uint4 va[4], vb[4];
    #pragma unroll
    for (int i = 0; i < 4; ++i) {
      const int g = tid + i * 256;          // granule: row = g>>3, kc = g&7
      const int row = g >> 3, kc = g & 7;
      va[i] = *(const uint4*)(A  + (bm + row) * K + kk + kc * 8);
      vb[i] = *(const uint4*)(Wt + (long)(bn + row) * K + kk + kc * 8);
    }
    #pragma unroll
    for (int i = 0; i < 4; ++i) {
      const int g = tid + i * 256;
      const int row = g >> 3, kc = g & 7;
      *(uint4*)&As[kc][row][0] = va[i];
      *(uint4*)&Bs[kc][row][0] = vb[i];
    }
    __syncthreads();
    #pragma unroll
    for (int ks = 0; ks < 2; ++ks) {
      bf16x8 af[4], bv[4];
      #pragma unroll
      for (int mf = 0; mf < 4; ++mf)
        af[mf] = *(const bf16x8*)&As[ks * 4 + ls][wm * 64 + mf * 16 + lr][0];
      #pragma unroll
      for (int nf = 0; nf < 4; ++nf)
        bv[nf] = *(const bf16x8*)&Bs[ks * 4 + ls][wn * 64 + nf * 16 + lr][0];
      #pragma unroll
      for (int mf = 0; mf < 4; ++mf)
        #pragma unroll
        for (int nf = 0; nf < 4; ++nf)
          acc[mf][nf] = __builtin_amdgcn_mfma_f32_16x16x32_bf16(
              af[mf], bv[nf], acc[mf][nf], 0, 0, 0);
    }
  }

  float* Cf = (float*)Cv + (long)z * cz;
  u16*   Cu = (u16*)Cv  + (long)z * cz;
  const int r0 = ls * 4;
  #pragma unroll
  for (int nf = 0; nf < 4; ++nf) {
    const int col = bn + wn * 64 + nf * 16 + lr;
    const float bvv = bias[col];
    #pragma unroll
    for (int mf = 0; mf < 4; ++mf) {
      #pragma unroll
      for (int r = 0; r < 4; ++r) {
        const long row = bm + wm * 64 + mf * 16 + r0 + r;
        float vv = acc[mf][nf][r] + bvv;
        if (mode == 1) {
          float u = 0.7978845608028654f * (vv + 0.044715f * vv * vv * vv);
          vv = 0.5f * vv * (1.f + tanhf(u));
          Cu[row * N + col] = f2bf(vv);
        } else if (mode == 2) {
          Cf[row * N + col] += vv;
        } else {
          Cf[row * N + col] = vv;
        }
      }
    }
  }
}

// ---------------- block attention: 64x64 GEMM-tiled flash (fp32 in, bf16 ctx out) ----
__global__ __launch_bounds__(256, 3) void attn2_kern(
    const float* __restrict__ q, const float* __restrict__ k, const float* __restrict__ v,
    const float* __restrict__ mask, const int* __restrict__ rb,
    u16* __restrict__ ctx, float* __restrict__ part, int dense)
{
  int qb, kv0, nkv, qb2 = 0, ch = 0;
  if (dense) {
    qb2 = blockIdx.x / NCH; ch = blockIdx.x % NCH;
    qb = qb2 ? NB - 1 : 0; kv0 = ch * (NB / NCH); nkv = NB / NCH;
  } else {
    qb = blockIdx.x;
    if (qb == 0 || qb == NB - 1) return;
    kv0 = 0; nkv = NKV;
  }
  const int hh = blockIdx.y, b = blockIdx.z;
  const int tid = threadIdx.x;
  const int tx = tid & 15, ty = tid >> 4;

  __shared__ float Qt[64][68];
  __shared__ float KtPs[64][68];
  __shared__ float Vs[64][68];
  __shared__ float Ms[64];

  const long qbase = ((long)b * S + qb * 64) * D + hh * 64;

  {
    const int r = tid >> 2, d0 = (tid & 3) * 16;
    const float* qp = q + qbase + (long)r * D + d0;
    #pragma unroll
    for (int i = 0; i < 4; ++i) {
      float4 t4 = *(const float4*)(qp + i * 4);
      Qt[d0 + i*4 + 0][r] = t4.x;
      Qt[d0 + i*4 + 1][r] = t4.y;
      Qt[d0 + i*4 + 2][r] = t4.z;
      Qt[d0 + i*4 + 3][r] = t4.w;
    }
  }

  float acc[4][4] = {};
  float m_run[4], l_run[4];
  #pragma unroll
  for (int j = 0; j < 4; ++j) { m_run[j] = -1e30f; l_run[j] = 0.f; }

  for (int jj = 0; jj < nkv; ++jj) {
    int kb;
    if (dense) kb = kv0 + jj;
    else if (jj < 3) kb = qb - 1 + jj;
    else if (jj == 3) kb = 0;
    else if (jj == 4) kb = NB - 1;
    else kb = rb[qb * 3 + (jj - 5)];

    const long kbase = ((long)b * S + kb * 64) * D + hh * 64;
    __syncthreads();
    {
      const int c = tid >> 2, d0 = (tid & 3) * 16;
      const float* kp = k + kbase + (long)c * D + d0;
      const float* vp = v + kbase + (long)c * D + d0;
      #pragma unroll
      for (int i = 0; i < 4; ++i) {
        float4 t4 = *(const float4*)(kp + i * 4);
        KtPs[d0 + i*4 + 0][c] = t4.x;
        KtPs[d0 + i*4 + 1][c] = t4.y;
        KtPs[d0 + i*4 + 2][c] = t4.z;
        KtPs[d0 + i*4 + 3][c] = t4.w;
        *(float4*)&Vs[c][d0 + i*4] = *(const float4*)(vp + i * 4);
      }
      if (tid < 64) Ms[tid] = mask[(long)b * S + kb * 64 + tid];
    }
    __syncthreads();

    float sc[4][4] = {};
    #pragma unroll 8
    for (int d = 0; d < 64; ++d) {
      float4 qv = *(const float4*)&Qt[d][ty * 4];
      float4 kv = *(const float4*)&KtPs[d][tx * 4];
      const float qa[4] = {qv.x, qv.y, qv.z, qv.w};
      const float ka[4] = {kv.x, kv.y, kv.z, kv.w};
      #pragma unroll
      for (int j = 0; j < 4; ++j)
        #pragma unroll
        for (int i = 0; i < 4; ++i)
          sc[j][i] += qa[j] * ka[i];
    }

    float mk[4];
    #pragma unroll
    for (int i = 0; i < 4; ++i) mk[i] = (Ms[tx * 4 + i] - 1.f) * 1e9f;
    #pragma unroll
    for (int j = 0; j < 4; ++j) {
      float s0 = sc[j][0] * SCALE + mk[0];
      float s1 = sc[j][1] * SCALE + mk[1];
      float s2 = sc[j][2] * SCALE + mk[2];
      float s3 = sc[j][3] * SCALE + mk[3];
      float mx = fmaxf(fmaxf(s0, s1), fmaxf(s2, s3));
      mx = fmaxf(mx, __shfl_xor(mx, 1));
      mx = fmaxf(mx, __shfl_xor(mx, 2));
      mx = fmaxf(mx, __shfl_xor(mx, 4));
      mx = fmaxf(mx, __shfl_xor(mx, 8));
      const float mn = fmaxf(m_run[j], mx);
      const float al = __expf(m_run[j] - mn);
      float p0 = __expf(s0 - mn), p1 = __expf(s1 - mn);
      float p2 = __expf(s2 - mn), p3 = __expf(s3 - mn);
      sc[j][0] = p0; sc[j][1] = p1; sc[j][2] = p2; sc[j][3] = p3;
      float sum = p0 + p1 + p2 + p3;
      sum += __shfl_xor(sum, 1);
      sum += __shfl_xor(sum, 2);
      sum += __shfl_xor(sum, 4);
      sum += __shfl_xor(sum, 8);
      l_run[j] = l_run[j] * al + sum;
      m_run[j] = mn;
      acc[j][0] *= al; acc[j][1] *= al; acc[j][2] *= al; acc[j][3] *= al;
    }

    __syncthreads();
    #pragma unroll
    for (int i = 0; i < 4; ++i)
      *(float4*)&KtPs[tx * 4 + i][ty * 4] =
          make_float4(sc[0][i], sc[1][i], sc[2][i], sc[3][i]);
    __syncthreads();

    #pragma unroll 8
    for (int c = 0; c < 64; ++c) {
      float4 pv = *(const float4*)&KtPs[c][ty * 4];
      float4 vv = *(const float4*)&Vs[c][tx * 4];
      const float pa[4] = {pv.x, pv.y, pv.z, pv.w};
      const float va[4] = {vv.x, vv.y, vv.z, vv.w};
      #pragma unroll
      for (int j = 0; j < 4; ++j)
        #pragma unroll
        for (int i = 0; i < 4; ++i)
          acc[j][i] += pa[j] * va[i];
    }
  }

  if (!dense) {
    #pragma unroll
    for (int j = 0; j < 4; ++j) {
      const float inv = 1.f / l_run[j];
      u32 lo = pack2(acc[j][0] * inv, acc[j][1] * inv);
      u32 hi = pack2(acc[j][2] * inv, acc[j][3] * inv);
      *(uint2*)(ctx + qbase + (long)(ty * 4 + j) * D + tx * 4) = make_uint2(lo, hi);
    }
  } else {
    const long pb = ((((long)b * H + hh) * 2 + qb2) * NCH + ch) * (64 * 68);
    #pragma unroll
    for (int j = 0; j < 4; ++j) {
      const int r = ty * 4 + j;
      *(float4*)(part + pb + r * 68 + tx * 4) =
          make_float4(acc[j][0], acc[j][1], acc[j][2], acc[j][3]);
      if (tx == 0) { part[pb + r * 68 + 64] = m_run[j]; part[pb + r * 68 + 65] = l_run[j]; }
    }
  }
}

// ---------------- combine dense split-K partials ----------------
__global__ __launch_bounds__(256) void attn_combine_kern(
    const float* __restrict__ part, u16* __restrict__ ctx)
{
  const int g = blockIdx.x;
  const int qb2 = g & 1;
  const int hh = (g >> 1) % H;
  const int b  = g / (2 * H);
  const int r  = threadIdx.x >> 2;
  const int d0 = (threadIdx.x & 3) * 16;
  const long pb = (long)g * NCH * 64 * 68;
  float mg = -1e30f;
  for (int ch = 0; ch < NCH; ++ch)
    mg = fmaxf(mg, part[pb + ch * 64 * 68 + r * 68 + 64]);
  float lg = 0.f;
  float a[16] = {};
  for (int ch = 0; ch < NCH; ++ch) {
    const float* pp = part + pb + ch * 64 * 68 + r * 68;
    const float w = __expf(pp[64] - mg);
    lg += pp[65] * w;
    #pragma unroll
    for (int i = 0; i < 4; ++i) {
      float4 t4 = *(const float4*)(pp + d0 + i * 4);
      a[i*4+0] += t4.x * w; a[i*4+1] += t4.y * w; a[i*4+2] += t4.z * w; a[i*4+3] += t4.w * w;
    }
  }
  const int qb = qb2 ? NB - 1 : 0;
  const float inv = 1.f / lg;
  u16* op = ctx + ((long)b * S + qb * 64 + r) * D + hh * 64 + d0;
  #pragma unroll
  for (int i = 0; i < 4; ++i)
    *(uint2*)(op + i * 4) = make_uint2(pack2(a[i*4+0]*inv, a[i*4+1]*inv),
                                       pack2(a[i*4+2]*inv, a[i*4+3]*inv));
}

// ---------------- span mean-pool + head ----------------
__global__ __launch_bounds__(256) void span_head_kern(
    const float* __restrict__ h, const int* __restrict__ spans,
    const float* __restrict__ hw, const float* __restrict__ hb, float* __restrict__ out)
{
  __shared__ float s0[4], s1[4];
  const int bn = blockIdx.x;
  const int tid = threadIdx.x;
  const int st = spans[bn * 2], en = spans[bn * 2 + 1];
  const int b = bn >> 3;
  float a0 = 0.f, a1 = 0.f, a2 = 0.f;
  for (int s = st; s < en; ++s) {
    const float* row = h + ((long)b * S + s) * D;
    a0 += row[tid]; a1 += row[tid + 256]; a2 += row[tid + 512];
  }
  const float inv = 1.f / (float)(en - st);
  a0 *= inv; a1 *= inv; a2 *= inv;
  float p0 = a0 * hw[tid * 2]     + a1 * hw[(tid + 256) * 2]     + a2 * hw[(tid + 512) * 2];
  float p1 = a0 * hw[tid * 2 + 1] + a1 * hw[(tid + 256) * 2 + 1] + a2 * hw[(tid + 512) * 2 + 1];
  #pragma unroll
  for (int o = 32; o; o >>= 1) { p0 += __shfl_xor(p0, o); p1 += __shfl_xor(p1, o); }
  if ((tid & 63) == 0) { s0[tid >> 6] = p0; s1[tid >> 6] = p1; }
  __syncthreads();
  if (tid == 0) {
    out[bn * 2]     = s0[0] + s0[1] + s0[2] + s0[3] + hb[0];
    out[bn * 2 + 1] = s1[0] + s1[1] + s1[2] + s1[3] + hb[1];
  }
}

// ---------------- launcher ----------------
extern "C" void kernel_launch(void* const* d_in, const int* in_sizes, int n_in,
                              void* d_out, int out_size, void* d_ws, size_t ws_size,
                              hipStream_t stream) {
  const int*   input_ids  = (const int*)  d_in[0];
  const float* attn_mask  = (const float*)d_in[1];
  const int*   tok_type   = (const int*)  d_in[2];
  const int*   spans      = (const int*)  d_in[3];
  const int*   rand_blk   = (const int*)  d_in[4];
  const float* word_emb   = (const float*)d_in[5];
  const float* pos_emb    = (const float*)d_in[6];
  const float* type_emb   = (const float*)d_in[7];
  const float* emb_g      = (const float*)d_in[8];
  const float* emb_b      = (const float*)d_in[9];
  const float* qkv_w      = (const float*)d_in[10];
  const float* qkv_b      = (const float*)d_in[11];
  const float* aow        = (const float*)d_in[12];
  const float* aob        = (const float*)d_in[13];
  const float* ln1g       = (const float*)d_in[14];
  const float* ln1b       = (const float*)d_in[15];
  const float* ff1w       = (const float*)d_in[16];
  const float* ff1b       = (const float*)d_in[17];
  const float* ff2w       = (const float*)d_in[18];
  const float* ff2b       = (const float*)d_in[19];
  const float* ln2g       = (const float*)d_in[20];
  const float* ln2b       = (const float*)d_in[21];
  const float* headw      = (const float*)d_in[22];
  const float* headb      = (const float*)d_in[23];

  float* ws    = (float*)d_ws;
  float* h     = ws;                         // [M,D] fp32
  float* qkv   = ws + HD;                    // q,k,v fp32 (3*HD); ffb bf16 aliases
  u16*   ctx16 = (u16*)(ws + 4 * HD);        // [M,D] bf16
  u16*   hb    = (u16*)(ws + 4 * HD + HD/2); // [M,D] bf16; part aliases
  float* part  = (float*)hb;                 // dense split-K partials (~0.84M floats)
  u16*   wb    = (u16*)(ws + 5 * HD);        // bf16 transposed weights, 2*WL ushorts
  u16*   ffb   = (u16*)qkv;                  // [M,F] bf16 overlays qkv during FFN

  // ---- weight prep (bf16 transposed) ----
  for (int l = 0; l < 2; ++l) {
    u16* wl = wb + (long)l * WL;
    wtrans_kern<<<dim3(24, 24, 3), dim3(256), 0, stream>>>(
        qkv_w + (long)l * 3 * D * D, wl, D, D, (long)D * D, (long)D * D);
    wtrans_kern<<<dim3(24, 24, 1), dim3(256), 0, stream>>>(
        aow + (long)l * D * D, wl + WQ, D, D, 0, 0);
    wtrans_kern<<<dim3(96, 24, 1), dim3(256), 0, stream>>>(
        ff1w + (long)l * D * F, wl + WQ + WA, D, F, 0, 0);
    wtrans_kern<<<dim3(24, 96, 1), dim3(256), 0, stream>>>(
        ff2w + (long)l * F * D, wl + WQ + WA + W1, F, D, 0, 0);
  }

  embed_ln_kern<<<dim3(M), dim3(256), 0, stream>>>(
      input_ids, tok_type, word_emb, pos_emb, type_emb, emb_g, emb_b, h, hb);

  for (int l = 0; l < 2; ++l) {
    u16* wl = wb + (long)l * WL;
    // QKV projection (z over t=0..2): qkv fp32
    mgemm_kern<<<dim3(6, 64, 3), dim3(256), 0, stream>>>(
        hb, wl, qkv_b + (long)l * 3 * D, qkv, D, D, (long)D * D, (long)D, HD, 0);
    // sparse block attention
    attn2_kern<<<dim3(NB, H, B), dim3(256), 0, stream>>>(
        qkv, qkv + HD, qkv + 2 * HD, attn_mask, rand_blk, ctx16, part, 0);
    // dense attention for global query blocks, split-K
    attn2_kern<<<dim3(2 * NCH, H, B), dim3(256), 0, stream>>>(
        qkv, qkv + HD, qkv + 2 * HD, attn_mask, rand_blk, ctx16, part, 1);
    attn_combine_kern<<<dim3(B * H * 2), dim3(256), 0, stream>>>(part, ctx16);
    // output projection + residual into h
    mgemm_kern<<<dim3(6, 64, 1), dim3(256), 0, stream>>>(
        ctx16, wl + WQ, aob + (long)l * D, h, D, D, 0, 0, 0, 2);
    ln_kern<<<dim3(M), dim3(256), 0, stream>>>(h, ln1g + (long)l * D, ln1b + (long)l * D, hb);
    // FFN
    mgemm_kern<<<dim3(24, 64, 1), dim3(256), 0, stream>>>(
        hb, wl + WQ + WA, ff1b + (long)l * F, ffb, F, D, 0, 0, 0, 1);
    mgemm_kern<<<dim3(6, 64, 1), dim3(256), 0, stream>>>(
        ffb, wl + WQ + WA + W1, ff2b + (long)l * D, h, D, F, 0, 0, 0, 2);
    ln_kern<<<dim3(M), dim3(256), 0, stream>>>(h, ln2g + (long)l * D, ln2b + (long)l * D, hb);
  }

  span_head_kern<<<dim3(B * NS), dim3(256), 0, stream>>>(h, spans, headw, headb, (float*)d_out);
}

// Round 4
// 1126.891 us; speedup vs baseline: 5.3201x; 1.3010x over previous
//
#include <hip/hip_runtime.h>

// ---------------- constants ----------------
constexpr int B = 2, S = 4096, D = 768, H = 12, DH = 64, BLK = 64, NB = 64, NKV = 8;
constexpr int F = 3072, NS = 8, M = B * S;            // M = 8192 tokens
constexpr int NCH = 4;                                 // dense split-K chunks
constexpr float SCALE = 0.125f;                        // 1/sqrt(64)
constexpr long HD = (long)M * D;                       // 6291456 elems per [M,D] buffer

using u16 = unsigned short;
using u32 = unsigned int;
using bf16 = __bf16;
using bf16x8 = __attribute__((ext_vector_type(8))) bf16;
using f32x4 = __attribute__((ext_vector_type(4))) float;

// per-layer bf16 weight region (ushort counts)
constexpr long WQ = 3L * D * D;
constexpr long WA = (long)D * D;
constexpr long W1 = (long)D * F;
constexpr long WL = WQ + WA + W1 + W1;

__device__ __forceinline__ u16 f2bf(float x) {
  u32 u = __builtin_bit_cast(u32, x);
  u = (u + 0x7fffu + ((u >> 16) & 1u)) >> 16;
  return (u16)u;
}
__device__ __forceinline__ u32 pack2(float a, float b) {
  return (u32)f2bf(a) | ((u32)f2bf(b) << 16);
}

// ---------------- weight transpose + cast: out[n][k] = bf16(in[k][n]) ----------------
__global__ __launch_bounds__(256) void wtrans_kern(
    const float* __restrict__ in, u16* __restrict__ out, int K, int N, long inz, long outz)
{
  in += (long)blockIdx.z * inz; out += (long)blockIdx.z * outz;
  __shared__ float T[32][33];
  const int n0 = blockIdx.x * 32, k0 = blockIdx.y * 32;
  const int c = threadIdx.x & 31, r8 = threadIdx.x >> 5;
  #pragma unroll
  for (int i = 0; i < 4; ++i)
    T[r8 + i * 8][c] = in[(long)(k0 + r8 + i * 8) * N + n0 + c];
  __syncthreads();
  #pragma unroll
  for (int i = 0; i < 4; ++i)
    out[(long)(n0 + r8 + i * 8) * K + k0 + c] = f2bf(T[c][r8 + i * 8]);
}

// ---------------- embedding + LN (fp32 h + bf16 hb) ----------------
__global__ __launch_bounds__(256) void embed_ln_kern(
    const int* __restrict__ ids, const int* __restrict__ tt,
    const float* __restrict__ we, const float* __restrict__ pe, const float* __restrict__ te,
    const float* __restrict__ g, const float* __restrict__ bb,
    float* __restrict__ h, u16* __restrict__ hb)
{
  __shared__ float sa[4], sb[4];
  const long i = blockIdx.x;
  const int tid = threadIdx.x;
  const int s = (int)(i & (S - 1));
  const long wo = (long)ids[i] * D;
  const long to = (long)tt[i] * D;
  const long po = (long)s * D;
  float x0 = we[wo + tid]       + pe[po + tid]       + te[to + tid];
  float x1 = we[wo + tid + 256] + pe[po + tid + 256] + te[to + tid + 256];
  float x2 = we[wo + tid + 512] + pe[po + tid + 512] + te[to + tid + 512];
  float sm = x0 + x1 + x2, sq = x0*x0 + x1*x1 + x2*x2;
  #pragma unroll
  for (int o = 32; o; o >>= 1) { sm += __shfl_xor(sm, o); sq += __shfl_xor(sq, o); }
  if ((tid & 63) == 0) { sa[tid >> 6] = sm; sb[tid >> 6] = sq; }
  __syncthreads();
  sm = sa[0] + sa[1] + sa[2] + sa[3];
  sq = sb[0] + sb[1] + sb[2] + sb[3];
  const float mean = sm * (1.f / D);
  const float var  = sq * (1.f / D) - mean * mean;
  const float rs   = rsqrtf(var + 1e-12f);
  float* row = h + i * D;
  u16* rb = hb + i * D;
  float y0 = (x0 - mean) * rs * g[tid]       + bb[tid];
  float y1 = (x1 - mean) * rs * g[tid + 256] + bb[tid + 256];
  float y2 = (x2 - mean) * rs * g[tid + 512] + bb[tid + 512];
  row[tid] = y0; row[tid + 256] = y1; row[tid + 512] = y2;
  rb[tid] = f2bf(y0); rb[tid + 256] = f2bf(y1); rb[tid + 512] = f2bf(y2);
}

// ---------------- in-place LayerNorm (fp32 h + bf16 hb) ----------------
__global__ __launch_bounds__(256) void ln_kern(
    float* __restrict__ h, const float* __restrict__ g, const float* __restrict__ bb,
    u16* __restrict__ hb)
{
  __shared__ float sa[4], sb[4];
  const long i = blockIdx.x;
  const int tid = threadIdx.x;
  float* row = h + i * D;
  u16* rb = hb + i * D;
  float x0 = row[tid], x1 = row[tid + 256], x2 = row[tid + 512];
  float sm = x0 + x1 + x2, sq = x0*x0 + x1*x1 + x2*x2;
  #pragma unroll
  for (int o = 32; o; o >>= 1) { sm += __shfl_xor(sm, o); sq += __shfl_xor(sq, o); }
  if ((tid & 63) == 0) { sa[tid >> 6] = sm; sb[tid >> 6] = sq; }
  __syncthreads();
  sm = sa[0] + sa[1] + sa[2] + sa[3];
  sq = sb[0] + sb[1] + sb[2] + sb[3];
  const float mean = sm * (1.f / D);
  const float var  = sq * (1.f / D) - mean * mean;
  const float rs   = rsqrtf(var + 1e-12f);
  float y0 = (x0 - mean) * rs * g[tid]       + bb[tid];
  float y1 = (x1 - mean) * rs * g[tid + 256] + bb[tid + 256];
  float y2 = (x2 - mean) * rs * g[tid + 512] + bb[tid + 512];
  row[tid] = y0; row[tid + 256] = y1; row[tid + 512] = y2;
  rb[tid] = f2bf(y0); rb[tid + 256] = f2bf(y1); rb[tid + 512] = f2bf(y2);
}

// ---------------- bf16 MFMA GEMM ----------------
// C[M,N] = A[M,K]_bf16 @ Wt[N,K]_bf16^T + bias
// 128x128 tile, BK=64, 4 waves (2x2), 4x4 16x16x32 fragments per wave.
// mode 0: fp32 store; 1: gelu->bf16; 2: fp32 residual add;
// mode 3: bf16 store, but z==2 (V of QKV) stored transposed to [b,h,d,S].
__global__ __launch_bounds__(256) void mgemm_kern(
    const u16* __restrict__ A, const u16* __restrict__ Wt,
    const float* __restrict__ bias, void* __restrict__ Cv,
    int N, int K, long wz, long bz, long cz, int mode)
{
  const int z = blockIdx.z;
  Wt += (long)z * wz; bias += (long)z * bz;
  const int tid = threadIdx.x;
  const int lane = tid & 63, w = tid >> 6;
  const int wm = w >> 1, wn = w & 1;
  const long bm = (long)blockIdx.y * 128;
  const int bn = blockIdx.x * 128;
  const int ls = lane >> 4, lr = lane & 15;

  __shared__ u16 As[8][128][8];
  __shared__ u16 Bs[8][128][8];

  f32x4 acc[4][4];
  #pragma unroll
  for (int i = 0; i < 4; ++i)
    #pragma unroll
    for (int j = 0; j < 4; ++j)
      acc[i][j] = (f32x4){0.f, 0.f, 0.f, 0.f};

  for (int kk = 0; kk < K; kk += 64) {
    __syncthreads();
    uint4 va[4], vb[4];
    #pragma unroll
    for (int i = 0; i < 4; ++i) {
      const int g = tid + i * 256;
      const int row = g >> 3, kc = g & 7;
      va[i] = *(const uint4*)(A  + (bm + row) * K + kk + kc * 8);
      vb[i] = *(const uint4*)(Wt + (long)(bn + row) * K + kk + kc * 8);
    }
    #pragma unroll
    for (int i = 0; i < 4; ++i) {
      const int g = tid + i * 256;
      const int row = g >> 3, kc = g & 7;
      *(uint4*)&As[kc][row][0] = va[i];
      *(uint4*)&Bs[kc][row][0] = vb[i];
    }
    __syncthreads();
    #pragma unroll
    for (int ks = 0; ks < 2; ++ks) {
      bf16x8 af[4], bv[4];
      #pragma unroll
      for (int mf = 0; mf < 4; ++mf)
        af[mf] = *(const bf16x8*)&As[ks * 4 + ls][wm * 64 + mf * 16 + lr][0];
      #pragma unroll
      for (int nf = 0; nf < 4; ++nf)
        bv[nf] = *(const bf16x8*)&Bs[ks * 4 + ls][wn * 64 + nf * 16 + lr][0];
      #pragma unroll
      for (int mf = 0; mf < 4; ++mf)
        #pragma unroll
        for (int nf = 0; nf < 4; ++nf)
          acc[mf][nf] = __builtin_amdgcn_mfma_f32_16x16x32_bf16(
              af[mf], bv[nf], acc[mf][nf], 0, 0, 0);
    }
  }

  float* Cf = (float*)Cv + (long)z * cz;
  u16*   Cu = (u16*)Cv  + (long)z * cz;
  const int r0 = ls * 4;

  if (mode == 3 && z == 2) {
    // V: store transposed [b][h][d][S] bf16, packed 4 tokens per uint2
    #pragma unroll
    for (int nf = 0; nf < 4; ++nf) {
      const int col = bn + wn * 64 + nf * 16 + lr;
      const int hcol = col >> 6, dcol = col & 63;
      const float bvv = bias[col];
      #pragma unroll
      for (int mf = 0; mf < 4; ++mf) {
        const long t0 = bm + wm * 64 + mf * 16 + r0;   // 4 consecutive tokens
        const int bb2 = (int)(t0 >> 12), s0 = (int)(t0 & (S - 1));
        const float v0 = acc[mf][nf][0] + bvv, v1 = acc[mf][nf][1] + bvv;
        const float v2 = acc[mf][nf][2] + bvv, v3 = acc[mf][nf][3] + bvv;
        *(uint2*)(Cu + (((long)bb2 * H + hcol) * 64 + dcol) * S + s0) =
            make_uint2(pack2(v0, v1), pack2(v2, v3));
      }
    }
    return;
  }

  #pragma unroll
  for (int nf = 0; nf < 4; ++nf) {
    const int col = bn + wn * 64 + nf * 16 + lr;
    const float bvv = bias[col];
    #pragma unroll
    for (int mf = 0; mf < 4; ++mf) {
      #pragma unroll
      for (int r = 0; r < 4; ++r) {
        const long row = bm + wm * 64 + mf * 16 + r0 + r;
        float vv = acc[mf][nf][r] + bvv;
        if (mode == 1) {
          float u = 0.7978845608028654f * (vv + 0.044715f * vv * vv * vv);
          vv = 0.5f * vv * (1.f + tanhf(u));
          Cu[row * N + col] = f2bf(vv);
        } else if (mode == 2) {
          Cf[row * N + col] += vv;
        } else if (mode == 3) {
          Cu[row * N + col] = f2bf(vv);
        } else {
          Cf[row * N + col] = vv;
        }
      }
    }
  }
}

// ---------------- MFMA block attention ----------------
// 4 waves; wave w owns q-rows w*16..w*16+15. Q frags in regs; K natural LDS;
// V^T (pre-transposed global [b,h,d,S]) staged LDS [d][key]; P via LDS.
__global__ __launch_bounds__(256) void mattn_kern(
    const u16* __restrict__ q, const u16* __restrict__ k, const u16* __restrict__ vt,
    const float* __restrict__ mask, const int* __restrict__ rb,
    u16* __restrict__ ctx, float* __restrict__ part, int dense)
{
  int qb, kv0, nkv, qb2 = 0, ch = 0;
  if (dense) {
    qb2 = blockIdx.x / NCH; ch = blockIdx.x % NCH;
    qb = qb2 ? NB - 1 : 0; kv0 = ch * (NB / NCH); nkv = NB / NCH;
  } else {
    qb = blockIdx.x;
    if (qb == 0 || qb == NB - 1) return;
    kv0 = 0; nkv = NKV;
  }
  const int hh = blockIdx.y, b = blockIdx.z;
  const int tid = threadIdx.x, lane = tid & 63, w = tid >> 6;
  const int lr = lane & 15, hi = lane >> 4;

  __shared__ u16 Ks[64][72];     // K tile [key][d]
  __shared__ u16 Vs[64][72];     // V^T tile [d][key]
  __shared__ u16 Ps[64][72];     // P tile [q][key] bf16
  __shared__ float Ms[64];

  const long qrow0 = (long)b * S + qb * 64;
  bf16x8 qf[2];
  {
    const u16* qp = q + (qrow0 + w * 16 + lr) * D + hh * 64 + hi * 8;
    qf[0] = *(const bf16x8*)(qp);
    qf[1] = *(const bf16x8*)(qp + 32);
  }
  const long vtbase = (((long)b * H + hh) * 64) * S;

  f32x4 acc[4];
  #pragma unroll
  for (int nf = 0; nf < 4; ++nf) acc[nf] = (f32x4){0.f, 0.f, 0.f, 0.f};
  float m_run[4], l_run[4];
  #pragma unroll
  for (int r = 0; r < 4; ++r) { m_run[r] = -1e30f; l_run[r] = 0.f; }

  for (int jj = 0; jj < nkv; ++jj) {
    int kb;
    if (dense) kb = kv0 + jj;
    else if (jj < 3) kb = qb - 1 + jj;
    else if (jj == 3) kb = 0;
    else if (jj == 4) kb = NB - 1;
    else kb = rb[qb * 3 + (jj - 5)];

    const long krow0 = (long)b * S + kb * 64;
    __syncthreads();
    {
      int key = tid >> 3, kc = tid & 7;
      *(uint4*)&Ks[key][kc * 8] = *(const uint4*)(k + (krow0 + key) * D + hh * 64 + kc * 8);
      *(uint4*)&Vs[key][kc * 8] = *(const uint4*)(vt + vtbase + (long)key * S + kb * 64 + kc * 8);
      key = (tid + 256) >> 3;
      *(uint4*)&Ks[key][kc * 8] = *(const uint4*)(k + (krow0 + key) * D + hh * 64 + kc * 8);
      *(uint4*)&Vs[key][kc * 8] = *(const uint4*)(vt + vtbase + (long)key * S + kb * 64 + kc * 8);
      if (tid < 64) Ms[tid] = mask[krow0 + tid];
    }
    __syncthreads();

    // ---- QK^T: sc[kf] rows = w*16 + hi*4 + r, col = kf*16 + lr
    f32x4 sc[4];
    #pragma unroll
    for (int kf = 0; kf < 4; ++kf) sc[kf] = (f32x4){0.f, 0.f, 0.f, 0.f};
    #pragma unroll
    for (int kc = 0; kc < 2; ++kc) {
      #pragma unroll
      for (int kf = 0; kf < 4; ++kf) {
        bf16x8 kfr = *(const bf16x8*)&Ks[kf * 16 + lr][kc * 32 + hi * 8];
        sc[kf] = __builtin_amdgcn_mfma_f32_16x16x32_bf16(qf[kc], kfr, sc[kf], 0, 0, 0);
      }
    }

    // ---- online softmax
    float mkk[4];
    #pragma unroll
    for (int kf = 0; kf < 4; ++kf) mkk[kf] = (Ms[kf * 16 + lr] - 1.f) * 1e9f;
    #pragma unroll
    for (int r = 0; r < 4; ++r) {
      float s0 = sc[0][r] * SCALE + mkk[0];
      float s1 = sc[1][r] * SCALE + mkk[1];
      float s2 = sc[2][r] * SCALE + mkk[2];
      float s3 = sc[3][r] * SCALE + mkk[3];
      float mx = fmaxf(fmaxf(s0, s1), fmaxf(s2, s3));
      mx = fmaxf(mx, __shfl_xor(mx, 1));
      mx = fmaxf(mx, __shfl_xor(mx, 2));
      mx = fmaxf(mx, __shfl_xor(mx, 4));
      mx = fmaxf(mx, __shfl_xor(mx, 8));
      const float mn = fmaxf(m_run[r], mx);
      const float al = __expf(m_run[r] - mn);
      float p0 = __expf(s0 - mn), p1 = __expf(s1 - mn);
      float p2 = __expf(s2 - mn), p3 = __expf(s3 - mn);
      float sum = p0 + p1 + p2 + p3;
      sum += __shfl_xor(sum, 1);
      sum += __shfl_xor(sum, 2);
      sum += __shfl_xor(sum, 4);
      sum += __shfl_xor(sum, 8);
      l_run[r] = l_run[r] * al + sum;
      m_run[r] = mn;
      acc[0][r] *= al; acc[1][r] *= al; acc[2][r] *= al; acc[3][r] *= al;
      const int prow = w * 16 + hi * 4 + r;
      Ps[prow][ 0 + lr] = f2bf(p0);
      Ps[prow][16 + lr] = f2bf(p1);
      Ps[prow][32 + lr] = f2bf(p2);
      Ps[prow][48 + lr] = f2bf(p3);
    }
    __syncthreads();

    // ---- PV: acc[nf] rows = q, cols = nf*16 + lr (d)
    #pragma unroll
    for (int kc = 0; kc < 2; ++kc) {
      bf16x8 pf = *(const bf16x8*)&Ps[w * 16 + lr][kc * 32 + hi * 8];
      #pragma unroll
      for (int nf = 0; nf < 4; ++nf) {
        bf16x8 vfr = *(const bf16x8*)&Vs[nf * 16 + lr][kc * 32 + hi * 8];
        acc[nf] = __builtin_amdgcn_mfma_f32_16x16x32_bf16(pf, vfr, acc[nf], 0, 0, 0);
      }
    }
  }

  if (!dense) {
    #pragma unroll
    for (int r = 0; r < 4; ++r) {
      const float inv = 1.f / l_run[r];
      u16* op = ctx + (qrow0 + w * 16 + hi * 4 + r) * D + hh * 64 + lr;
      op[ 0] = f2bf(acc[0][r] * inv);
      op[16] = f2bf(acc[1][r] * inv);
      op[32] = f2bf(acc[2][r] * inv);
      op[48] = f2bf(acc[3][r] * inv);
    }
  } else {
    const long pb = ((((long)b * H + hh) * 2 + qb2) * NCH + ch) * (64 * 68);
    #pragma unroll
    for (int r = 0; r < 4; ++r) {
      float* pp = part + pb + (w * 16 + hi * 4 + r) * 68;
      pp[ 0 + lr] = acc[0][r];
      pp[16 + lr] = acc[1][r];
      pp[32 + lr] = acc[2][r];
      pp[48 + lr] = acc[3][r];
      if (lr == 0) { pp[64] = m_run[r]; pp[65] = l_run[r]; }
    }
  }
}

// ---------------- combine dense split-K partials ----------------
__global__ __launch_bounds__(256) void attn_combine_kern(
    const float* __restrict__ part, u16* __restrict__ ctx)
{
  const int g = blockIdx.x;
  const int qb2 = g & 1;
  const int hh = (g >> 1) % H;
  const int b  = g / (2 * H);
  const int r  = threadIdx.x >> 2;
  const int d0 = (threadIdx.x & 3) * 16;
  const long pb = (long)g * NCH * 64 * 68;
  float mg = -1e30f;
  for (int ch = 0; ch < NCH; ++ch)
    mg = fmaxf(mg, part[pb + ch * 64 * 68 + r * 68 + 64]);
  float lg = 0.f;
  float a[16] = {};
  for (int ch = 0; ch < NCH; ++ch) {
    const float* pp = part + pb + ch * 64 * 68 + r * 68;
    const float w = __expf(pp[64] - mg);
    lg += pp[65] * w;
    #pragma unroll
    for (int i = 0; i < 4; ++i) {
      float4 t4 = *(const float4*)(pp + d0 + i * 4);
      a[i*4+0] += t4.x * w; a[i*4+1] += t4.y * w; a[i*4+2] += t4.z * w; a[i*4+3] += t4.w * w;
    }
  }
  const int qb = qb2 ? NB - 1 : 0;
  const float inv = 1.f / lg;
  u16* op = ctx + ((long)b * S + qb * 64 + r) * D + hh * 64 + d0;
  #pragma unroll
  for (int i = 0; i < 4; ++i)
    *(uint2*)(op + i * 4) = make_uint2(pack2(a[i*4+0]*inv, a[i*4+1]*inv),
                                       pack2(a[i*4+2]*inv, a[i*4+3]*inv));
}

// ---------------- span mean-pool + head ----------------
__global__ __launch_bounds__(256) void span_head_kern(
    const float* __restrict__ h, const int* __restrict__ spans,
    const float* __restrict__ hw, const float* __restrict__ hb, float* __restrict__ out)
{
  __shared__ float s0[4], s1[4];
  const int bn = blockIdx.x;
  const int tid = threadIdx.x;
  const int st = spans[bn * 2], en = spans[bn * 2 + 1];
  const int b = bn >> 3;
  float a0 = 0.f, a1 = 0.f, a2 = 0.f;
  for (int s = st; s < en; ++s) {
    const float* row = h + ((long)b * S + s) * D;
    a0 += row[tid]; a1 += row[tid + 256]; a2 += row[tid + 512];
  }
  const float inv = 1.f / (float)(en - st);
  a0 *= inv; a1 *= inv; a2 *= inv;
  float p0 = a0 * hw[tid * 2]     + a1 * hw[(tid + 256) * 2]     + a2 * hw[(tid + 512) * 2];
  float p1 = a0 * hw[tid * 2 + 1] + a1 * hw[(tid + 256) * 2 + 1] + a2 * hw[(tid + 512) * 2 + 1];
  #pragma unroll
  for (int o = 32; o; o >>= 1) { p0 += __shfl_xor(p0, o); p1 += __shfl_xor(p1, o); }
  if ((tid & 63) == 0) { s0[tid >> 6] = p0; s1[tid >> 6] = p1; }
  __syncthreads();
  if (tid == 0) {
    out[bn * 2]     = s0[0] + s0[1] + s0[2] + s0[3] + hb[0];
    out[bn * 2 + 1] = s1[0] + s1[1] + s1[2] + s1[3] + hb[1];
  }
}

// ---------------- launcher ----------------
extern "C" void kernel_launch(void* const* d_in, const int* in_sizes, int n_in,
                              void* d_out, int out_size, void* d_ws, size_t ws_size,
                              hipStream_t stream) {
  const int*   input_ids  = (const int*)  d_in[0];
  const float* attn_mask  = (const float*)d_in[1];
  const int*   tok_type   = (const int*)  d_in[2];
  const int*   spans      = (const int*)  d_in[3];
  const int*   rand_blk   = (const int*)  d_in[4];
  const float* word_emb   = (const float*)d_in[5];
  const float* pos_emb    = (const float*)d_in[6];
  const float* type_emb   = (const float*)d_in[7];
  const float* emb_g      = (const float*)d_in[8];
  const float* emb_b      = (const float*)d_in[9];
  const float* qkv_w      = (const float*)d_in[10];
  const float* qkv_b      = (const float*)d_in[11];
  const float* aow        = (const float*)d_in[12];
  const float* aob        = (const float*)d_in[13];
  const float* ln1g       = (const float*)d_in[14];
  const float* ln1b       = (const float*)d_in[15];
  const float* ff1w       = (const float*)d_in[16];
  const float* ff1b       = (const float*)d_in[17];
  const float* ff2w       = (const float*)d_in[18];
  const float* ff2b       = (const float*)d_in[19];
  const float* ln2g       = (const float*)d_in[20];
  const float* ln2b       = (const float*)d_in[21];
  const float* headw      = (const float*)d_in[22];
  const float* headb      = (const float*)d_in[23];

  float* ws    = (float*)d_ws;
  float* h     = ws;                          // [M,D] fp32                 0 .. HD
  u16*   qkvb  = (u16*)(ws + HD);             // q,k bf16 [M,D]; vt [B,H,64,S]  (3*HD u16)
  u16*   ffb   = (u16*)(ws + HD);             // [M,F] bf16 overlays qkv region (2*HD floats)
  u16*   ctx16 = (u16*)(ws + 3 * HD);         // [M,D] bf16                 3HD .. 3.5HD
  u16*   hb    = (u16*)(ws + 3 * HD + HD/2);  // [M,D] bf16                 3.5HD .. 4HD
  float* part  = ws + 4 * HD;                 // dense partials ~0.84M floats
  u16*   wb    = (u16*)(ws + 4 * HD + HD/4);  // bf16 weights 2*WL u16

  // ---- weight prep (bf16 transposed) ----
  for (int l = 0; l < 2; ++l) {
    u16* wl = wb + (long)l * WL;
    wtrans_kern<<<dim3(24, 24, 3), dim3(256), 0, stream>>>(
        qkv_w + (long)l * 3 * D * D, wl, D, D, (long)D * D, (long)D * D);
    wtrans_kern<<<dim3(24, 24, 1), dim3(256), 0, stream>>>(
        aow + (long)l * D * D, wl + WQ, D, D, 0, 0);
    wtrans_kern<<<dim3(96, 24, 1), dim3(256), 0, stream>>>(
        ff1w + (long)l * D * F, wl + WQ + WA, D, F, 0, 0);
    wtrans_kern<<<dim3(24, 96, 1), dim3(256), 0, stream>>>(
        ff2w + (long)l * F * D, wl + WQ + WA + W1, F, D, 0, 0);
  }

  embed_ln_kern<<<dim3(M), dim3(256), 0, stream>>>(
      input_ids, tok_type, word_emb, pos_emb, type_emb, emb_g, emb_b, h, hb);

  for (int l = 0; l < 2; ++l) {
    u16* wl = wb + (long)l * WL;
    // QKV projection -> bf16 q,k natural; v transposed [b,h,d,S]
    mgemm_kern<<<dim3(6, 64, 3), dim3(256), 0, stream>>>(
        hb, wl, qkv_b + (long)l * 3 * D, qkvb, D, D, (long)D * D, (long)D, HD, 3);
    // sparse block attention (MFMA)
    mattn_kern<<<dim3(NB, H, B), dim3(256), 0, stream>>>(
        qkvb, qkvb + HD, qkvb + 2 * HD, attn_mask, rand_blk, ctx16, part, 0);
    // dense attention for global query blocks, split-K
    mattn_kern<<<dim3(2 * NCH, H, B), dim3(256), 0, stream>>>(
        qkvb, qkvb + HD, qkvb + 2 * HD, attn_mask, rand_blk, ctx16, part, 1);
    attn_combine_kern<<<dim3(B * H * 2), dim3(256), 0, stream>>>(part, ctx16);
    // output projection + residual into h
    mgemm_kern<<<dim3(6, 64, 1), dim3(256), 0, stream>>>(
        ctx16, wl + WQ, aob + (long)l * D, h, D, D, 0, 0, 0, 2);
    ln_kern<<<dim3(M), dim3(256), 0, stream>>>(h, ln1g + (long)l * D, ln1b + (long)l * D, hb);
    // FFN
    mgemm_kern<<<dim3(24, 64, 1), dim3(256), 0, stream>>>(
        hb, wl + WQ + WA, ff1b + (long)l * F, ffb, F, D, 0, 0, 0, 1);
    mgemm_kern<<<dim3(6, 64, 1), dim3(256), 0, stream>>>(
        ffb, wl + WQ + WA + W1, ff2b + (long)l * D, h, D, F, 0, 0, 0, 2);
    ln_kern<<<dim3(M), dim3(256), 0, stream>>>(h, ln2g + (long)l * D, ln2b + (long)l * D, hb);
  }

  span_head_kern<<<dim3(B * NS), dim3(256), 0, stream>>>(h, spans, headw, headb, (float*)d_out);
}

// Round 5
// 893.254 us; speedup vs baseline: 6.7116x; 1.2616x over previous
//
#include <hip/hip_runtime.h>

// ---------------- constants ----------------
constexpr int B = 2, S = 4096, D = 768, H = 12, DH = 64, BLK = 64, NB = 64, NKV = 8;
constexpr int F = 3072, NS = 8, M = B * S;            // M = 8192 tokens
constexpr int NCH = 4;                                 // dense split-K chunks
constexpr float SCALE = 0.125f;                        // 1/sqrt(64)
constexpr long HD = (long)M * D;                       // 6291456 elems per [M,D] buffer

using u16 = unsigned short;
using u32 = unsigned int;
using bf16 = __bf16;
using bf16x8 = __attribute__((ext_vector_type(8))) bf16;
using f32x4 = __attribute__((ext_vector_type(4))) float;

// per-layer bf16 weight region (ushort counts)
constexpr long WQ = 3L * D * D;
constexpr long WA = (long)D * D;
constexpr long W1 = (long)D * F;
constexpr long WL = WQ + WA + W1 + W1;

__device__ __forceinline__ u16 f2bf(float x) {
  u32 u = __builtin_bit_cast(u32, x);
  u = (u + 0x7fffu + ((u >> 16) & 1u)) >> 16;
  return (u16)u;
}
__device__ __forceinline__ u32 pack2(float a, float b) {
  return (u32)f2bf(a) | ((u32)f2bf(b) << 16);
}

// async 16B global -> LDS (dest = wave-uniform base + lane*16)
__device__ __forceinline__ void gload16(const void* g, void* l) {
  __builtin_amdgcn_global_load_lds(
      (const __attribute__((address_space(1))) u32*)g,
      (__attribute__((address_space(3))) u32*)l, 16, 0, 0);
}

// ---------------- weight transpose + cast: out[n][k] = bf16(in[k][n]) ----------------
__global__ __launch_bounds__(256) void wtrans_kern(
    const float* __restrict__ in, u16* __restrict__ out, int K, int N, long inz, long outz)
{
  in += (long)blockIdx.z * inz; out += (long)blockIdx.z * outz;
  __shared__ float T[32][33];
  const int n0 = blockIdx.x * 32, k0 = blockIdx.y * 32;
  const int c = threadIdx.x & 31, r8 = threadIdx.x >> 5;
  #pragma unroll
  for (int i = 0; i < 4; ++i)
    T[r8 + i * 8][c] = in[(long)(k0 + r8 + i * 8) * N + n0 + c];
  __syncthreads();
  #pragma unroll
  for (int i = 0; i < 4; ++i)
    out[(long)(n0 + r8 + i * 8) * K + k0 + c] = f2bf(T[c][r8 + i * 8]);
}

// ---------------- embedding + LN (fp32 h + bf16 hb) ----------------
__global__ __launch_bounds__(256) void embed_ln_kern(
    const int* __restrict__ ids, const int* __restrict__ tt,
    const float* __restrict__ we, const float* __restrict__ pe, const float* __restrict__ te,
    const float* __restrict__ g, const float* __restrict__ bb,
    float* __restrict__ h, u16* __restrict__ hb)
{
  __shared__ float sa[4], sb[4];
  const long i = blockIdx.x;
  const int tid = threadIdx.x;
  const int s = (int)(i & (S - 1));
  const long wo = (long)ids[i] * D;
  const long to = (long)tt[i] * D;
  const long po = (long)s * D;
  float x0 = we[wo + tid]       + pe[po + tid]       + te[to + tid];
  float x1 = we[wo + tid + 256] + pe[po + tid + 256] + te[to + tid + 256];
  float x2 = we[wo + tid + 512] + pe[po + tid + 512] + te[to + tid + 512];
  float sm = x0 + x1 + x2, sq = x0*x0 + x1*x1 + x2*x2;
  #pragma unroll
  for (int o = 32; o; o >>= 1) { sm += __shfl_xor(sm, o); sq += __shfl_xor(sq, o); }
  if ((tid & 63) == 0) { sa[tid >> 6] = sm; sb[tid >> 6] = sq; }
  __syncthreads();
  sm = sa[0] + sa[1] + sa[2] + sa[3];
  sq = sb[0] + sb[1] + sb[2] + sb[3];
  const float mean = sm * (1.f / D);
  const float var  = sq * (1.f / D) - mean * mean;
  const float rs   = rsqrtf(var + 1e-12f);
  float* row = h + i * D;
  u16* rb = hb + i * D;
  float y0 = (x0 - mean) * rs * g[tid]       + bb[tid];
  float y1 = (x1 - mean) * rs * g[tid + 256] + bb[tid + 256];
  float y2 = (x2 - mean) * rs * g[tid + 512] + bb[tid + 512];
  row[tid] = y0; row[tid + 256] = y1; row[tid + 512] = y2;
  rb[tid] = f2bf(y0); rb[tid + 256] = f2bf(y1); rb[tid + 512] = f2bf(y2);
}

// ---------------- in-place LayerNorm (fp32 h + bf16 hb) ----------------
__global__ __launch_bounds__(256) void ln_kern(
    float* __restrict__ h, const float* __restrict__ g, const float* __restrict__ bb,
    u16* __restrict__ hb)
{
  __shared__ float sa[4], sb[4];
  const long i = blockIdx.x;
  const int tid = threadIdx.x;
  float* row = h + i * D;
  u16* rb = hb + i * D;
  float x0 = row[tid], x1 = row[tid + 256], x2 = row[tid + 512];
  float sm = x0 + x1 + x2, sq = x0*x0 + x1*x1 + x2*x2;
  #pragma unroll
  for (int o = 32; o; o >>= 1) { sm += __shfl_xor(sm, o); sq += __shfl_xor(sq, o); }
  if ((tid & 63) == 0) { sa[tid >> 6] = sm; sb[tid >> 6] = sq; }
  __syncthreads();
  sm = sa[0] + sa[1] + sa[2] + sa[3];
  sq = sb[0] + sb[1] + sb[2] + sb[3];
  const float mean = sm * (1.f / D);
  const float var  = sq * (1.f / D) - mean * mean;
  const float rs   = rsqrtf(var + 1e-12f);
  float y0 = (x0 - mean) * rs * g[tid]       + bb[tid];
  float y1 = (x1 - mean) * rs * g[tid + 256] + bb[tid + 256];
  float y2 = (x2 - mean) * rs * g[tid + 512] + bb[tid + 512];
  row[tid] = y0; row[tid + 256] = y1; row[tid + 512] = y2;
  rb[tid] = f2bf(y0); rb[tid + 256] = f2bf(y1); rb[tid + 512] = f2bf(y2);
}

// ---------------- bf16 MFMA GEMM (global_load_lds staging, XOR-swizzled LDS) ----------
// C[M,N] = A[M,K]_bf16 @ Wt[N,K]_bf16^T + bias
// 128x128 tile, BK=64, 4 waves (2x2), 4x4 16x16x32 fragments per wave.
// LDS tile linear [row][64]; granule n (16B) holds global (row=n>>3, kc=(n&7)^(row&7));
// fragment read applies the same XOR -> <=4-way bank aliasing.
// mode 0: fp32 store; 1: gelu->bf16; 2: fp32 residual add (atomic if ksplit>1);
// mode 3: bf16 store, z==2 (V of QKV) stored transposed to [b,h,d,S].
// ksplit>1: blockIdx.z indexes a K-chunk of size K/ksplit (wz/bz/cz must be 0).
__global__ __launch_bounds__(256) void mgemm_kern(
    const u16* __restrict__ A, const u16* __restrict__ Wt,
    const float* __restrict__ bias, void* __restrict__ Cv,
    int N, int K, long wz, long bz, long cz, int mode, int ksplit)
{
  const int z = blockIdx.z;
  int k0 = 0, kend = K;
  if (ksplit > 1) {
    const int kch = K / ksplit;
    k0 = z * kch; kend = k0 + kch;
  } else {
    Wt += (long)z * wz; bias += (long)z * bz;
  }
  const int tid = threadIdx.x;
  const int lane = tid & 63, w = tid >> 6;
  const int wm = w >> 1, wn = w & 1;
  const long bm = (long)blockIdx.y * 128;
  const int bn = blockIdx.x * 128;
  const int ls = lane >> 4, lr = lane & 15;

  __shared__ u16 As[128][64];
  __shared__ u16 Bs[128][64];
  u16* AsL = &As[0][0];
  u16* BsL = &Bs[0][0];

  f32x4 acc[4][4];
  #pragma unroll
  for (int i = 0; i < 4; ++i)
    #pragma unroll
    for (int j = 0; j < 4; ++j)
      acc[i][j] = (f32x4){0.f, 0.f, 0.f, 0.f};

  for (int kk = k0; kk < kend; kk += 64) {
    __syncthreads();
    // stage: each wave issues 4 A-calls + 4 B-calls of 64 granules each
    #pragma unroll
    for (int c = 0; c < 4; ++c) {
      const int n = (w * 4 + c) * 64 + lane;       // granule index 0..1023
      const int row = n >> 3;
      const int kc2 = (n & 7) ^ (row & 7);         // inverse-swizzled source column
      gload16(A  + (bm + row) * K + kk + kc2 * 8, AsL + (w * 4 + c) * 512);
      gload16(Wt + (long)(bn + row) * K + kk + kc2 * 8, BsL + (w * 4 + c) * 512);
    }
    __syncthreads();   // vmcnt(0) drain before compute
    #pragma unroll
    for (int ks = 0; ks < 2; ++ks) {
      bf16x8 af[4], bv[4];
      const int kc = ks * 4 + ls;
      const int sw = (kc ^ (lr & 7)) << 3;         // (row&7)==(lr&7) for frag rows
      #pragma unroll
      for (int mf = 0; mf < 4; ++mf)
        af[mf] = *(const bf16x8*)&AsL[(wm * 64 + mf * 16 + lr) * 64 + sw];
      #pragma unroll
      for (int nf = 0; nf < 4; ++nf)
        bv[nf] = *(const bf16x8*)&BsL[(wn * 64 + nf * 16 + lr) * 64 + sw];
      #pragma unroll
      for (int mf = 0; mf < 4; ++mf)
        #pragma unroll
        for (int nf = 0; nf < 4; ++nf)
          acc[mf][nf] = __builtin_amdgcn_mfma_f32_16x16x32_bf16(
              af[mf], bv[nf], acc[mf][nf], 0, 0, 0);
    }
  }

  float* Cf = (float*)Cv + (long)z * cz;
  u16*   Cu = (u16*)Cv  + (long)z * cz;
  const int r0 = ls * 4;
  const bool addb = (ksplit == 1) || (z == 0);

  if (mode == 3 && z == 2) {
    // V: store transposed [b][h][d][S] bf16, packed 4 tokens per uint2
    #pragma unroll
    for (int nf = 0; nf < 4; ++nf) {
      const int col = bn + wn * 64 + nf * 16 + lr;
      const int hcol = col >> 6, dcol = col & 63;
      const float bvv = bias[col];
      #pragma unroll
      for (int mf = 0; mf < 4; ++mf) {
        const long t0 = bm + wm * 64 + mf * 16 + r0;
        const int bb2 = (int)(t0 >> 12), s0 = (int)(t0 & (S - 1));
        const float v0 = acc[mf][nf][0] + bvv, v1 = acc[mf][nf][1] + bvv;
        const float v2 = acc[mf][nf][2] + bvv, v3 = acc[mf][nf][3] + bvv;
        *(uint2*)(Cu + (((long)bb2 * H + hcol) * 64 + dcol) * S + s0) =
            make_uint2(pack2(v0, v1), pack2(v2, v3));
      }
    }
    return;
  }

  #pragma unroll
  for (int nf = 0; nf < 4; ++nf) {
    const int col = bn + wn * 64 + nf * 16 + lr;
    const float bvv = addb ? bias[col] : 0.f;
    #pragma unroll
    for (int mf = 0; mf < 4; ++mf) {
      #pragma unroll
      for (int r = 0; r < 4; ++r) {
        const long row = bm + wm * 64 + mf * 16 + r0 + r;
        float vv = acc[mf][nf][r] + bvv;
        if (mode == 1) {
          float u = 0.7978845608028654f * (vv + 0.044715f * vv * vv * vv);
          vv = 0.5f * vv * (1.f + tanhf(u));
          Cu[row * N + col] = f2bf(vv);
        } else if (mode == 2) {
          if (ksplit > 1) atomicAdd(&Cf[row * N + col], vv);
          else            Cf[row * N + col] += vv;
        } else if (mode == 3) {
          Cu[row * N + col] = f2bf(vv);
        } else {
          Cf[row * N + col] = vv;
        }
      }
    }
  }
}

// ---------------- MFMA block attention ----------------
__global__ __launch_bounds__(256) void mattn_kern(
    const u16* __restrict__ q, const u16* __restrict__ k, const u16* __restrict__ vt,
    const float* __restrict__ mask, const int* __restrict__ rb,
    u16* __restrict__ ctx, float* __restrict__ part, int dense)
{
  int qb, kv0, nkv, qb2 = 0, ch = 0;
  if (dense) {
    qb2 = blockIdx.x / NCH; ch = blockIdx.x % NCH;
    qb = qb2 ? NB - 1 : 0; kv0 = ch * (NB / NCH); nkv = NB / NCH;
  } else {
    qb = blockIdx.x;
    if (qb == 0 || qb == NB - 1) return;
    kv0 = 0; nkv = NKV;
  }
  const int hh = blockIdx.y, b = blockIdx.z;
  const int tid = threadIdx.x, lane = tid & 63, w = tid >> 6;
  const int lr = lane & 15, hi = lane >> 4;

  __shared__ u16 Ks[64][72];
  __shared__ u16 Vs[64][72];
  __shared__ u16 Ps[64][72];
  __shared__ float Ms[64];

  const long qrow0 = (long)b * S + qb * 64;
  bf16x8 qf[2];
  {
    const u16* qp = q + (qrow0 + w * 16 + lr) * D + hh * 64 + hi * 8;
    qf[0] = *(const bf16x8*)(qp);
    qf[1] = *(const bf16x8*)(qp + 32);
  }
  const long vtbase = (((long)b * H + hh) * 64) * S;

  f32x4 acc[4];
  #pragma unroll
  for (int nf = 0; nf < 4; ++nf) acc[nf] = (f32x4){0.f, 0.f, 0.f, 0.f};
  float m_run[4], l_run[4];
  #pragma unroll
  for (int r = 0; r < 4; ++r) { m_run[r] = -1e30f; l_run[r] = 0.f; }

  for (int jj = 0; jj < nkv; ++jj) {
    int kb;
    if (dense) kb = kv0 + jj;
    else if (jj < 3) kb = qb - 1 + jj;
    else if (jj == 3) kb = 0;
    else if (jj == 4) kb = NB - 1;
    else kb = rb[qb * 3 + (jj - 5)];

    const long krow0 = (long)b * S + kb * 64;
    __syncthreads();
    {
      int key = tid >> 3, kc = tid & 7;
      *(uint4*)&Ks[key][kc * 8] = *(const uint4*)(k + (krow0 + key) * D + hh * 64 + kc * 8);
      *(uint4*)&Vs[key][kc * 8] = *(const uint4*)(vt + vtbase + (long)key * S + kb * 64 + kc * 8);
      key = (tid + 256) >> 3;
      *(uint4*)&Ks[key][kc * 8] = *(const uint4*)(k + (krow0 + key) * D + hh * 64 + kc * 8);
      *(uint4*)&Vs[key][kc * 8] = *(const uint4*)(vt + vtbase + (long)key * S + kb * 64 + kc * 8);
      if (tid < 64) Ms[tid] = mask[krow0 + tid];
    }
    __syncthreads();

    f32x4 sc[4];
    #pragma unroll
    for (int kf = 0; kf < 4; ++kf) sc[kf] = (f32x4){0.f, 0.f, 0.f, 0.f};
    #pragma unroll
    for (int kc = 0; kc < 2; ++kc) {
      #pragma unroll
      for (int kf = 0; kf < 4; ++kf) {
        bf16x8 kfr = *(const bf16x8*)&Ks[kf * 16 + lr][kc * 32 + hi * 8];
        sc[kf] = __builtin_amdgcn_mfma_f32_16x16x32_bf16(qf[kc], kfr, sc[kf], 0, 0, 0);
      }
    }

    float mkk[4];
    #pragma unroll
    for (int kf = 0; kf < 4; ++kf) mkk[kf] = (Ms[kf * 16 + lr] - 1.f) * 1e9f;
    #pragma unroll
    for (int r = 0; r < 4; ++r) {
      float s0 = sc[0][r] * SCALE + mkk[0];
      float s1 = sc[1][r] * SCALE + mkk[1];
      float s2 = sc[2][r] * SCALE + mkk[2];
      float s3 = sc[3][r] * SCALE + mkk[3];
      float mx = fmaxf(fmaxf(s0, s1), fmaxf(s2, s3));
      mx = fmaxf(mx, __shfl_xor(mx, 1));
      mx = fmaxf(mx, __shfl_xor(mx, 2));
      mx = fmaxf(mx, __shfl_xor(mx, 4));
      mx = fmaxf(mx, __shfl_xor(mx, 8));
      const float mn = fmaxf(m_run[r], mx);
      const float al = __expf(m_run[r] - mn);
      float p0 = __expf(s0 - mn), p1 = __expf(s1 - mn);
      float p2 = __expf(s2 - mn), p3 = __expf(s3 - mn);
      float sum = p0 + p1 + p2 + p3;
      sum += __shfl_xor(sum, 1);
      sum += __shfl_xor(sum, 2);
      sum += __shfl_xor(sum, 4);
      sum += __shfl_xor(sum, 8);
      l_run[r] = l_run[r] * al + sum;
      m_run[r] = mn;
      acc[0][r] *= al; acc[1][r] *= al; acc[2][r] *= al; acc[3][r] *= al;
      const int prow = w * 16 + hi * 4 + r;
      Ps[prow][ 0 + lr] = f2bf(p0);
      Ps[prow][16 + lr] = f2bf(p1);
      Ps[prow][32 + lr] = f2bf(p2);
      Ps[prow][48 + lr] = f2bf(p3);
    }
    __syncthreads();

    #pragma unroll
    for (int kc = 0; kc < 2; ++kc) {
      bf16x8 pf = *(const bf16x8*)&Ps[w * 16 + lr][kc * 32 + hi * 8];
      #pragma unroll
      for (int nf = 0; nf < 4; ++nf) {
        bf16x8 vfr = *(const bf16x8*)&Vs[nf * 16 + lr][kc * 32 + hi * 8];
        acc[nf] = __builtin_amdgcn_mfma_f32_16x16x32_bf16(pf, vfr, acc[nf], 0, 0, 0);
      }
    }
  }

  if (!dense) {
    #pragma unroll
    for (int r = 0; r < 4; ++r) {
      const float inv = 1.f / l_run[r];
      u16* op = ctx + (qrow0 + w * 16 + hi * 4 + r) * D + hh * 64 + lr;
      op[ 0] = f2bf(acc[0][r] * inv);
      op[16] = f2bf(acc[1][r] * inv);
      op[32] = f2bf(acc[2][r] * inv);
      op[48] = f2bf(acc[3][r] * inv);
    }
  } else {
    const long pb = ((((long)b * H + hh) * 2 + qb2) * NCH + ch) * (64 * 68);
    #pragma unroll
    for (int r = 0; r < 4; ++r) {
      float* pp = part + pb + (w * 16 + hi * 4 + r) * 68;
      pp[ 0 + lr] = acc[0][r];
      pp[16 + lr] = acc[1][r];
      pp[32 + lr] = acc[2][r];
      pp[48 + lr] = acc[3][r];
      if (lr == 0) { pp[64] = m_run[r]; pp[65] = l_run[r]; }
    }
  }
}

// ---------------- combine dense split-K partials ----------------
__global__ __launch_bounds__(256) void attn_combine_kern(
    const float* __restrict__ part, u16* __restrict__ ctx)
{
  const int g = blockIdx.x;
  const int qb2 = g & 1;
  const int hh = (g >> 1) % H;
  const int b  = g / (2 * H);
  const int r  = threadIdx.x >> 2;
  const int d0 = (threadIdx.x & 3) * 16;
  const long pb = (long)g * NCH * 64 * 68;
  float mg = -1e30f;
  for (int ch = 0; ch < NCH; ++ch)
    mg = fmaxf(mg, part[pb + ch * 64 * 68 + r * 68 + 64]);
  float lg = 0.f;
  float a[16] = {};
  for (int ch = 0; ch < NCH; ++ch) {
    const float* pp = part + pb + ch * 64 * 68 + r * 68;
    const float w = __expf(pp[64] - mg);
    lg += pp[65] * w;
    #pragma unroll
    for (int i = 0; i < 4; ++i) {
      float4 t4 = *(const float4*)(pp + d0 + i * 4);
      a[i*4+0] += t4.x * w; a[i*4+1] += t4.y * w; a[i*4+2] += t4.z * w; a[i*4+3] += t4.w * w;
    }
  }
  const int qb = qb2 ? NB - 1 : 0;
  const float inv = 1.f / lg;
  u16* op = ctx + ((long)b * S + qb * 64 + r) * D + hh * 64 + d0;
  #pragma unroll
  for (int i = 0; i < 4; ++i)
    *(uint2*)(op + i * 4) = make_uint2(pack2(a[i*4+0]*inv, a[i*4+1]*inv),
                                       pack2(a[i*4+2]*inv, a[i*4+3]*inv));
}

// ---------------- span mean-pool + head ----------------
__global__ __launch_bounds__(256) void span_head_kern(
    const float* __restrict__ h, const int* __restrict__ spans,
    const float* __restrict__ hw, const float* __restrict__ hb, float* __restrict__ out)
{
  __shared__ float s0[4], s1[4];
  const int bn = blockIdx.x;
  const int tid = threadIdx.x;
  const int st = spans[bn * 2], en = spans[bn * 2 + 1];
  const int b = bn >> 3;
  float a0 = 0.f, a1 = 0.f, a2 = 0.f;
  for (int s = st; s < en; ++s) {
    const float* row = h + ((long)b * S + s) * D;
    a0 += row[tid]; a1 += row[tid + 256]; a2 += row[tid + 512];
  }
  const float inv = 1.f / (float)(en - st);
  a0 *= inv; a1 *= inv; a2 *= inv;
  float p0 = a0 * hw[tid * 2]     + a1 * hw[(tid + 256) * 2]     + a2 * hw[(tid + 512) * 2];
  float p1 = a0 * hw[tid * 2 + 1] + a1 * hw[(tid + 256) * 2 + 1] + a2 * hw[(tid + 512) * 2 + 1];
  #pragma unroll
  for (int o = 32; o; o >>= 1) { p0 += __shfl_xor(p0, o); p1 += __shfl_xor(p1, o); }
  if ((tid & 63) == 0) { s0[tid >> 6] = p0; s1[tid >> 6] = p1; }
  __syncthreads();
  if (tid == 0) {
    out[bn * 2]     = s0[0] + s0[1] + s0[2] + s0[3] + hb[0];
    out[bn * 2 + 1] = s1[0] + s1[1] + s1[2] + s1[3] + hb[1];
  }
}

// ---------------- launcher ----------------
extern "C" void kernel_launch(void* const* d_in, const int* in_sizes, int n_in,
                              void* d_out, int out_size, void* d_ws, size_t ws_size,
                              hipStream_t stream) {
  const int*   input_ids  = (const int*)  d_in[0];
  const float* attn_mask  = (const float*)d_in[1];
  const int*   tok_type   = (const int*)  d_in[2];
  const int*   spans      = (const int*)  d_in[3];
  const int*   rand_blk   = (const int*)  d_in[4];
  const float* word_emb   = (const float*)d_in[5];
  const float* pos_emb    = (const float*)d_in[6];
  const float* type_emb   = (const float*)d_in[7];
  const float* emb_g      = (const float*)d_in[8];
  const float* emb_b      = (const float*)d_in[9];
  const float* qkv_w      = (const float*)d_in[10];
  const float* qkv_b      = (const float*)d_in[11];
  const float* aow        = (const float*)d_in[12];
  const float* aob        = (const float*)d_in[13];
  const float* ln1g       = (const float*)d_in[14];
  const float* ln1b       = (const float*)d_in[15];
  const float* ff1w       = (const float*)d_in[16];
  const float* ff1b       = (const float*)d_in[17];
  const float* ff2w       = (const float*)d_in[18];
  const float* ff2b       = (const float*)d_in[19];
  const float* ln2g       = (const float*)d_in[20];
  const float* ln2b       = (const float*)d_in[21];
  const float* headw      = (const float*)d_in[22];
  const float* headb      = (const float*)d_in[23];

  float* ws    = (float*)d_ws;
  float* h     = ws;                          // [M,D] fp32
  u16*   qkvb  = (u16*)(ws + HD);             // q,k bf16 [M,D]; vt [B,H,64,S]
  u16*   ffb   = (u16*)(ws + HD);             // [M,F] bf16 overlays qkv region
  u16*   ctx16 = (u16*)(ws + 3 * HD);         // [M,D] bf16
  u16*   hb    = (u16*)(ws + 3 * HD + HD/2);  // [M,D] bf16
  float* part  = ws + 4 * HD;                 // dense partials ~0.84M floats
  u16*   wb    = (u16*)(ws + 4 * HD + HD/4);  // bf16 weights 2*WL u16

  // ---- weight prep (bf16 transposed) ----
  for (int l = 0; l < 2; ++l) {
    u16* wl = wb + (long)l * WL;
    wtrans_kern<<<dim3(24, 24, 3), dim3(256), 0, stream>>>(
        qkv_w + (long)l * 3 * D * D, wl, D, D, (long)D * D, (long)D * D);
    wtrans_kern<<<dim3(24, 24, 1), dim3(256), 0, stream>>>(
        aow + (long)l * D * D, wl + WQ, D, D, 0, 0);
    wtrans_kern<<<dim3(96, 24, 1), dim3(256), 0, stream>>>(
        ff1w + (long)l * D * F, wl + WQ + WA, D, F, 0, 0);
    wtrans_kern<<<dim3(24, 96, 1), dim3(256), 0, stream>>>(
        ff2w + (long)l * F * D, wl + WQ + WA + W1, F, D, 0, 0);
  }

  embed_ln_kern<<<dim3(M), dim3(256), 0, stream>>>(
      input_ids, tok_type, word_emb, pos_emb, type_emb, emb_g, emb_b, h, hb);

  for (int l = 0; l < 2; ++l) {
    u16* wl = wb + (long)l * WL;
    // QKV projection -> bf16 q,k natural; v transposed [b,h,d,S]
    mgemm_kern<<<dim3(6, 64, 3), dim3(256), 0, stream>>>(
        hb, wl, qkv_b + (long)l * 3 * D, qkvb, D, D, (long)D * D, (long)D, HD, 3, 1);
    // sparse block attention (MFMA)
    mattn_kern<<<dim3(NB, H, B), dim3(256), 0, stream>>>(
        qkvb, qkvb + HD, qkvb + 2 * HD, attn_mask, rand_blk, ctx16, part, 0);
    // dense attention for global query blocks, split-K
    mattn_kern<<<dim3(2 * NCH, H, B), dim3(256), 0, stream>>>(
        qkvb, qkvb + HD, qkvb + 2 * HD, attn_mask, rand_blk, ctx16, part, 1);
    attn_combine_kern<<<dim3(B * H * 2), dim3(256), 0, stream>>>(part, ctx16);
    // output projection + residual into h (split-K 2, atomic)
    mgemm_kern<<<dim3(6, 64, 2), dim3(256), 0, stream>>>(
        ctx16, wl + WQ, aob + (long)l * D, h, D, D, 0, 0, 0, 2, 2);
    ln_kern<<<dim3(M), dim3(256), 0, stream>>>(h, ln1g + (long)l * D, ln1b + (long)l * D, hb);
    // FFN
    mgemm_kern<<<dim3(24, 64, 1), dim3(256), 0, stream>>>(
        hb, wl + WQ + WA, ff1b + (long)l * F, ffb, F, D, 0, 0, 0, 1, 1);
    mgemm_kern<<<dim3(6, 64, 2), dim3(256), 0, stream>>>(
        ffb, wl + WQ + WA + W1, ff2b + (long)l * D, h, D, F, 0, 0, 0, 2, 2);
    ln_kern<<<dim3(M), dim3(256), 0, stream>>>(h, ln2g + (long)l * D, ln2b + (long)l * D, hb);
  }

  span_head_kern<<<dim3(B * NS), dim3(256), 0, stream>>>(h, spans, headw, headb, (float*)d_out);
}

// Round 6
// 858.093 us; speedup vs baseline: 6.9866x; 1.0410x over previous
//
#include <hip/hip_runtime.h>

// ---------------- constants ----------------
constexpr int B = 2, S = 4096, D = 768, H = 12, DH = 64, BLK = 64, NB = 64, NKV = 8;
constexpr int F = 3072, NS = 8, M = B * S;            // M = 8192 tokens
constexpr int NCH = 4;                                 // dense split-K chunks
constexpr float SCALE = 0.125f;                        // 1/sqrt(64)
constexpr long HD = (long)M * D;                       // 6291456 elems per [M,D] buffer

using u16 = unsigned short;
using u32 = unsigned int;
using bf16 = __bf16;
using bf16x8 = __attribute__((ext_vector_type(8))) bf16;
using f32x4 = __attribute__((ext_vector_type(4))) float;

// per-layer bf16 weight region (ushort counts)
constexpr long WQ = 3L * D * D;
constexpr long WA = (long)D * D;
constexpr long W1 = (long)D * F;
constexpr long WL = WQ + WA + W1 + W1;

__device__ __forceinline__ u16 f2bf(float x) {
  u32 u = __builtin_bit_cast(u32, x);
  u = (u + 0x7fffu + ((u >> 16) & 1u)) >> 16;
  return (u16)u;
}
__device__ __forceinline__ u32 pack2(float a, float b) {
  return (u32)f2bf(a) | ((u32)f2bf(b) << 16);
}

// async 16B global -> LDS (dest = wave-uniform base + lane*16)
__device__ __forceinline__ void gload16(const void* g, void* l) {
  __builtin_amdgcn_global_load_lds(
      (const __attribute__((address_space(1))) u32*)g,
      (__attribute__((address_space(3))) u32*)l, 16, 0, 0);
}

// ---------------- weight transpose + cast: out[n][k] = bf16(in[k][n]) ----------------
__global__ __launch_bounds__(256) void wtrans_kern(
    const float* __restrict__ in, u16* __restrict__ out, int K, int N, long inz, long outz)
{
  in += (long)blockIdx.z * inz; out += (long)blockIdx.z * outz;
  __shared__ float T[32][33];
  const int n0 = blockIdx.x * 32, k0 = blockIdx.y * 32;
  const int c = threadIdx.x & 31, r8 = threadIdx.x >> 5;
  #pragma unroll
  for (int i = 0; i < 4; ++i)
    T[r8 + i * 8][c] = in[(long)(k0 + r8 + i * 8) * N + n0 + c];
  __syncthreads();
  #pragma unroll
  for (int i = 0; i < 4; ++i)
    out[(long)(n0 + r8 + i * 8) * K + k0 + c] = f2bf(T[c][r8 + i * 8]);
}

// ---------------- embedding + LN (fp32 h + bf16 hb) ----------------
__global__ __launch_bounds__(256) void embed_ln_kern(
    const int* __restrict__ ids, const int* __restrict__ tt,
    const float* __restrict__ we, const float* __restrict__ pe, const float* __restrict__ te,
    const float* __restrict__ g, const float* __restrict__ bb,
    float* __restrict__ h, u16* __restrict__ hb)
{
  __shared__ float sa[4], sb[4];
  const long i = blockIdx.x;
  const int tid = threadIdx.x;
  const int s = (int)(i & (S - 1));
  const long wo = (long)ids[i] * D;
  const long to = (long)tt[i] * D;
  const long po = (long)s * D;
  float x0 = we[wo + tid]       + pe[po + tid]       + te[to + tid];
  float x1 = we[wo + tid + 256] + pe[po + tid + 256] + te[to + tid + 256];
  float x2 = we[wo + tid + 512] + pe[po + tid + 512] + te[to + tid + 512];
  float sm = x0 + x1 + x2, sq = x0*x0 + x1*x1 + x2*x2;
  #pragma unroll
  for (int o = 32; o; o >>= 1) { sm += __shfl_xor(sm, o); sq += __shfl_xor(sq, o); }
  if ((tid & 63) == 0) { sa[tid >> 6] = sm; sb[tid >> 6] = sq; }
  __syncthreads();
  sm = sa[0] + sa[1] + sa[2] + sa[3];
  sq = sb[0] + sb[1] + sb[2] + sb[3];
  const float mean = sm * (1.f / D);
  const float var  = sq * (1.f / D) - mean * mean;
  const float rs   = rsqrtf(var + 1e-12f);
  float* row = h + i * D;
  u16* rb = hb + i * D;
  float y0 = (x0 - mean) * rs * g[tid]       + bb[tid];
  float y1 = (x1 - mean) * rs * g[tid + 256] + bb[tid + 256];
  float y2 = (x2 - mean) * rs * g[tid + 512] + bb[tid + 512];
  row[tid] = y0; row[tid + 256] = y1; row[tid + 512] = y2;
  rb[tid] = f2bf(y0); rb[tid + 256] = f2bf(y1); rb[tid + 512] = f2bf(y2);
}

// ---------------- in-place LayerNorm (fp32 h + bf16 hb) ----------------
__global__ __launch_bounds__(256) void ln_kern(
    float* __restrict__ h, const float* __restrict__ g, const float* __restrict__ bb,
    u16* __restrict__ hb)
{
  __shared__ float sa[4], sb[4];
  const long i = blockIdx.x;
  const int tid = threadIdx.x;
  float* row = h + i * D;
  u16* rb = hb + i * D;
  float x0 = row[tid], x1 = row[tid + 256], x2 = row[tid + 512];
  float sm = x0 + x1 + x2, sq = x0*x0 + x1*x1 + x2*x2;
  #pragma unroll
  for (int o = 32; o; o >>= 1) { sm += __shfl_xor(sm, o); sq += __shfl_xor(sq, o); }
  if ((tid & 63) == 0) { sa[tid >> 6] = sm; sb[tid >> 6] = sq; }
  __syncthreads();
  sm = sa[0] + sa[1] + sa[2] + sa[3];
  sq = sb[0] + sb[1] + sb[2] + sb[3];
  const float mean = sm * (1.f / D);
  const float var  = sq * (1.f / D) - mean * mean;
  const float rs   = rsqrtf(var + 1e-12f);
  float y0 = (x0 - mean) * rs * g[tid]       + bb[tid];
  float y1 = (x1 - mean) * rs * g[tid + 256] + bb[tid + 256];
  float y2 = (x2 - mean) * rs * g[tid + 512] + bb[tid + 512];
  row[tid] = y0; row[tid + 256] = y1; row[tid + 512] = y2;
  rb[tid] = f2bf(y0); rb[tid + 256] = f2bf(y1); rb[tid + 512] = f2bf(y2);
}

// ---------------- bf16 MFMA GEMM (global_load_lds staging, XOR-swizzled LDS) ----------
// C[M,N] = A[M,K]_bf16 @ Wt[N,K]_bf16^T + bias
// 128x128 tile, BK=64, 4 waves (2x2), 4x4 16x16x32 fragments per wave.
// XCD-chunked block swizzle (requires gridX*gridY % 8 == 0).
// mode 0: fp32 store; 1: gelu->bf16; 2: fp32 residual add (atomic if ksplit>1);
// mode 4: merged QKV (N=2304): t<2 natural bf16 [M,768]; t==2 V transposed [b,h,d,S].
// ksplit>1: blockIdx.z indexes a K-chunk of size K/ksplit (wz/bz/cz must be 0).
__global__ __launch_bounds__(256) void mgemm_kern(
    const u16* __restrict__ A, const u16* __restrict__ Wt,
    const float* __restrict__ bias, void* __restrict__ Cv,
    int N, int K, long wz, long bz, long cz, int mode, int ksplit)
{
  const int z = blockIdx.z;
  int k0 = 0, kend = K;
  if (ksplit > 1) {
    const int kch = K / ksplit;
    k0 = z * kch; kend = k0 + kch;
  } else {
    Wt += (long)z * wz; bias += (long)z * bz;
  }
  // XCD-aware chunked swizzle: each XCD owns a contiguous run of M-panels
  const int gx = gridDim.x;
  const int nwg = gx * gridDim.y;
  int bid = blockIdx.y * gx + blockIdx.x;
  bid = (bid & 7) * (nwg >> 3) + (bid >> 3);
  const long bm = (long)(bid / gx) * 128;
  const int bn = (bid % gx) * 128;

  const int tid = threadIdx.x;
  const int lane = tid & 63, w = tid >> 6;
  const int wm = w >> 1, wn = w & 1;
  const int ls = lane >> 4, lr = lane & 15;

  __shared__ u16 As[128][64];
  __shared__ u16 Bs[128][64];
  u16* AsL = &As[0][0];
  u16* BsL = &Bs[0][0];

  f32x4 acc[4][4];
  #pragma unroll
  for (int i = 0; i < 4; ++i)
    #pragma unroll
    for (int j = 0; j < 4; ++j)
      acc[i][j] = (f32x4){0.f, 0.f, 0.f, 0.f};

  for (int kk = k0; kk < kend; kk += 64) {
    __syncthreads();
    #pragma unroll
    for (int c = 0; c < 4; ++c) {
      const int n = (w * 4 + c) * 64 + lane;       // granule index 0..1023
      const int row = n >> 3;
      const int kc2 = (n & 7) ^ (row & 7);         // inverse-swizzled source column
      gload16(A  + (bm + row) * K + kk + kc2 * 8, AsL + (w * 4 + c) * 512);
      gload16(Wt + (long)(bn + row) * K + kk + kc2 * 8, BsL + (w * 4 + c) * 512);
    }
    __syncthreads();
    #pragma unroll
    for (int ks = 0; ks < 2; ++ks) {
      bf16x8 af[4], bv[4];
      const int kc = ks * 4 + ls;
      const int sw = (kc ^ (lr & 7)) << 3;
      #pragma unroll
      for (int mf = 0; mf < 4; ++mf)
        af[mf] = *(const bf16x8*)&AsL[(wm * 64 + mf * 16 + lr) * 64 + sw];
      #pragma unroll
      for (int nf = 0; nf < 4; ++nf)
        bv[nf] = *(const bf16x8*)&BsL[(wn * 64 + nf * 16 + lr) * 64 + sw];
      #pragma unroll
      for (int mf = 0; mf < 4; ++mf)
        #pragma unroll
        for (int nf = 0; nf < 4; ++nf)
          acc[mf][nf] = __builtin_amdgcn_mfma_f32_16x16x32_bf16(
              af[mf], bv[nf], acc[mf][nf], 0, 0, 0);
    }
  }

  float* Cf = (float*)Cv + (long)z * cz;
  u16*   Cu = (u16*)Cv  + (long)z * cz;
  const int r0 = ls * 4;
  const bool addb = (ksplit == 1) || (z == 0);

  if (mode == 4) {
    // merged QKV epilogue: col in [0,2304), t = col/768
    #pragma unroll
    for (int nf = 0; nf < 4; ++nf) {
      const int col = bn + wn * 64 + nf * 16 + lr;
      const int t = col / 768;
      const int cl = col - t * 768;
      const float bvv = bias[col];
      if (t < 2) {
        #pragma unroll
        for (int mf = 0; mf < 4; ++mf)
          #pragma unroll
          for (int r = 0; r < 4; ++r) {
            const long row = bm + wm * 64 + mf * 16 + r0 + r;
            Cu[(long)t * HD + row * D + cl] = f2bf(acc[mf][nf][r] + bvv);
          }
      } else {
        const int hcol = cl >> 6, dcol = cl & 63;
        #pragma unroll
        for (int mf = 0; mf < 4; ++mf) {
          const long t0 = bm + wm * 64 + mf * 16 + r0;
          const int bb2 = (int)(t0 >> 12), s0 = (int)(t0 & (S - 1));
          const float v0 = acc[mf][nf][0] + bvv, v1 = acc[mf][nf][1] + bvv;
          const float v2 = acc[mf][nf][2] + bvv, v3 = acc[mf][nf][3] + bvv;
          *(uint2*)(Cu + 2 * HD + (((long)bb2 * H + hcol) * 64 + dcol) * S + s0) =
              make_uint2(pack2(v0, v1), pack2(v2, v3));
        }
      }
    }
    return;
  }

  #pragma unroll
  for (int nf = 0; nf < 4; ++nf) {
    const int col = bn + wn * 64 + nf * 16 + lr;
    const float bvv = addb ? bias[col] : 0.f;
    #pragma unroll
    for (int mf = 0; mf < 4; ++mf) {
      #pragma unroll
      for (int r = 0; r < 4; ++r) {
        const long row = bm + wm * 64 + mf * 16 + r0 + r;
        float vv = acc[mf][nf][r] + bvv;
        if (mode == 1) {
          float u = 0.7978845608028654f * (vv + 0.044715f * vv * vv * vv);
          vv = 0.5f * vv * (1.f + tanhf(u));
          Cu[row * N + col] = f2bf(vv);
        } else if (mode == 2) {
          if (ksplit > 1) atomicAdd(&Cf[row * N + col], vv);
          else            Cf[row * N + col] += vv;
        } else {
          Cf[row * N + col] = vv;
        }
      }
    }
  }
}

// ---------------- MFMA block attention ----------------
__global__ __launch_bounds__(256) void mattn_kern(
    const u16* __restrict__ q, const u16* __restrict__ k, const u16* __restrict__ vt,
    const float* __restrict__ mask, const int* __restrict__ rb,
    u16* __restrict__ ctx, float* __restrict__ part, int dense)
{
  int qb, kv0, nkv, qb2 = 0, ch = 0;
  if (dense) {
    qb2 = blockIdx.x / NCH; ch = blockIdx.x % NCH;
    qb = qb2 ? NB - 1 : 0; kv0 = ch * (NB / NCH); nkv = NB / NCH;
  } else {
    qb = blockIdx.x;
    if (qb == 0 || qb == NB - 1) return;
    kv0 = 0; nkv = NKV;
  }
  const int hh = blockIdx.y, b = blockIdx.z;
  const int tid = threadIdx.x, lane = tid & 63, w = tid >> 6;
  const int lr = lane & 15, hi = lane >> 4;

  __shared__ u16 Ks[64][72];
  __shared__ u16 Vs[64][72];
  __shared__ u16 Ps[64][72];
  __shared__ float Ms[64];

  const long qrow0 = (long)b * S + qb * 64;
  bf16x8 qf[2];
  {
    const u16* qp = q + (qrow0 + w * 16 + lr) * D + hh * 64 + hi * 8;
    qf[0] = *(const bf16x8*)(qp);
    qf[1] = *(const bf16x8*)(qp + 32);
  }
  const long vtbase = (((long)b * H + hh) * 64) * S;

  f32x4 acc[4];
  #pragma unroll
  for (int nf = 0; nf < 4; ++nf) acc[nf] = (f32x4){0.f, 0.f, 0.f, 0.f};
  float m_run[4], l_run[4];
  #pragma unroll
  for (int r = 0; r < 4; ++r) { m_run[r] = -1e30f; l_run[r] = 0.f; }

  for (int jj = 0; jj < nkv; ++jj) {
    int kb;
    if (dense) kb = kv0 + jj;
    else if (jj < 3) kb = qb - 1 + jj;
    else if (jj == 3) kb = 0;
    else if (jj == 4) kb = NB - 1;
    else kb = rb[qb * 3 + (jj - 5)];

    const long krow0 = (long)b * S + kb * 64;
    __syncthreads();
    {
      int key = tid >> 3, kc = tid & 7;
      *(uint4*)&Ks[key][kc * 8] = *(const uint4*)(k + (krow0 + key) * D + hh * 64 + kc * 8);
      *(uint4*)&Vs[key][kc * 8] = *(const uint4*)(vt + vtbase + (long)key * S + kb * 64 + kc * 8);
      key = (tid + 256) >> 3;
      *(uint4*)&Ks[key][kc * 8] = *(const uint4*)(k + (krow0 + key) * D + hh * 64 + kc * 8);
      *(uint4*)&Vs[key][kc * 8] = *(const uint4*)(vt + vtbase + (long)key * S + kb * 64 + kc * 8);
      if (tid < 64) Ms[tid] = mask[krow0 + tid];
    }
    __syncthreads();

    f32x4 sc[4];
    #pragma unroll
    for (int kf = 0; kf < 4; ++kf) sc[kf] = (f32x4){0.f, 0.f, 0.f, 0.f};
    #pragma unroll
    for (int kc = 0; kc < 2; ++kc) {
      #pragma unroll
      for (int kf = 0; kf < 4; ++kf) {
        bf16x8 kfr = *(const bf16x8*)&Ks[kf * 16 + lr][kc * 32 + hi * 8];
        sc[kf] = __builtin_amdgcn_mfma_f32_16x16x32_bf16(qf[kc], kfr, sc[kf], 0, 0, 0);
      }
    }

    float mkk[4];
    #pragma unroll
    for (int kf = 0; kf < 4; ++kf) mkk[kf] = (Ms[kf * 16 + lr] - 1.f) * 1e9f;
    #pragma unroll
    for (int r = 0; r < 4; ++r) {
      float s0 = sc[0][r] * SCALE + mkk[0];
      float s1 = sc[1][r] * SCALE + mkk[1];
      float s2 = sc[2][r] * SCALE + mkk[2];
      float s3 = sc[3][r] * SCALE + mkk[3];
      float mx = fmaxf(fmaxf(s0, s1), fmaxf(s2, s3));
      mx = fmaxf(mx, __shfl_xor(mx, 1));
      mx = fmaxf(mx, __shfl_xor(mx, 2));
      mx = fmaxf(mx, __shfl_xor(mx, 4));
      mx = fmaxf(mx, __shfl_xor(mx, 8));
      const float mn = fmaxf(m_run[r], mx);
      const float al = __expf(m_run[r] - mn);
      float p0 = __expf(s0 - mn), p1 = __expf(s1 - mn);
      float p2 = __expf(s2 - mn), p3 = __expf(s3 - mn);
      float sum = p0 + p1 + p2 + p3;
      sum += __shfl_xor(sum, 1);
      sum += __shfl_xor(sum, 2);
      sum += __shfl_xor(sum, 4);
      sum += __shfl_xor(sum, 8);
      l_run[r] = l_run[r] * al + sum;
      m_run[r] = mn;
      acc[0][r] *= al; acc[1][r] *= al; acc[2][r] *= al; acc[3][r] *= al;
      const int prow = w * 16 + hi * 4 + r;
      Ps[prow][ 0 + lr] = f2bf(p0);
      Ps[prow][16 + lr] = f2bf(p1);
      Ps[prow][32 + lr] = f2bf(p2);
      Ps[prow][48 + lr] = f2bf(p3);
    }
    __syncthreads();

    #pragma unroll
    for (int kc = 0; kc < 2; ++kc) {
      bf16x8 pf = *(const bf16x8*)&Ps[w * 16 + lr][kc * 32 + hi * 8];
      #pragma unroll
      for (int nf = 0; nf < 4; ++nf) {
        bf16x8 vfr = *(const bf16x8*)&Vs[nf * 16 + lr][kc * 32 + hi * 8];
        acc[nf] = __builtin_amdgcn_mfma_f32_16x16x32_bf16(pf, vfr, acc[nf], 0, 0, 0);
      }
    }
  }

  if (!dense) {
    #pragma unroll
    for (int r = 0; r < 4; ++r) {
      const float inv = 1.f / l_run[r];
      u16* op = ctx + (qrow0 + w * 16 + hi * 4 + r) * D + hh * 64 + lr;
      op[ 0] = f2bf(acc[0][r] * inv);
      op[16] = f2bf(acc[1][r] * inv);
      op[32] = f2bf(acc[2][r] * inv);
      op[48] = f2bf(acc[3][r] * inv);
    }
  } else {
    const long pb = ((((long)b * H + hh) * 2 + qb2) * NCH + ch) * (64 * 68);
    #pragma unroll
    for (int r = 0; r < 4; ++r) {
      float* pp = part + pb + (w * 16 + hi * 4 + r) * 68;
      pp[ 0 + lr] = acc[0][r];
      pp[16 + lr] = acc[1][r];
      pp[32 + lr] = acc[2][r];
      pp[48 + lr] = acc[3][r];
      if (lr == 0) { pp[64] = m_run[r]; pp[65] = l_run[r]; }
    }
  }
}

// ---------------- combine dense split-K partials ----------------
__global__ __launch_bounds__(256) void attn_combine_kern(
    const float* __restrict__ part, u16* __restrict__ ctx)
{
  const int g = blockIdx.x;
  const int qb2 = g & 1;
  const int hh = (g >> 1) % H;
  const int b  = g / (2 * H);
  const int r  = threadIdx.x >> 2;
  const int d0 = (threadIdx.x & 3) * 16;
  const long pb = (long)g * NCH * 64 * 68;
  float mg = -1e30f;
  for (int ch = 0; ch < NCH; ++ch)
    mg = fmaxf(mg, part[pb + ch * 64 * 68 + r * 68 + 64]);
  float lg = 0.f;
  float a[16] = {};
  for (int ch = 0; ch < NCH; ++ch) {
    const float* pp = part + pb + ch * 64 * 68 + r * 68;
    const float w = __expf(pp[64] - mg);
    lg += pp[65] * w;
    #pragma unroll
    for (int i = 0; i < 4; ++i) {
      float4 t4 = *(const float4*)(pp + d0 + i * 4);
      a[i*4+0] += t4.x * w; a[i*4+1] += t4.y * w; a[i*4+2] += t4.z * w; a[i*4+3] += t4.w * w;
    }
  }
  const int qb = qb2 ? NB - 1 : 0;
  const float inv = 1.f / lg;
  u16* op = ctx + ((long)b * S + qb * 64 + r) * D + hh * 64 + d0;
  #pragma unroll
  for (int i = 0; i < 4; ++i)
    *(uint2*)(op + i * 4) = make_uint2(pack2(a[i*4+0]*inv, a[i*4+1]*inv),
                                       pack2(a[i*4+2]*inv, a[i*4+3]*inv));
}

// ---------------- span mean-pool + head ----------------
__global__ __launch_bounds__(256) void span_head_kern(
    const float* __restrict__ h, const int* __restrict__ spans,
    const float* __restrict__ hw, const float* __restrict__ hb, float* __restrict__ out)
{
  __shared__ float s0[4], s1[4];
  const int bn = blockIdx.x;
  const int tid = threadIdx.x;
  const int st = spans[bn * 2], en = spans[bn * 2 + 1];
  const int b = bn >> 3;
  float a0 = 0.f, a1 = 0.f, a2 = 0.f;
  for (int s = st; s < en; ++s) {
    const float* row = h + ((long)b * S + s) * D;
    a0 += row[tid]; a1 += row[tid + 256]; a2 += row[tid + 512];
  }
  const float inv = 1.f / (float)(en - st);
  a0 *= inv; a1 *= inv; a2 *= inv;
  float p0 = a0 * hw[tid * 2]     + a1 * hw[(tid + 256) * 2]     + a2 * hw[(tid + 512) * 2];
  float p1 = a0 * hw[tid * 2 + 1] + a1 * hw[(tid + 256) * 2 + 1] + a2 * hw[(tid + 512) * 2 + 1];
  #pragma unroll
  for (int o = 32; o; o >>= 1) { p0 += __shfl_xor(p0, o); p1 += __shfl_xor(p1, o); }
  if ((tid & 63) == 0) { s0[tid >> 6] = p0; s1[tid >> 6] = p1; }
  __syncthreads();
  if (tid == 0) {
    out[bn * 2]     = s0[0] + s0[1] + s0[2] + s0[3] + hb[0];
    out[bn * 2 + 1] = s1[0] + s1[1] + s1[2] + s1[3] + hb[1];
  }
}

// ---------------- launcher ----------------
extern "C" void kernel_launch(void* const* d_in, const int* in_sizes, int n_in,
                              void* d_out, int out_size, void* d_ws, size_t ws_size,
                              hipStream_t stream) {
  const int*   input_ids  = (const int*)  d_in[0];
  const float* attn_mask  = (const float*)d_in[1];
  const int*   tok_type   = (const int*)  d_in[2];
  const int*   spans      = (const int*)  d_in[3];
  const int*   rand_blk   = (const int*)  d_in[4];
  const float* word_emb   = (const float*)d_in[5];
  const float* pos_emb    = (const float*)d_in[6];
  const float* type_emb   = (const float*)d_in[7];
  const float* emb_g      = (const float*)d_in[8];
  const float* emb_b      = (const float*)d_in[9];
  const float* qkv_w      = (const float*)d_in[10];
  const float* qkv_b      = (const float*)d_in[11];
  const float* aow        = (const float*)d_in[12];
  const float* aob        = (const float*)d_in[13];
  const float* ln1g       = (const float*)d_in[14];
  const float* ln1b       = (const float*)d_in[15];
  const float* ff1w       = (const float*)d_in[16];
  const float* ff1b       = (const float*)d_in[17];
  const float* ff2w       = (const float*)d_in[18];
  const float* ff2b       = (const float*)d_in[19];
  const float* ln2g       = (const float*)d_in[20];
  const float* ln2b       = (const float*)d_in[21];
  const float* headw      = (const float*)d_in[22];
  const float* headb      = (const float*)d_in[23];

  float* ws    = (float*)d_ws;
  float* h     = ws;                          // [M,D] fp32
  u16*   qkvb  = (u16*)(ws + HD);             // q,k bf16 [M,D]; vt [B,H,64,S]
  u16*   ffb   = (u16*)(ws + HD);             // [M,F] bf16 overlays qkv region
  u16*   ctx16 = (u16*)(ws + 3 * HD);         // [M,D] bf16
  u16*   hb    = (u16*)(ws + 3 * HD + HD/2);  // [M,D] bf16
  float* part  = ws + 4 * HD;                 // dense partials ~0.84M floats
  u16*   wb    = (u16*)(ws + 4 * HD + HD/4);  // bf16 weights 2*WL u16

  // ---- weight prep (bf16 transposed) ----
  for (int l = 0; l < 2; ++l) {
    u16* wl = wb + (long)l * WL;
    wtrans_kern<<<dim3(24, 24, 3), dim3(256), 0, stream>>>(
        qkv_w + (long)l * 3 * D * D, wl, D, D, (long)D * D, (long)D * D);
    wtrans_kern<<<dim3(24, 24, 1), dim3(256), 0, stream>>>(
        aow + (long)l * D * D, wl + WQ, D, D, 0, 0);
    wtrans_kern<<<dim3(96, 24, 1), dim3(256), 0, stream>>>(
        ff1w + (long)l * D * F, wl + WQ + WA, D, F, 0, 0);
    wtrans_kern<<<dim3(24, 96, 1), dim3(256), 0, stream>>>(
        ff2w + (long)l * F * D, wl + WQ + WA + W1, F, D, 0, 0);
  }

  embed_ln_kern<<<dim3(M), dim3(256), 0, stream>>>(
      input_ids, tok_type, word_emb, pos_emb, type_emb, emb_g, emb_b, h, hb);

  for (int l = 0; l < 2; ++l) {
    u16* wl = wb + (long)l * WL;
    // merged QKV projection (N=2304): q,k natural bf16; v transposed [b,h,d,S]
    mgemm_kern<<<dim3(18, 64, 1), dim3(256), 0, stream>>>(
        hb, wl, qkv_b + (long)l * 3 * D, qkvb, 2304, D, 0, 0, 0, 4, 1);
    // sparse block attention (MFMA)
    mattn_kern<<<dim3(NB, H, B), dim3(256), 0, stream>>>(
        qkvb, qkvb + HD, qkvb + 2 * HD, attn_mask, rand_blk, ctx16, part, 0);
    // dense attention for global query blocks, split-K
    mattn_kern<<<dim3(2 * NCH, H, B), dim3(256), 0, stream>>>(
        qkvb, qkvb + HD, qkvb + 2 * HD, attn_mask, rand_blk, ctx16, part, 1);
    attn_combine_kern<<<dim3(B * H * 2), dim3(256), 0, stream>>>(part, ctx16);
    // output projection + residual into h (split-K 2, atomic)
    mgemm_kern<<<dim3(6, 64, 2), dim3(256), 0, stream>>>(
        ctx16, wl + WQ, aob + (long)l * D, h, D, D, 0, 0, 0, 2, 2);
    ln_kern<<<dim3(M), dim3(256), 0, stream>>>(h, ln1g + (long)l * D, ln1b + (long)l * D, hb);
    // FFN
    mgemm_kern<<<dim3(24, 64, 1), dim3(256), 0, stream>>>(
        hb, wl + WQ + WA, ff1b + (long)l * F, ffb, F, D, 0, 0, 0, 1, 1);
    mgemm_kern<<<dim3(6, 64, 2), dim3(256), 0, stream>>>(
        ffb, wl + WQ + WA + W1, ff2b + (long)l * D, h, D, F, 0, 0, 0, 2, 2);
    ln_kern<<<dim3(M), dim3(256), 0, stream>>>(h, ln2g + (long)l * D, ln2b + (long)l * D, hb);
  }

  span_head_kern<<<dim3(B * NS), dim3(256), 0, stream>>>(h, spans, headw, headb, (float*)d_out);
}

// Round 7
// 797.432 us; speedup vs baseline: 7.5181x; 1.0761x over previous
//
#include <hip/hip_runtime.h>

// ---------------- constants ----------------
constexpr int B = 2, S = 4096, D = 768, H = 12, DH = 64, BLK = 64, NB = 64, NKV = 8;
constexpr int F = 3072, NS = 8, M = B * S;            // M = 8192 tokens
constexpr int NCH = 4;                                 // dense split-K chunks
constexpr float SCALE = 0.125f;                        // 1/sqrt(64)
constexpr long HD = (long)M * D;                       // 6291456 elems per [M,D] buffer

using u16 = unsigned short;
using u32 = unsigned int;
using bf16 = __bf16;
using bf16x8 = __attribute__((ext_vector_type(8))) bf16;
using f32x4 = __attribute__((ext_vector_type(4))) float;

// per-layer bf16 weight region (ushort counts)
constexpr long WQ = 3L * D * D;
constexpr long WA = (long)D * D;
constexpr long W1 = (long)D * F;
constexpr long WL = WQ + WA + W1 + W1;

__device__ __forceinline__ u16 f2bf(float x) {
  u32 u = __builtin_bit_cast(u32, x);
  u = (u + 0x7fffu + ((u >> 16) & 1u)) >> 16;
  return (u16)u;
}
__device__ __forceinline__ u32 pack2(float a, float b) {
  return (u32)f2bf(a) | ((u32)f2bf(b) << 16);
}
// fast tanh-gelu: 0.5x(1+tanh(u)) == x - x/(exp(2u)+1); inf-safe both tails
__device__ __forceinline__ float fast_gelu(float x) {
  float u = 0.7978845608028654f * (x + 0.044715f * x * x * x);
  float t = __expf(u + u);
  return x - x * __builtin_amdgcn_rcpf(t + 1.f);
}

// async 16B global -> LDS (dest = wave-uniform base + lane*16)
__device__ __forceinline__ void gload16(const void* g, void* l) {
  __builtin_amdgcn_global_load_lds(
      (const __attribute__((address_space(1))) u32*)g,
      (__attribute__((address_space(3))) u32*)l, 16, 0, 0);
}

// ---------------- weight transpose + cast: out[n][k] = bf16(in[k][n]) ----------------
__global__ __launch_bounds__(256) void wtrans_kern(
    const float* __restrict__ in, u16* __restrict__ out, int K, int N, long inz, long outz)
{
  in += (long)blockIdx.z * inz; out += (long)blockIdx.z * outz;
  __shared__ float T[32][33];
  const int n0 = blockIdx.x * 32, k0 = blockIdx.y * 32;
  const int c = threadIdx.x & 31, r8 = threadIdx.x >> 5;
  #pragma unroll
  for (int i = 0; i < 4; ++i)
    T[r8 + i * 8][c] = in[(long)(k0 + r8 + i * 8) * N + n0 + c];
  __syncthreads();
  #pragma unroll
  for (int i = 0; i < 4; ++i)
    out[(long)(n0 + r8 + i * 8) * K + k0 + c] = f2bf(T[c][r8 + i * 8]);
}

// ---------------- embedding + LN (fp32 h + bf16 hb) ----------------
__global__ __launch_bounds__(256) void embed_ln_kern(
    const int* __restrict__ ids, const int* __restrict__ tt,
    const float* __restrict__ we, const float* __restrict__ pe, const float* __restrict__ te,
    const float* __restrict__ g, const float* __restrict__ bb,
    float* __restrict__ h, u16* __restrict__ hb)
{
  __shared__ float sa[4], sb[4];
  const long i = blockIdx.x;
  const int tid = threadIdx.x;
  const int s = (int)(i & (S - 1));
  const long wo = (long)ids[i] * D;
  const long to = (long)tt[i] * D;
  const long po = (long)s * D;
  float x0 = we[wo + tid]       + pe[po + tid]       + te[to + tid];
  float x1 = we[wo + tid + 256] + pe[po + tid + 256] + te[to + tid + 256];
  float x2 = we[wo + tid + 512] + pe[po + tid + 512] + te[to + tid + 512];
  float sm = x0 + x1 + x2, sq = x0*x0 + x1*x1 + x2*x2;
  #pragma unroll
  for (int o = 32; o; o >>= 1) { sm += __shfl_xor(sm, o); sq += __shfl_xor(sq, o); }
  if ((tid & 63) == 0) { sa[tid >> 6] = sm; sb[tid >> 6] = sq; }
  __syncthreads();
  sm = sa[0] + sa[1] + sa[2] + sa[3];
  sq = sb[0] + sb[1] + sb[2] + sb[3];
  const float mean = sm * (1.f / D);
  const float var  = sq * (1.f / D) - mean * mean;
  const float rs   = rsqrtf(var + 1e-12f);
  float* row = h + i * D;
  u16* rb = hb + i * D;
  float y0 = (x0 - mean) * rs * g[tid]       + bb[tid];
  float y1 = (x1 - mean) * rs * g[tid + 256] + bb[tid + 256];
  float y2 = (x2 - mean) * rs * g[tid + 512] + bb[tid + 512];
  row[tid] = y0; row[tid + 256] = y1; row[tid + 512] = y2;
  rb[tid] = f2bf(y0); rb[tid + 256] = f2bf(y1); rb[tid + 512] = f2bf(y2);
}

// ---------------- in-place LayerNorm (fp32 h + bf16 hb) ----------------
__global__ __launch_bounds__(256) void ln_kern(
    float* __restrict__ h, const float* __restrict__ g, const float* __restrict__ bb,
    u16* __restrict__ hb)
{
  __shared__ float sa[4], sb[4];
  const long i = blockIdx.x;
  const int tid = threadIdx.x;
  float* row = h + i * D;
  u16* rb = hb + i * D;
  float x0 = row[tid], x1 = row[tid + 256], x2 = row[tid + 512];
  float sm = x0 + x1 + x2, sq = x0*x0 + x1*x1 + x2*x2;
  #pragma unroll
  for (int o = 32; o; o >>= 1) { sm += __shfl_xor(sm, o); sq += __shfl_xor(sq, o); }
  if ((tid & 63) == 0) { sa[tid >> 6] = sm; sb[tid >> 6] = sq; }
  __syncthreads();
  sm = sa[0] + sa[1] + sa[2] + sa[3];
  sq = sb[0] + sb[1] + sb[2] + sb[3];
  const float mean = sm * (1.f / D);
  const float var  = sq * (1.f / D) - mean * mean;
  const float rs   = rsqrtf(var + 1e-12f);
  float y0 = (x0 - mean) * rs * g[tid]       + bb[tid];
  float y1 = (x1 - mean) * rs * g[tid + 256] + bb[tid + 256];
  float y2 = (x2 - mean) * rs * g[tid + 512] + bb[tid + 512];
  row[tid] = y0; row[tid + 256] = y1; row[tid + 512] = y2;
  rb[tid] = f2bf(y0); rb[tid + 256] = f2bf(y1); rb[tid + 512] = f2bf(y2);
}

// ---------------- bf16 MFMA GEMM (global_load_lds staging, XOR-swizzled LDS) ----------
// C[M,N] = A[M,K]_bf16 @ Wt[N,K]_bf16^T + bias
// 128x128 tile, BK=64, 4 waves (2x2), 4x4 16x16x32 fragments per wave.
// XCD-chunked block swizzle (requires gridX*gridY % 8 == 0).
// mode 0: fp32 store; 1: fast-gelu -> bf16 coalesced store via LDS transpose;
// mode 2: fp32 residual add (atomic if ksplit>1);
// mode 4: merged QKV (N=2304): t<2 natural bf16 [M,768]; t==2 V transposed [b,h,d,S].
// ksplit>1: blockIdx.z indexes a K-chunk of size K/ksplit (wz/bz/cz must be 0).
__global__ __launch_bounds__(256) void mgemm_kern(
    const u16* __restrict__ A, const u16* __restrict__ Wt,
    const float* __restrict__ bias, void* __restrict__ Cv,
    int N, int K, long wz, long bz, long cz, int mode, int ksplit)
{
  const int z = blockIdx.z;
  int k0 = 0, kend = K;
  if (ksplit > 1) {
    const int kch = K / ksplit;
    k0 = z * kch; kend = k0 + kch;
  } else {
    Wt += (long)z * wz; bias += (long)z * bz;
  }
  // XCD-aware chunked swizzle: each XCD owns a contiguous run of M-panels
  const int gx = gridDim.x;
  const int nwg = gx * gridDim.y;
  int bid = blockIdx.y * gx + blockIdx.x;
  bid = (bid & 7) * (nwg >> 3) + (bid >> 3);
  const long bm = (long)(bid / gx) * 128;
  const int bn = (bid % gx) * 128;

  const int tid = threadIdx.x;
  const int lane = tid & 63, w = tid >> 6;
  const int wm = w >> 1, wn = w & 1;
  const int ls = lane >> 4, lr = lane & 15;

  __shared__ u16 LB[16384];          // 32 KB: staging (A half + B half), epilogue transpose
  u16* AsL = LB;
  u16* BsL = LB + 8192;

  f32x4 acc[4][4];
  #pragma unroll
  for (int i = 0; i < 4; ++i)
    #pragma unroll
    for (int j = 0; j < 4; ++j)
      acc[i][j] = (f32x4){0.f, 0.f, 0.f, 0.f};

  for (int kk = k0; kk < kend; kk += 64) {
    __syncthreads();
    #pragma unroll
    for (int c = 0; c < 4; ++c) {
      const int n = (w * 4 + c) * 64 + lane;       // granule index 0..1023
      const int row = n >> 3;
      const int kc2 = (n & 7) ^ (row & 7);         // inverse-swizzled source column
      gload16(A  + (bm + row) * K + kk + kc2 * 8, AsL + (w * 4 + c) * 512);
      gload16(Wt + (long)(bn + row) * K + kk + kc2 * 8, BsL + (w * 4 + c) * 512);
    }
    __syncthreads();
    #pragma unroll
    for (int ks = 0; ks < 2; ++ks) {
      bf16x8 af[4], bv[4];
      const int kc = ks * 4 + ls;
      const int sw = (kc ^ (lr & 7)) << 3;
      #pragma unroll
      for (int mf = 0; mf < 4; ++mf)
        af[mf] = *(const bf16x8*)&AsL[(wm * 64 + mf * 16 + lr) * 64 + sw];
      #pragma unroll
      for (int nf = 0; nf < 4; ++nf)
        bv[nf] = *(const bf16x8*)&BsL[(wn * 64 + nf * 16 + lr) * 64 + sw];
      #pragma unroll
      for (int mf = 0; mf < 4; ++mf)
        #pragma unroll
        for (int nf = 0; nf < 4; ++nf)
          acc[mf][nf] = __builtin_amdgcn_mfma_f32_16x16x32_bf16(
              af[mf], bv[nf], acc[mf][nf], 0, 0, 0);
    }
  }

  float* Cf = (float*)Cv + (long)z * cz;
  u16*   Cu = (u16*)Cv  + (long)z * cz;
  const int r0 = ls * 4;
  const bool addb = (ksplit == 1) || (z == 0);

  if (mode == 1) {
    // fast-gelu + bf16, coalesced via LDS transpose (reuse LB as [128][128] u16)
    __syncthreads();                          // all LDS frag reads done
    #pragma unroll
    for (int nf = 0; nf < 4; ++nf) {
      const int col = wn * 64 + nf * 16 + lr;
      const float bvv = bias[bn + col];
      #pragma unroll
      for (int mf = 0; mf < 4; ++mf) {
        #pragma unroll
        for (int r = 0; r < 4; ++r) {
          const int rowl = wm * 64 + mf * 16 + r0 + r;
          float vv = fast_gelu(acc[mf][nf][r] + bvv);
          LB[rowl * 128 + (col ^ ((rowl & 7) << 3))] = f2bf(vv);
        }
      }
    }
    __syncthreads();
    const int c0 = (tid & 15) * 8;
    #pragma unroll
    for (int i = 0; i < 8; ++i) {
      const int gr = (tid >> 4) + i * 16;
      uint4 v4 = *(const uint4*)&LB[gr * 128 + (c0 ^ ((gr & 7) << 3))];
      *(uint4*)(Cu + (bm + gr) * N + bn + c0) = v4;
    }
    return;
  }

  if (mode == 4) {
    // merged QKV epilogue: col in [0,2304), t = col/768
    #pragma unroll
    for (int nf = 0; nf < 4; ++nf) {
      const int col = bn + wn * 64 + nf * 16 + lr;
      const int t = col / 768;
      const int cl = col - t * 768;
      const float bvv = bias[col];
      if (t < 2) {
        #pragma unroll
        for (int mf = 0; mf < 4; ++mf)
          #pragma unroll
          for (int r = 0; r < 4; ++r) {
            const long row = bm + wm * 64 + mf * 16 + r0 + r;
            Cu[(long)t * HD + row * D + cl] = f2bf(acc[mf][nf][r] + bvv);
          }
      } else {
        const int hcol = cl >> 6, dcol = cl & 63;
        #pragma unroll
        for (int mf = 0; mf < 4; ++mf) {
          const long t0 = bm + wm * 64 + mf * 16 + r0;
          const int bb2 = (int)(t0 >> 12), s0 = (int)(t0 & (S - 1));
          const float v0 = acc[mf][nf][0] + bvv, v1 = acc[mf][nf][1] + bvv;
          const float v2 = acc[mf][nf][2] + bvv, v3 = acc[mf][nf][3] + bvv;
          *(uint2*)(Cu + 2 * HD + (((long)bb2 * H + hcol) * 64 + dcol) * S + s0) =
              make_uint2(pack2(v0, v1), pack2(v2, v3));
        }
      }
    }
    return;
  }

  #pragma unroll
  for (int nf = 0; nf < 4; ++nf) {
    const int col = bn + wn * 64 + nf * 16 + lr;
    const float bvv = addb ? bias[col] : 0.f;
    #pragma unroll
    for (int mf = 0; mf < 4; ++mf) {
      #pragma unroll
      for (int r = 0; r < 4; ++r) {
        const long row = bm + wm * 64 + mf * 16 + r0 + r;
        float vv = acc[mf][nf][r] + bvv;
        if (mode == 2) {
          if (ksplit > 1) atomicAdd(&Cf[row * N + col], vv);
          else            Cf[row * N + col] += vv;
        } else {
          Cf[row * N + col] = vv;
        }
      }
    }
  }
}

// ---------------- MFMA block attention ----------------
__global__ __launch_bounds__(256) void mattn_kern(
    const u16* __restrict__ q, const u16* __restrict__ k, const u16* __restrict__ vt,
    const float* __restrict__ mask, const int* __restrict__ rb,
    u16* __restrict__ ctx, float* __restrict__ part, int dense)
{
  int qb, kv0, nkv, qb2 = 0, ch = 0;
  if (dense) {
    qb2 = blockIdx.x / NCH; ch = blockIdx.x % NCH;
    qb = qb2 ? NB - 1 : 0; kv0 = ch * (NB / NCH); nkv = NB / NCH;
  } else {
    qb = blockIdx.x;
    if (qb == 0 || qb == NB - 1) return;
    kv0 = 0; nkv = NKV;
  }
  const int hh = blockIdx.y, b = blockIdx.z;
  const int tid = threadIdx.x, lane = tid & 63, w = tid >> 6;
  const int lr = lane & 15, hi = lane >> 4;

  __shared__ u16 Ks[64][72];
  __shared__ u16 Vs[64][72];
  __shared__ u16 Ps[64][72];
  __shared__ float Ms[64];

  const long qrow0 = (long)b * S + qb * 64;
  bf16x8 qf[2];
  {
    const u16* qp = q + (qrow0 + w * 16 + lr) * D + hh * 64 + hi * 8;
    qf[0] = *(const bf16x8*)(qp);
    qf[1] = *(const bf16x8*)(qp + 32);
  }
  const long vtbase = (((long)b * H + hh) * 64) * S;

  f32x4 acc[4];
  #pragma unroll
  for (int nf = 0; nf < 4; ++nf) acc[nf] = (f32x4){0.f, 0.f, 0.f, 0.f};
  float m_run[4], l_run[4];
  #pragma unroll
  for (int r = 0; r < 4; ++r) { m_run[r] = -1e30f; l_run[r] = 0.f; }

  for (int jj = 0; jj < nkv; ++jj) {
    int kb;
    if (dense) kb = kv0 + jj;
    else if (jj < 3) kb = qb - 1 + jj;
    else if (jj == 3) kb = 0;
    else if (jj == 4) kb = NB - 1;
    else kb = rb[qb * 3 + (jj - 5)];

    const long krow0 = (long)b * S + kb * 64;
    __syncthreads();
    {
      int key = tid >> 3, kc = tid & 7;
      *(uint4*)&Ks[key][kc * 8] = *(const uint4*)(k + (krow0 + key) * D + hh * 64 + kc * 8);
      *(uint4*)&Vs[key][kc * 8] = *(const uint4*)(vt + vtbase + (long)key * S + kb * 64 + kc * 8);
      key = (tid + 256) >> 3;
      *(uint4*)&Ks[key][kc * 8] = *(const uint4*)(k + (krow0 + key) * D + hh * 64 + kc * 8);
      *(uint4*)&Vs[key][kc * 8] = *(const uint4*)(vt + vtbase + (long)key * S + kb * 64 + kc * 8);
      if (tid < 64) Ms[tid] = mask[krow0 + tid];
    }
    __syncthreads();

    f32x4 sc[4];
    #pragma unroll
    for (int kf = 0; kf < 4; ++kf) sc[kf] = (f32x4){0.f, 0.f, 0.f, 0.f};
    __builtin_amdgcn_s_setprio(1);
    #pragma unroll
    for (int kc = 0; kc < 2; ++kc) {
      #pragma unroll
      for (int kf = 0; kf < 4; ++kf) {
        bf16x8 kfr = *(const bf16x8*)&Ks[kf * 16 + lr][kc * 32 + hi * 8];
        sc[kf] = __builtin_amdgcn_mfma_f32_16x16x32_bf16(qf[kc], kfr, sc[kf], 0, 0, 0);
      }
    }
    __builtin_amdgcn_s_setprio(0);

    float mkk[4];
    #pragma unroll
    for (int kf = 0; kf < 4; ++kf) mkk[kf] = (Ms[kf * 16 + lr] - 1.f) * 1e9f;
    #pragma unroll
    for (int r = 0; r < 4; ++r) {
      float s0 = sc[0][r] * SCALE + mkk[0];
      float s1 = sc[1][r] * SCALE + mkk[1];
      float s2 = sc[2][r] * SCALE + mkk[2];
      float s3 = sc[3][r] * SCALE + mkk[3];
      float mx = fmaxf(fmaxf(s0, s1), fmaxf(s2, s3));
      mx = fmaxf(mx, __shfl_xor(mx, 1));
      mx = fmaxf(mx, __shfl_xor(mx, 2));
      mx = fmaxf(mx, __shfl_xor(mx, 4));
      mx = fmaxf(mx, __shfl_xor(mx, 8));
      const float mn = fmaxf(m_run[r], mx);
      const float al = __expf(m_run[r] - mn);
      float p0 = __expf(s0 - mn), p1 = __expf(s1 - mn);
      float p2 = __expf(s2 - mn), p3 = __expf(s3 - mn);
      float sum = p0 + p1 + p2 + p3;
      sum += __shfl_xor(sum, 1);
      sum += __shfl_xor(sum, 2);
      sum += __shfl_xor(sum, 4);
      sum += __shfl_xor(sum, 8);
      l_run[r] = l_run[r] * al + sum;
      m_run[r] = mn;
      acc[0][r] *= al; acc[1][r] *= al; acc[2][r] *= al; acc[3][r] *= al;
      const int prow = w * 16 + hi * 4 + r;
      Ps[prow][ 0 + lr] = f2bf(p0);
      Ps[prow][16 + lr] = f2bf(p1);
      Ps[prow][32 + lr] = f2bf(p2);
      Ps[prow][48 + lr] = f2bf(p3);
    }
    __syncthreads();

    __builtin_amdgcn_s_setprio(1);
    #pragma unroll
    for (int kc = 0; kc < 2; ++kc) {
      bf16x8 pf = *(const bf16x8*)&Ps[w * 16 + lr][kc * 32 + hi * 8];
      #pragma unroll
      for (int nf = 0; nf < 4; ++nf) {
        bf16x8 vfr = *(const bf16x8*)&Vs[nf * 16 + lr][kc * 32 + hi * 8];
        acc[nf] = __builtin_amdgcn_mfma_f32_16x16x32_bf16(pf, vfr, acc[nf], 0, 0, 0);
      }
    }
    __builtin_amdgcn_s_setprio(0);
  }

  if (!dense) {
    #pragma unroll
    for (int r = 0; r < 4; ++r) {
      const float inv = 1.f / l_run[r];
      u16* op = ctx + (qrow0 + w * 16 + hi * 4 + r) * D + hh * 64 + lr;
      op[ 0] = f2bf(acc[0][r] * inv);
      op[16] = f2bf(acc[1][r] * inv);
      op[32] = f2bf(acc[2][r] * inv);
      op[48] = f2bf(acc[3][r] * inv);
    }
  } else {
    const long pb = ((((long)b * H + hh) * 2 + qb2) * NCH + ch) * (64 * 68);
    #pragma unroll
    for (int r = 0; r < 4; ++r) {
      float* pp = part + pb + (w * 16 + hi * 4 + r) * 68;
      pp[ 0 + lr] = acc[0][r];
      pp[16 + lr] = acc[1][r];
      pp[32 + lr] = acc[2][r];
      pp[48 + lr] = acc[3][r];
      if (lr == 0) { pp[64] = m_run[r]; pp[65] = l_run[r]; }
    }
  }
}

// ---------------- combine dense split-K partials ----------------
__global__ __launch_bounds__(256) void attn_combine_kern(
    const float* __restrict__ part, u16* __restrict__ ctx)
{
  const int g = blockIdx.x;
  const int qb2 = g & 1;
  const int hh = (g >> 1) % H;
  const int b  = g / (2 * H);
  const int r  = threadIdx.x >> 2;
  const int d0 = (threadIdx.x & 3) * 16;
  const long pb = (long)g * NCH * 64 * 68;
  float mg = -1e30f;
  for (int ch = 0; ch < NCH; ++ch)
    mg = fmaxf(mg, part[pb + ch * 64 * 68 + r * 68 + 64]);
  float lg = 0.f;
  float a[16] = {};
  for (int ch = 0; ch < NCH; ++ch) {
    const float* pp = part + pb + ch * 64 * 68 + r * 68;
    const float w = __expf(pp[64] - mg);
    lg += pp[65] * w;
    #pragma unroll
    for (int i = 0; i < 4; ++i) {
      float4 t4 = *(const float4*)(pp + d0 + i * 4);
      a[i*4+0] += t4.x * w; a[i*4+1] += t4.y * w; a[i*4+2] += t4.z * w; a[i*4+3] += t4.w * w;
    }
  }
  const int qb = qb2 ? NB - 1 : 0;
  const float inv = 1.f / lg;
  u16* op = ctx + ((long)b * S + qb * 64 + r) * D + hh * 64 + d0;
  #pragma unroll
  for (int i = 0; i < 4; ++i)
    *(uint2*)(op + i * 4) = make_uint2(pack2(a[i*4+0]*inv, a[i*4+1]*inv),
                                       pack2(a[i*4+2]*inv, a[i*4+3]*inv));
}

// ---------------- span mean-pool + head ----------------
__global__ __launch_bounds__(256) void span_head_kern(
    const float* __restrict__ h, const int* __restrict__ spans,
    const float* __restrict__ hw, const float* __restrict__ hb, float* __restrict__ out)
{
  __shared__ float s0[4], s1[4];
  const int bn = blockIdx.x;
  const int tid = threadIdx.x;
  const int st = spans[bn * 2], en = spans[bn * 2 + 1];
  const int b = bn >> 3;
  float a0 = 0.f, a1 = 0.f, a2 = 0.f;
  for (int s = st; s < en; ++s) {
    const float* row = h + ((long)b * S + s) * D;
    a0 += row[tid]; a1 += row[tid + 256]; a2 += row[tid + 512];
  }
  const float inv = 1.f / (float)(en - st);
  a0 *= inv; a1 *= inv; a2 *= inv;
  float p0 = a0 * hw[tid * 2]     + a1 * hw[(tid + 256) * 2]     + a2 * hw[(tid + 512) * 2];
  float p1 = a0 * hw[tid * 2 + 1] + a1 * hw[(tid + 256) * 2 + 1] + a2 * hw[(tid + 512) * 2 + 1];
  #pragma unroll
  for (int o = 32; o; o >>= 1) { p0 += __shfl_xor(p0, o); p1 += __shfl_xor(p1, o); }
  if ((tid & 63) == 0) { s0[tid >> 6] = p0; s1[tid >> 6] = p1; }
  __syncthreads();
  if (tid == 0) {
    out[bn * 2]     = s0[0] + s0[1] + s0[2] + s0[3] + hb[0];
    out[bn * 2 + 1] = s1[0] + s1[1] + s1[2] + s1[3] + hb[1];
  }
}

// ---------------- launcher ----------------
extern "C" void kernel_launch(void* const* d_in, const int* in_sizes, int n_in,
                              void* d_out, int out_size, void* d_ws, size_t ws_size,
                              hipStream_t stream) {
  const int*   input_ids  = (const int*)  d_in[0];
  const float* attn_mask  = (const float*)d_in[1];
  const int*   tok_type   = (const int*)  d_in[2];
  const int*   spans      = (const int*)  d_in[3];
  const int*   rand_blk   = (const int*)  d_in[4];
  const float* word_emb   = (const float*)d_in[5];
  const float* pos_emb    = (const float*)d_in[6];
  const float* type_emb   = (const float*)d_in[7];
  const float* emb_g      = (const float*)d_in[8];
  const float* emb_b      = (const float*)d_in[9];
  const float* qkv_w      = (const float*)d_in[10];
  const float* qkv_b      = (const float*)d_in[11];
  const float* aow        = (const float*)d_in[12];
  const float* aob        = (const float*)d_in[13];
  const float* ln1g       = (const float*)d_in[14];
  const float* ln1b       = (const float*)d_in[15];
  const float* ff1w       = (const float*)d_in[16];
  const float* ff1b       = (const float*)d_in[17];
  const float* ff2w       = (const float*)d_in[18];
  const float* ff2b       = (const float*)d_in[19];
  const float* ln2g       = (const float*)d_in[20];
  const float* ln2b       = (const float*)d_in[21];
  const float* headw      = (const float*)d_in[22];
  const float* headb      = (const float*)d_in[23];

  float* ws    = (float*)d_ws;
  float* h     = ws;                          // [M,D] fp32
  u16*   qkvb  = (u16*)(ws + HD);             // q,k bf16 [M,D]; vt [B,H,64,S]
  u16*   ffb   = (u16*)(ws + HD);             // [M,F] bf16 overlays qkv region
  u16*   ctx16 = (u16*)(ws + 3 * HD);         // [M,D] bf16
  u16*   hb    = (u16*)(ws + 3 * HD + HD/2);  // [M,D] bf16
  float* part  = ws + 4 * HD;                 // dense partials ~0.84M floats
  u16*   wb    = (u16*)(ws + 4 * HD + HD/4);  // bf16 weights 2*WL u16

  // ---- weight prep (bf16 transposed) ----
  for (int l = 0; l < 2; ++l) {
    u16* wl = wb + (long)l * WL;
    wtrans_kern<<<dim3(24, 24, 3), dim3(256), 0, stream>>>(
        qkv_w + (long)l * 3 * D * D, wl, D, D, (long)D * D, (long)D * D);
    wtrans_kern<<<dim3(24, 24, 1), dim3(256), 0, stream>>>(
        aow + (long)l * D * D, wl + WQ, D, D, 0, 0);
    wtrans_kern<<<dim3(96, 24, 1), dim3(256), 0, stream>>>(
        ff1w + (long)l * D * F, wl + WQ + WA, D, F, 0, 0);
    wtrans_kern<<<dim3(24, 96, 1), dim3(256), 0, stream>>>(
        ff2w + (long)l * F * D, wl + WQ + WA + W1, F, D, 0, 0);
  }

  embed_ln_kern<<<dim3(M), dim3(256), 0, stream>>>(
      input_ids, tok_type, word_emb, pos_emb, type_emb, emb_g, emb_b, h, hb);

  for (int l = 0; l < 2; ++l) {
    u16* wl = wb + (long)l * WL;
    // merged QKV projection (N=2304): q,k natural bf16; v transposed [b,h,d,S]
    mgemm_kern<<<dim3(18, 64, 1), dim3(256), 0, stream>>>(
        hb, wl, qkv_b + (long)l * 3 * D, qkvb, 2304, D, 0, 0, 0, 4, 1);
    // sparse block attention (MFMA)
    mattn_kern<<<dim3(NB, H, B), dim3(256), 0, stream>>>(
        qkvb, qkvb + HD, qkvb + 2 * HD, attn_mask, rand_blk, ctx16, part, 0);
    // dense attention for global query blocks, split-K
    mattn_kern<<<dim3(2 * NCH, H, B), dim3(256), 0, stream>>>(
        qkvb, qkvb + HD, qkvb + 2 * HD, attn_mask, rand_blk, ctx16, part, 1);
    attn_combine_kern<<<dim3(B * H * 2), dim3(256), 0, stream>>>(part, ctx16);
    // output projection + residual into h (split-K 2, atomic)
    mgemm_kern<<<dim3(6, 64, 2), dim3(256), 0, stream>>>(
        ctx16, wl + WQ, aob + (long)l * D, h, D, D, 0, 0, 0, 2, 2);
    ln_kern<<<dim3(M), dim3(256), 0, stream>>>(h, ln1g + (long)l * D, ln1b + (long)l * D, hb);
    // FFN
    mgemm_kern<<<dim3(24, 64, 1), dim3(256), 0, stream>>>(
        hb, wl + WQ + WA, ff1b + (long)l * F, ffb, F, D, 0, 0, 0, 1, 1);
    mgemm_kern<<<dim3(6, 64, 2), dim3(256), 0, stream>>>(
        ffb, wl + WQ + WA + W1, ff2b + (long)l * D, h, D, F, 0, 0, 0, 2, 2);
    ln_kern<<<dim3(M), dim3(256), 0, stream>>>(h, ln2g + (long)l * D, ln2b + (long)l * D, hb);
  }

  span_head_kern<<<dim3(B * NS), dim3(256), 0, stream>>>(h, spans, headw, headb, (float*)d_out);
}

// Round 8
// 758.260 us; speedup vs baseline: 7.9064x; 1.0517x over previous
//
#include <hip/hip_runtime.h>

// ---------------- constants ----------------
constexpr int B = 2, S = 4096, D = 768, H = 12, DH = 64, BLK = 64, NB = 64, NKV = 8;
constexpr int F = 3072, NS = 8, M = B * S;            // M = 8192 tokens
constexpr int NCH = 4;                                 // dense split-K chunks
constexpr float SCALE = 0.125f;                        // 1/sqrt(64)
constexpr long HD = (long)M * D;                       // 6291456 elems per [M,D] buffer

using u16 = unsigned short;
using u32 = unsigned int;
using bf16 = __bf16;
using bf16x8 = __attribute__((ext_vector_type(8))) bf16;
using f32x4 = __attribute__((ext_vector_type(4))) float;

// per-layer bf16 weight region (ushort counts)
constexpr long WQ = 3L * D * D;
constexpr long WA = (long)D * D;
constexpr long W1 = (long)D * F;
constexpr long WL = WQ + WA + W1 + W1;

__device__ __forceinline__ u16 f2bf(float x) {
  u32 u = __builtin_bit_cast(u32, x);
  u = (u + 0x7fffu + ((u >> 16) & 1u)) >> 16;
  return (u16)u;
}
__device__ __forceinline__ u32 pack2(float a, float b) {
  return (u32)f2bf(a) | ((u32)f2bf(b) << 16);
}
// fast tanh-gelu: 0.5x(1+tanh(u)) == x - x/(exp(2u)+1); inf-safe both tails
__device__ __forceinline__ float fast_gelu(float x) {
  float u = 0.7978845608028654f * (x + 0.044715f * x * x * x);
  float t = __expf(u + u);
  return x - x * __builtin_amdgcn_rcpf(t + 1.f);
}

// async 16B global -> LDS (dest = wave-uniform base + lane*16)
__device__ __forceinline__ void gload16(const void* g, void* l) {
  __builtin_amdgcn_global_load_lds(
      (const __attribute__((address_space(1))) u32*)g,
      (__attribute__((address_space(3))) u32*)l, 16, 0, 0);
}

// ---------------- weight transpose + cast: out[n][k] = bf16(in[k][n]) ----------------
__global__ __launch_bounds__(256) void wtrans_kern(
    const float* __restrict__ in, u16* __restrict__ out, int K, int N, long inz, long outz)
{
  in += (long)blockIdx.z * inz; out += (long)blockIdx.z * outz;
  __shared__ float T[32][33];
  const int n0 = blockIdx.x * 32, k0 = blockIdx.y * 32;
  const int c = threadIdx.x & 31, r8 = threadIdx.x >> 5;
  #pragma unroll
  for (int i = 0; i < 4; ++i)
    T[r8 + i * 8][c] = in[(long)(k0 + r8 + i * 8) * N + n0 + c];
  __syncthreads();
  #pragma unroll
  for (int i = 0; i < 4; ++i)
    out[(long)(n0 + r8 + i * 8) * K + k0 + c] = f2bf(T[c][r8 + i * 8]);
}

// ---------------- embedding + LN (fp32 h + bf16 hb) ----------------
__global__ __launch_bounds__(256) void embed_ln_kern(
    const int* __restrict__ ids, const int* __restrict__ tt,
    const float* __restrict__ we, const float* __restrict__ pe, const float* __restrict__ te,
    const float* __restrict__ g, const float* __restrict__ bb,
    float* __restrict__ h, u16* __restrict__ hb)
{
  __shared__ float sa[4], sb[4];
  const long i = blockIdx.x;
  const int tid = threadIdx.x;
  const int s = (int)(i & (S - 1));
  const long wo = (long)ids[i] * D;
  const long to = (long)tt[i] * D;
  const long po = (long)s * D;
  float x0 = we[wo + tid]       + pe[po + tid]       + te[to + tid];
  float x1 = we[wo + tid + 256] + pe[po + tid + 256] + te[to + tid + 256];
  float x2 = we[wo + tid + 512] + pe[po + tid + 512] + te[to + tid + 512];
  float sm = x0 + x1 + x2, sq = x0*x0 + x1*x1 + x2*x2;
  #pragma unroll
  for (int o = 32; o; o >>= 1) { sm += __shfl_xor(sm, o); sq += __shfl_xor(sq, o); }
  if ((tid & 63) == 0) { sa[tid >> 6] = sm; sb[tid >> 6] = sq; }
  __syncthreads();
  sm = sa[0] + sa[1] + sa[2] + sa[3];
  sq = sb[0] + sb[1] + sb[2] + sb[3];
  const float mean = sm * (1.f / D);
  const float var  = sq * (1.f / D) - mean * mean;
  const float rs   = rsqrtf(var + 1e-12f);
  float* row = h + i * D;
  u16* rb = hb + i * D;
  float y0 = (x0 - mean) * rs * g[tid]       + bb[tid];
  float y1 = (x1 - mean) * rs * g[tid + 256] + bb[tid + 256];
  float y2 = (x2 - mean) * rs * g[tid + 512] + bb[tid + 512];
  row[tid] = y0; row[tid + 256] = y1; row[tid + 512] = y2;
  rb[tid] = f2bf(y0); rb[tid + 256] = f2bf(y1); rb[tid + 512] = f2bf(y2);
}

// ---------------- in-place LayerNorm (fp32 h + bf16 hb) ----------------
__global__ __launch_bounds__(256) void ln_kern(
    float* __restrict__ h, const float* __restrict__ g, const float* __restrict__ bb,
    u16* __restrict__ hb)
{
  __shared__ float sa[4], sb[4];
  const long i = blockIdx.x;
  const int tid = threadIdx.x;
  float* row = h + i * D;
  u16* rb = hb + i * D;
  float x0 = row[tid], x1 = row[tid + 256], x2 = row[tid + 512];
  float sm = x0 + x1 + x2, sq = x0*x0 + x1*x1 + x2*x2;
  #pragma unroll
  for (int o = 32; o; o >>= 1) { sm += __shfl_xor(sm, o); sq += __shfl_xor(sq, o); }
  if ((tid & 63) == 0) { sa[tid >> 6] = sm; sb[tid >> 6] = sq; }
  __syncthreads();
  sm = sa[0] + sa[1] + sa[2] + sa[3];
  sq = sb[0] + sb[1] + sb[2] + sb[3];
  const float mean = sm * (1.f / D);
  const float var  = sq * (1.f / D) - mean * mean;
  const float rs   = rsqrtf(var + 1e-12f);
  float y0 = (x0 - mean) * rs * g[tid]       + bb[tid];
  float y1 = (x1 - mean) * rs * g[tid + 256] + bb[tid + 256];
  float y2 = (x2 - mean) * rs * g[tid + 512] + bb[tid + 512];
  row[tid] = y0; row[tid + 256] = y1; row[tid + 512] = y2;
  rb[tid] = f2bf(y0); rb[tid + 256] = f2bf(y1); rb[tid + 512] = f2bf(y2);
}

// ---------------- bf16 MFMA GEMM: 2-phase double-buffered global_load_lds pipeline ----
// C[M,N] = A[M,K]_bf16 @ Wt[N,K]_bf16^T + bias
// 128x128 tile, BK=64, 4 waves (2x2), 4x4 16x16x32 fragments per wave.
// LDS: two 32KB stages (A+B each); stage t+1 issued before computing t; ONE barrier/iter.
// XCD-chunked block swizzle (requires gridX*gridY % 8 == 0).
// mode 0: fp32 store; 1: fast-gelu -> bf16 coalesced store via LDS transpose;
// mode 2: fp32 residual add (atomic if ksplit>1);
// mode 4: merged QKV (N=2304): t=bn/768 uniform; t<2 coalesced bf16 [M,768];
//         t==2 V transposed [b,h,d,S].
// ksplit>1: blockIdx.z indexes a K-chunk of size K/ksplit (wz/bz/cz must be 0).
__global__ __launch_bounds__(256) void mgemm_kern(
    const u16* __restrict__ A, const u16* __restrict__ Wt,
    const float* __restrict__ bias, void* __restrict__ Cv,
    int N, int K, long wz, long bz, long cz, int mode, int ksplit)
{
  const int z = blockIdx.z;
  int k0 = 0, kend = K;
  if (ksplit > 1) {
    const int kch = K / ksplit;
    k0 = z * kch; kend = k0 + kch;
  } else {
    Wt += (long)z * wz; bias += (long)z * bz;
  }
  // XCD-aware chunked swizzle: each XCD owns a contiguous run of M-panels
  const int gx = gridDim.x;
  const int nwg = gx * gridDim.y;
  int bid = blockIdx.y * gx + blockIdx.x;
  bid = (bid & 7) * (nwg >> 3) + (bid >> 3);
  const long bm = (long)(bid / gx) * 128;
  const int bn = (bid % gx) * 128;

  const int tid = threadIdx.x;
  const int lane = tid & 63, w = tid >> 6;
  const int wm = w >> 1, wn = w & 1;
  const int ls = lane >> 4, lr = lane & 15;

  __shared__ u16 LB[32768];            // 64 KB: two 32KB stages; epilogue reuses first 32KB
  u16* const St0 = LB;                 // stage 0: A[0..8191], B[8192..16383]
  u16* const St1 = LB + 16384;         // stage 1

  f32x4 acc[4][4];
  #pragma unroll
  for (int i = 0; i < 4; ++i)
    #pragma unroll
    for (int j = 0; j < 4; ++j)
      acc[i][j] = (f32x4){0.f, 0.f, 0.f, 0.f};

  // stage one K-tile (BK=64) into buf: granule n -> row=n>>3, kc=(n&7)^(row&7)
  auto STAGE = [&](u16* buf, int kk) {
    #pragma unroll
    for (int c = 0; c < 4; ++c) {
      const int n = (w * 4 + c) * 64 + lane;
      const int row = n >> 3;
      const int kc2 = (n & 7) ^ (row & 7);
      gload16(A  + (bm + row) * K + kk + kc2 * 8, buf + (w * 4 + c) * 512);
      gload16(Wt + (long)(bn + row) * K + kk + kc2 * 8, buf + 8192 + (w * 4 + c) * 512);
    }
  };

  STAGE(St0, k0);
  __syncthreads();
  int cur = 0;
  for (int kk = k0; kk < kend; kk += 64) {
    if (kk + 64 < kend) STAGE(cur ? St0 : St1, kk + 64);
    const u16* AsL = cur ? St1 : St0;
    const u16* BsL = AsL + 8192;
    #pragma unroll
    for (int ks = 0; ks < 2; ++ks) {
      bf16x8 af[4], bv[4];
      const int kc = ks * 4 + ls;
      const int sw = (kc ^ (lr & 7)) << 3;
      #pragma unroll
      for (int mf = 0; mf < 4; ++mf)
        af[mf] = *(const bf16x8*)&AsL[(wm * 64 + mf * 16 + lr) * 64 + sw];
      #pragma unroll
      for (int nf = 0; nf < 4; ++nf)
        bv[nf] = *(const bf16x8*)&BsL[(wn * 64 + nf * 16 + lr) * 64 + sw];
      #pragma unroll
      for (int mf = 0; mf < 4; ++mf)
        #pragma unroll
        for (int nf = 0; nf < 4; ++nf)
          acc[mf][nf] = __builtin_amdgcn_mfma_f32_16x16x32_bf16(
              af[mf], bv[nf], acc[mf][nf], 0, 0, 0);
    }
    __syncthreads();   // drains next-stage vmcnt; all reads of cur done
    cur ^= 1;
  }

  float* Cf = (float*)Cv + (long)z * cz;
  u16*   Cu = (u16*)Cv  + (long)z * cz;
  const int r0 = ls * 4;
  const bool addb = (ksplit == 1) || (z == 0);

  if (mode == 1 || (mode == 4 && bn < 1536)) {
    // bf16 coalesced store via LDS transpose (first 32KB of LB as [128][128] u16)
    const int t = (mode == 4) ? (bn / 768) : 0;
    const int cl0 = (mode == 4) ? (bn - t * 768) : bn;
    const int Nt = (mode == 4) ? 768 : N;
    u16* Cd = (mode == 4) ? (Cu + (long)t * HD) : Cu;
    #pragma unroll
    for (int nf = 0; nf < 4; ++nf) {
      const int col = wn * 64 + nf * 16 + lr;
      const float bvv = bias[bn + col];
      #pragma unroll
      for (int mf = 0; mf < 4; ++mf) {
        #pragma unroll
        for (int r = 0; r < 4; ++r) {
          const int rowl = wm * 64 + mf * 16 + r0 + r;
          float vv = acc[mf][nf][r] + bvv;
          if (mode == 1) vv = fast_gelu(vv);
          LB[rowl * 128 + (col ^ ((rowl & 7) << 3))] = f2bf(vv);
        }
      }
    }
    __syncthreads();
    const int c0 = (tid & 15) * 8;
    #pragma unroll
    for (int i = 0; i < 8; ++i) {
      const int gr = (tid >> 4) + i * 16;
      uint4 v4 = *(const uint4*)&LB[gr * 128 + (c0 ^ ((gr & 7) << 3))];
      *(uint4*)(Cd + (bm + gr) * Nt + cl0 + c0) = v4;
    }
    return;
  }

  if (mode == 4) {
    // V columns: store transposed [b][h][d][S] bf16, packed 4 tokens per uint2
    #pragma unroll
    for (int nf = 0; nf < 4; ++nf) {
      const int cl = bn - 1536 + wn * 64 + nf * 16 + lr;
      const int hcol = cl >> 6, dcol = cl & 63;
      const float bvv = bias[1536 + cl];
      #pragma unroll
      for (int mf = 0; mf < 4; ++mf) {
        const long t0 = bm + wm * 64 + mf * 16 + r0;
        const int bb2 = (int)(t0 >> 12), s0 = (int)(t0 & (S - 1));
        const float v0 = acc[mf][nf][0] + bvv, v1 = acc[mf][nf][1] + bvv;
        const float v2 = acc[mf][nf][2] + bvv, v3 = acc[mf][nf][3] + bvv;
        *(uint2*)(Cu + 2 * HD + (((long)bb2 * H + hcol) * 64 + dcol) * S + s0) =
            make_uint2(pack2(v0, v1), pack2(v2, v3));
      }
    }
    return;
  }

  #pragma unroll
  for (int nf = 0; nf < 4; ++nf) {
    const int col = bn + wn * 64 + nf * 16 + lr;
    const float bvv = addb ? bias[col] : 0.f;
    #pragma unroll
    for (int mf = 0; mf < 4; ++mf) {
      #pragma unroll
      for (int r = 0; r < 4; ++r) {
        const long row = bm + wm * 64 + mf * 16 + r0 + r;
        float vv = acc[mf][nf][r] + bvv;
        if (mode == 2) {
          if (ksplit > 1) atomicAdd(&Cf[row * N + col], vv);
          else            Cf[row * N + col] += vv;
        } else {
          Cf[row * N + col] = vv;
        }
      }
    }
  }
}

// ---------------- MFMA block attention ----------------
__global__ __launch_bounds__(256) void mattn_kern(
    const u16* __restrict__ q, const u16* __restrict__ k, const u16* __restrict__ vt,
    const float* __restrict__ mask, const int* __restrict__ rb,
    u16* __restrict__ ctx, float* __restrict__ part, int dense)
{
  int qb, kv0, nkv, qb2 = 0, ch = 0;
  if (dense) {
    qb2 = blockIdx.x / NCH; ch = blockIdx.x % NCH;
    qb = qb2 ? NB - 1 : 0; kv0 = ch * (NB / NCH); nkv = NB / NCH;
  } else {
    qb = blockIdx.x;
    if (qb == 0 || qb == NB - 1) return;
    kv0 = 0; nkv = NKV;
  }
  const int hh = blockIdx.y, b = blockIdx.z;
  const int tid = threadIdx.x, lane = tid & 63, w = tid >> 6;
  const int lr = lane & 15, hi = lane >> 4;

  __shared__ u16 Ks[64][72];
  __shared__ u16 Vs[64][72];
  __shared__ u16 Ps[64][72];
  __shared__ float Ms[64];

  const long qrow0 = (long)b * S + qb * 64;
  bf16x8 qf[2];
  {
    const u16* qp = q + (qrow0 + w * 16 + lr) * D + hh * 64 + hi * 8;
    qf[0] = *(const bf16x8*)(qp);
    qf[1] = *(const bf16x8*)(qp + 32);
  }
  const long vtbase = (((long)b * H + hh) * 64) * S;

  f32x4 acc[4];
  #pragma unroll
  for (int nf = 0; nf < 4; ++nf) acc[nf] = (f32x4){0.f, 0.f, 0.f, 0.f};
  float m_run[4], l_run[4];
  #pragma unroll
  for (int r = 0; r < 4; ++r) { m_run[r] = -1e30f; l_run[r] = 0.f; }

  for (int jj = 0; jj < nkv; ++jj) {
    int kb;
    if (dense) kb = kv0 + jj;
    else if (jj < 3) kb = qb - 1 + jj;
    else if (jj == 3) kb = 0;
    else if (jj == 4) kb = NB - 1;
    else kb = rb[qb * 3 + (jj - 5)];

    const long krow0 = (long)b * S + kb * 64;
    __syncthreads();
    {
      int key = tid >> 3, kc = tid & 7;
      *(uint4*)&Ks[key][kc * 8] = *(const uint4*)(k + (krow0 + key) * D + hh * 64 + kc * 8);
      *(uint4*)&Vs[key][kc * 8] = *(const uint4*)(vt + vtbase + (long)key * S + kb * 64 + kc * 8);
      key = (tid + 256) >> 3;
      *(uint4*)&Ks[key][kc * 8] = *(const uint4*)(k + (krow0 + key) * D + hh * 64 + kc * 8);
      *(uint4*)&Vs[key][kc * 8] = *(const uint4*)(vt + vtbase + (long)key * S + kb * 64 + kc * 8);
      if (tid < 64) Ms[tid] = mask[krow0 + tid];
    }
    __syncthreads();

    f32x4 sc[4];
    #pragma unroll
    for (int kf = 0; kf < 4; ++kf) sc[kf] = (f32x4){0.f, 0.f, 0.f, 0.f};
    __builtin_amdgcn_s_setprio(1);
    #pragma unroll
    for (int kc = 0; kc < 2; ++kc) {
      #pragma unroll
      for (int kf = 0; kf < 4; ++kf) {
        bf16x8 kfr = *(const bf16x8*)&Ks[kf * 16 + lr][kc * 32 + hi * 8];
        sc[kf] = __builtin_amdgcn_mfma_f32_16x16x32_bf16(qf[kc], kfr, sc[kf], 0, 0, 0);
      }
    }
    __builtin_amdgcn_s_setprio(0);

    float mkk[4];
    #pragma unroll
    for (int kf = 0; kf < 4; ++kf) mkk[kf] = (Ms[kf * 16 + lr] - 1.f) * 1e9f;
    #pragma unroll
    for (int r = 0; r < 4; ++r) {
      float s0 = sc[0][r] * SCALE + mkk[0];
      float s1 = sc[1][r] * SCALE + mkk[1];
      float s2 = sc[2][r] * SCALE + mkk[2];
      float s3 = sc[3][r] * SCALE + mkk[3];
      float mx = fmaxf(fmaxf(s0, s1), fmaxf(s2, s3));
      mx = fmaxf(mx, __shfl_xor(mx, 1));
      mx = fmaxf(mx, __shfl_xor(mx, 2));
      mx = fmaxf(mx, __shfl_xor(mx, 4));
      mx = fmaxf(mx, __shfl_xor(mx, 8));
      const float mn = fmaxf(m_run[r], mx);
      const float al = __expf(m_run[r] - mn);
      float p0 = __expf(s0 - mn), p1 = __expf(s1 - mn);
      float p2 = __expf(s2 - mn), p3 = __expf(s3 - mn);
      float sum = p0 + p1 + p2 + p3;
      sum += __shfl_xor(sum, 1);
      sum += __shfl_xor(sum, 2);
      sum += __shfl_xor(sum, 4);
      sum += __shfl_xor(sum, 8);
      l_run[r] = l_run[r] * al + sum;
      m_run[r] = mn;
      acc[0][r] *= al; acc[1][r] *= al; acc[2][r] *= al; acc[3][r] *= al;
      const int prow = w * 16 + hi * 4 + r;
      Ps[prow][ 0 + lr] = f2bf(p0);
      Ps[prow][16 + lr] = f2bf(p1);
      Ps[prow][32 + lr] = f2bf(p2);
      Ps[prow][48 + lr] = f2bf(p3);
    }
    __syncthreads();

    __builtin_amdgcn_s_setprio(1);
    #pragma unroll
    for (int kc = 0; kc < 2; ++kc) {
      bf16x8 pf = *(const bf16x8*)&Ps[w * 16 + lr][kc * 32 + hi * 8];
      #pragma unroll
      for (int nf = 0; nf < 4; ++nf) {
        bf16x8 vfr = *(const bf16x8*)&Vs[nf * 16 + lr][kc * 32 + hi * 8];
        acc[nf] = __builtin_amdgcn_mfma_f32_16x16x32_bf16(pf, vfr, acc[nf], 0, 0, 0);
      }
    }
    __builtin_amdgcn_s_setprio(0);
  }

  if (!dense) {
    #pragma unroll
    for (int r = 0; r < 4; ++r) {
      const float inv = 1.f / l_run[r];
      u16* op = ctx + (qrow0 + w * 16 + hi * 4 + r) * D + hh * 64 + lr;
      op[ 0] = f2bf(acc[0][r] * inv);
      op[16] = f2bf(acc[1][r] * inv);
      op[32] = f2bf(acc[2][r] * inv);
      op[48] = f2bf(acc[3][r] * inv);
    }
  } else {
    const long pb = ((((long)b * H + hh) * 2 + qb2) * NCH + ch) * (64 * 68);
    #pragma unroll
    for (int r = 0; r < 4; ++r) {
      float* pp = part + pb + (w * 16 + hi * 4 + r) * 68;
      pp[ 0 + lr] = acc[0][r];
      pp[16 + lr] = acc[1][r];
      pp[32 + lr] = acc[2][r];
      pp[48 + lr] = acc[3][r];
      if (lr == 0) { pp[64] = m_run[r]; pp[65] = l_run[r]; }
    }
  }
}

// ---------------- combine dense split-K partials ----------------
__global__ __launch_bounds__(256) void attn_combine_kern(
    const float* __restrict__ part, u16* __restrict__ ctx)
{
  const int g = blockIdx.x;
  const int qb2 = g & 1;
  const int hh = (g >> 1) % H;
  const int b  = g / (2 * H);
  const int r  = threadIdx.x >> 2;
  const int d0 = (threadIdx.x & 3) * 16;
  const long pb = (long)g * NCH * 64 * 68;
  float mg = -1e30f;
  for (int ch = 0; ch < NCH; ++ch)
    mg = fmaxf(mg, part[pb + ch * 64 * 68 + r * 68 + 64]);
  float lg = 0.f;
  float a[16] = {};
  for (int ch = 0; ch < NCH; ++ch) {
    const float* pp = part + pb + ch * 64 * 68 + r * 68;
    const float w = __expf(pp[64] - mg);
    lg += pp[65] * w;
    #pragma unroll
    for (int i = 0; i < 4; ++i) {
      float4 t4 = *(const float4*)(pp + d0 + i * 4);
      a[i*4+0] += t4.x * w; a[i*4+1] += t4.y * w; a[i*4+2] += t4.z * w; a[i*4+3] += t4.w * w;
    }
  }
  const int qb = qb2 ? NB - 1 : 0;
  const float inv = 1.f / lg;
  u16* op = ctx + ((long)b * S + qb * 64 + r) * D + hh * 64 + d0;
  #pragma unroll
  for (int i = 0; i < 4; ++i)
    *(uint2*)(op + i * 4) = make_uint2(pack2(a[i*4+0]*inv, a[i*4+1]*inv),
                                       pack2(a[i*4+2]*inv, a[i*4+3]*inv));
}

// ---------------- span mean-pool + head ----------------
__global__ __launch_bounds__(256) void span_head_kern(
    const float* __restrict__ h, const int* __restrict__ spans,
    const float* __restrict__ hw, const float* __restrict__ hb, float* __restrict__ out)
{
  __shared__ float s0[4], s1[4];
  const int bn = blockIdx.x;
  const int tid = threadIdx.x;
  const int st = spans[bn * 2], en = spans[bn * 2 + 1];
  const int b = bn >> 3;
  float a0 = 0.f, a1 = 0.f, a2 = 0.f;
  for (int s = st; s < en; ++s) {
    const float* row = h + ((long)b * S + s) * D;
    a0 += row[tid]; a1 += row[tid + 256]; a2 += row[tid + 512];
  }
  const float inv = 1.f / (float)(en - st);
  a0 *= inv; a1 *= inv; a2 *= inv;
  float p0 = a0 * hw[tid * 2]     + a1 * hw[(tid + 256) * 2]     + a2 * hw[(tid + 512) * 2];
  float p1 = a0 * hw[tid * 2 + 1] + a1 * hw[(tid + 256) * 2 + 1] + a2 * hw[(tid + 512) * 2 + 1];
  #pragma unroll
  for (int o = 32; o; o >>= 1) { p0 += __shfl_xor(p0, o); p1 += __shfl_xor(p1, o); }
  if ((tid & 63) == 0) { s0[tid >> 6] = p0; s1[tid >> 6] = p1; }
  __syncthreads();
  if (tid == 0) {
    out[bn * 2]     = s0[0] + s0[1] + s0[2] + s0[3] + hb[0];
    out[bn * 2 + 1] = s1[0] + s1[1] + s1[2] + s1[3] + hb[1];
  }
}

// ---------------- launcher ----------------
extern "C" void kernel_launch(void* const* d_in, const int* in_sizes, int n_in,
                              void* d_out, int out_size, void* d_ws, size_t ws_size,
                              hipStream_t stream) {
  const int*   input_ids  = (const int*)  d_in[0];
  const float* attn_mask  = (const float*)d_in[1];
  const int*   tok_type   = (const int*)  d_in[2];
  const int*   spans      = (const int*)  d_in[3];
  const int*   rand_blk   = (const int*)  d_in[4];
  const float* word_emb   = (const float*)d_in[5];
  const float* pos_emb    = (const float*)d_in[6];
  const float* type_emb   = (const float*)d_in[7];
  const float* emb_g      = (const float*)d_in[8];
  const float* emb_b      = (const float*)d_in[9];
  const float* qkv_w      = (const float*)d_in[10];
  const float* qkv_b      = (const float*)d_in[11];
  const float* aow        = (const float*)d_in[12];
  const float* aob        = (const float*)d_in[13];
  const float* ln1g       = (const float*)d_in[14];
  const float* ln1b       = (const float*)d_in[15];
  const float* ff1w       = (const float*)d_in[16];
  const float* ff1b       = (const float*)d_in[17];
  const float* ff2w       = (const float*)d_in[18];
  const float* ff2b       = (const float*)d_in[19];
  const float* ln2g       = (const float*)d_in[20];
  const float* ln2b       = (const float*)d_in[21];
  const float* headw      = (const float*)d_in[22];
  const float* headb      = (const float*)d_in[23];

  float* ws    = (float*)d_ws;
  float* h     = ws;                          // [M,D] fp32
  u16*   qkvb  = (u16*)(ws + HD);             // q,k bf16 [M,D]; vt [B,H,64,S]
  u16*   ffb   = (u16*)(ws + HD);             // [M,F] bf16 overlays qkv region
  u16*   ctx16 = (u16*)(ws + 3 * HD);         // [M,D] bf16
  u16*   hb    = (u16*)(ws + 3 * HD + HD/2);  // [M,D] bf16
  float* part  = ws + 4 * HD;                 // dense partials ~0.84M floats
  u16*   wb    = (u16*)(ws + 4 * HD + HD/4);  // bf16 weights 2*WL u16

  // ---- weight prep (bf16 transposed) ----
  for (int l = 0; l < 2; ++l) {
    u16* wl = wb + (long)l * WL;
    wtrans_kern<<<dim3(24, 24, 3), dim3(256), 0, stream>>>(
        qkv_w + (long)l * 3 * D * D, wl, D, D, (long)D * D, (long)D * D);
    wtrans_kern<<<dim3(24, 24, 1), dim3(256), 0, stream>>>(
        aow + (long)l * D * D, wl + WQ, D, D, 0, 0);
    wtrans_kern<<<dim3(96, 24, 1), dim3(256), 0, stream>>>(
        ff1w + (long)l * D * F, wl + WQ + WA, D, F, 0, 0);
    wtrans_kern<<<dim3(24, 96, 1), dim3(256), 0, stream>>>(
        ff2w + (long)l * F * D, wl + WQ + WA + W1, F, D, 0, 0);
  }

  embed_ln_kern<<<dim3(M), dim3(256), 0, stream>>>(
      input_ids, tok_type, word_emb, pos_emb, type_emb, emb_g, emb_b, h, hb);

  for (int l = 0; l < 2; ++l) {
    u16* wl = wb + (long)l * WL;
    // merged QKV projection (N=2304): q,k coalesced bf16; v transposed [b,h,d,S]
    mgemm_kern<<<dim3(18, 64, 1), dim3(256), 0, stream>>>(
        hb, wl, qkv_b + (long)l * 3 * D, qkvb, 2304, D, 0, 0, 0, 4, 1);
    // sparse block attention (MFMA)
    mattn_kern<<<dim3(NB, H, B), dim3(256), 0, stream>>>(
        qkvb, qkvb + HD, qkvb + 2 * HD, attn_mask, rand_blk, ctx16, part, 0);
    // dense attention for global query blocks, split-K
    mattn_kern<<<dim3(2 * NCH, H, B), dim3(256), 0, stream>>>(
        qkvb, qkvb + HD, qkvb + 2 * HD, attn_mask, rand_blk, ctx16, part, 1);
    attn_combine_kern<<<dim3(B * H * 2), dim3(256), 0, stream>>>(part, ctx16);
    // output projection + residual into h (split-K 2, atomic)
    mgemm_kern<<<dim3(6, 64, 2), dim3(256), 0, stream>>>(
        ctx16, wl + WQ, aob + (long)l * D, h, D, D, 0, 0, 0, 2, 2);
    ln_kern<<<dim3(M), dim3(256), 0, stream>>>(h, ln1g + (long)l * D, ln1b + (long)l * D, hb);
    // FFN
    mgemm_kern<<<dim3(24, 64, 1), dim3(256), 0, stream>>>(
        hb, wl + WQ + WA, ff1b + (long)l * F, ffb, F, D, 0, 0, 0, 1, 1);
    mgemm_kern<<<dim3(6, 64, 2), dim3(256), 0, stream>>>(
        ffb, wl + WQ + WA + W1, ff2b + (long)l * D, h, D, F, 0, 0, 0, 2, 2);
    ln_kern<<<dim3(M), dim3(256), 0, stream>>>(h, ln2g + (long)l * D, ln2b + (long)l * D, hb);
  }

  span_head_kern<<<dim3(B * NS), dim3(256), 0, stream>>>(h, spans, headw, headb, (float*)d_out);
}